// Round 1
// baseline (498.657 us; speedup 1.0000x reference)
//
#include <hip/hip_runtime.h>
#include <hip/hip_bf16.h>

// Problem constants
constexpr int B_ = 4;
constexpr int C_ = 192;
constexpr int L_ = 4096;     // H*W = 64*64
constexpr int DI = 384;      // d_inner
constexpr int DSs = 16;      // d_state
constexpr int DTR = 12;      // dt_rank
constexpr int NDBL = 44;     // dt_rank + 2*d_state
constexpr int NCHUNK = 64;   // scan chunks
constexpr int CSZ = 64;      // chunk size (NCHUNK*CSZ == L_)

constexpr size_t BL = (size_t)B_ * L_;                    // 16384
constexpr size_t OFF_SEQN = 0;                            // BL*C_
constexpr size_t OFF_XIN  = OFF_SEQN + BL * C_;           // BL*DI
constexpr size_t OFF_Z    = OFF_XIN + BL * DI;            // BL*DI
constexpr size_t OFF_XS   = OFF_Z + BL * DI;              // BL*DI
constexpr size_t OFF_DBL  = OFF_XS + BL * DI;             // BL*NDBL
constexpr size_t OFF_DTT  = OFF_DBL + BL * NDBL;          // BL*DI (transposed (B,DI,L))
constexpr size_t OFF_SBUF = OFF_DTT + BL * DI;            // B*DI*NCHUNK
constexpr size_t OFF_HLOC = OFF_SBUF + (size_t)B_ * DI * NCHUNK;
constexpr size_t OFF_HIN  = OFF_HLOC + (size_t)B_ * DI * NCHUNK * DSs;
// total = OFF_HIN + B*DI*NCHUNK*DS = 32,276,480 floats = ~129.1 MB

// ---------------- LayerNorm over C per (b,l), x(B,C,L) -> seqn(B,L,C) ----------------
__global__ __launch_bounds__(256) void k_ln(const float* __restrict__ x,
                                            const float* __restrict__ nw,
                                            const float* __restrict__ nb,
                                            float* __restrict__ seqn) {
  __shared__ float xt[192][65];
  __shared__ float ps[4][64], ps2[4][64];
  __shared__ float mu_[64], rs_[64];
  __shared__ float wsh[192], bsh[192];
  int tid = threadIdx.x;
  int blk = blockIdx.x;            // 0..255
  int b = blk >> 6;
  int l0 = (blk & 63) << 6;
  const float* xb = x + (size_t)b * C_ * L_;
  for (int idx = tid; idx < 192 * 64; idx += 256) {
    int c = idx >> 6, ll = idx & 63;
    xt[c][ll] = xb[(size_t)c * L_ + l0 + ll];
  }
  if (tid < 192) { wsh[tid] = nw[tid]; bsh[tid] = nb[tid]; }
  __syncthreads();
  int ll = tid & 63, q = tid >> 6;
  float s = 0.f, ss = 0.f;
  for (int c = q * 48; c < q * 48 + 48; ++c) { float v = xt[c][ll]; s += v; ss += v * v; }
  ps[q][ll] = s; ps2[q][ll] = ss;
  __syncthreads();
  if (q == 0) {
    float st = ps[0][ll] + ps[1][ll] + ps[2][ll] + ps[3][ll];
    float sst = ps2[0][ll] + ps2[1][ll] + ps2[2][ll] + ps2[3][ll];
    float mu = st * (1.f / 192.f);
    float var = sst * (1.f / 192.f) - mu * mu;
    mu_[ll] = mu; rs_[ll] = rsqrtf(var + 1e-5f);
  }
  __syncthreads();
  float* so = seqn + ((size_t)b * L_ + l0) * C_;
  for (int idx = tid; idx < 64 * 192; idx += 256) {
    int l = idx / 192, c = idx - l * 192;
    so[idx] = (xt[c][l] - mu_[l]) * rs_[l] * wsh[c] + bsh[c];
  }
}

// ---------------- in_proj: seqn(BL,192) @ W(768,192)^T -> xin(BL,384), z(BL,384) -----
__global__ __launch_bounds__(256) void k_inproj(const float* __restrict__ A,
                                                const float* __restrict__ Wt,
                                                float* __restrict__ xin,
                                                float* __restrict__ z) {
  __shared__ float As[32][68];
  __shared__ float Bs[32][68];
  int tid = threadIdx.x;
  int m0 = blockIdx.x << 6;
  int n0 = blockIdx.y << 6;
  int r = tid >> 2;
  int kq = (tid & 3) << 3;
  int tx = tid & 15, ty = tid >> 4;
  float acc[4][4] = {{0.f}};
  for (int k0 = 0; k0 < 192; k0 += 32) {
    __syncthreads();
    const float* ap = A + (size_t)(m0 + r) * 192 + k0 + kq;
    float4 a0 = *(const float4*)ap;
    float4 a1 = *(const float4*)(ap + 4);
    const float* bp = Wt + (size_t)(n0 + r) * 192 + k0 + kq;
    float4 b0 = *(const float4*)bp;
    float4 b1 = *(const float4*)(bp + 4);
    As[kq + 0][r] = a0.x; As[kq + 1][r] = a0.y; As[kq + 2][r] = a0.z; As[kq + 3][r] = a0.w;
    As[kq + 4][r] = a1.x; As[kq + 5][r] = a1.y; As[kq + 6][r] = a1.z; As[kq + 7][r] = a1.w;
    Bs[kq + 0][r] = b0.x; Bs[kq + 1][r] = b0.y; Bs[kq + 2][r] = b0.z; Bs[kq + 3][r] = b0.w;
    Bs[kq + 4][r] = b1.x; Bs[kq + 5][r] = b1.y; Bs[kq + 6][r] = b1.z; Bs[kq + 7][r] = b1.w;
    __syncthreads();
#pragma unroll
    for (int k = 0; k < 32; ++k) {
      float4 av = *(const float4*)&As[k][ty << 2];
      float4 bv = *(const float4*)&Bs[k][tx << 2];
      float a4[4] = {av.x, av.y, av.z, av.w};
      float b4[4] = {bv.x, bv.y, bv.z, bv.w};
#pragma unroll
      for (int i = 0; i < 4; ++i)
#pragma unroll
        for (int j = 0; j < 4; ++j) acc[i][j] = fmaf(a4[i], b4[j], acc[i][j]);
    }
  }
  int col = n0 + (tx << 2);
  float* dst = (col < 384) ? xin : z;
  int cl = (col < 384) ? col : col - 384;
#pragma unroll
  for (int i = 0; i < 4; ++i) {
    int row = m0 + (ty << 2) + i;
    *(float4*)&dst[(size_t)row * DI + cl] = make_float4(acc[i][0], acc[i][1], acc[i][2], acc[i][3]);
  }
}

// ---------------- depthwise causal conv(4) + SiLU: xin(B,L,DI) -> xs(B,L,DI) ---------
__global__ __launch_bounds__(256) void k_conv(const float* __restrict__ xin,
                                              const float* __restrict__ cw,
                                              const float* __restrict__ cb,
                                              float* __restrict__ xs) {
  __shared__ float xt[67][64];
  __shared__ float res[64][65];
  int tid = threadIdx.x;
  int d0 = blockIdx.x << 6;
  int l0 = blockIdx.y << 6;
  int b = blockIdx.z;
  for (int idx = tid; idx < 67 * 16; idx += 256) {
    int rr = idx >> 4, q = idx & 15;
    int l = l0 - 3 + rr;
    float4 v = make_float4(0.f, 0.f, 0.f, 0.f);
    if (l >= 0) v = *(const float4*)&xin[((size_t)b * L_ + l) * DI + d0 + (q << 2)];
    *(float4*)&xt[rr][q << 2] = v;
  }
  __syncthreads();
  int dd = tid & 63, lq = tid >> 6;
  float4 w4 = *(const float4*)&cw[(d0 + dd) * 4];
  float bb = cb[d0 + dd];
  for (int rr = 0; rr < 16; ++rr) {
    int ll = (rr << 2) + lq;
    float a = bb + w4.x * xt[ll][dd] + w4.y * xt[ll + 1][dd] + w4.z * xt[ll + 2][dd] +
              w4.w * xt[ll + 3][dd];
    res[ll][dd] = a / (1.f + __expf(-a));
  }
  __syncthreads();
  for (int idx = tid; idx < 64 * 16; idx += 256) {
    int ll = idx >> 4, q = idx & 15;
    float4 v = make_float4(res[ll][(q << 2)], res[ll][(q << 2) + 1], res[ll][(q << 2) + 2],
                           res[ll][(q << 2) + 3]);
    *(float4*)&xs[((size_t)b * L_ + l0 + ll) * DI + d0 + (q << 2)] = v;
  }
}

// ---------------- x_proj: xs(BL,384) @ W(44,384)^T -> dbl(BL,44) ---------------------
__global__ __launch_bounds__(256) void k_xproj(const float* __restrict__ A,
                                               const float* __restrict__ Wt,
                                               float* __restrict__ dbl) {
  __shared__ float As[32][68];
  __shared__ float Bs[32][68];
  int tid = threadIdx.x;
  int m0 = blockIdx.x << 6;
  int r = tid >> 2;
  int kq = (tid & 3) << 3;
  int tx = tid & 15, ty = tid >> 4;
  float acc[4][4] = {{0.f}};
  for (int k0 = 0; k0 < 384; k0 += 32) {
    __syncthreads();
    const float* ap = A + (size_t)(m0 + r) * 384 + k0 + kq;
    float4 a0 = *(const float4*)ap;
    float4 a1 = *(const float4*)(ap + 4);
    float4 b0 = make_float4(0.f, 0.f, 0.f, 0.f), b1 = b0;
    if (r < 44) {
      const float* bp = Wt + (size_t)r * 384 + k0 + kq;
      b0 = *(const float4*)bp;
      b1 = *(const float4*)(bp + 4);
    }
    As[kq + 0][r] = a0.x; As[kq + 1][r] = a0.y; As[kq + 2][r] = a0.z; As[kq + 3][r] = a0.w;
    As[kq + 4][r] = a1.x; As[kq + 5][r] = a1.y; As[kq + 6][r] = a1.z; As[kq + 7][r] = a1.w;
    Bs[kq + 0][r] = b0.x; Bs[kq + 1][r] = b0.y; Bs[kq + 2][r] = b0.z; Bs[kq + 3][r] = b0.w;
    Bs[kq + 4][r] = b1.x; Bs[kq + 5][r] = b1.y; Bs[kq + 6][r] = b1.z; Bs[kq + 7][r] = b1.w;
    __syncthreads();
#pragma unroll
    for (int k = 0; k < 32; ++k) {
      float4 av = *(const float4*)&As[k][ty << 2];
      float4 bv = *(const float4*)&Bs[k][tx << 2];
      float a4[4] = {av.x, av.y, av.z, av.w};
      float b4[4] = {bv.x, bv.y, bv.z, bv.w};
#pragma unroll
      for (int i = 0; i < 4; ++i)
#pragma unroll
        for (int j = 0; j < 4; ++j) acc[i][j] = fmaf(a4[i], b4[j], acc[i][j]);
    }
  }
#pragma unroll
  for (int i = 0; i < 4; ++i) {
    int row = m0 + (ty << 2) + i;
#pragma unroll
    for (int j = 0; j < 4; ++j) {
      int col = (tx << 2) + j;
      if (col < NDBL) dbl[(size_t)row * NDBL + col] = acc[i][j];
    }
  }
}

// ---------------- dt_proj + softplus -> dt_t(B,DI,L) (transposed) --------------------
__global__ __launch_bounds__(256) void k_dtproj(const float* __restrict__ dbl,
                                                const float* __restrict__ dw,
                                                const float* __restrict__ db,
                                                float* __restrict__ dt_t) {
  __shared__ float wlds[384 * 12];
  __shared__ float blds[384];
  __shared__ float dl[256 * 13];
  int tid = threadIdx.x;
  int row0 = blockIdx.x << 8;  // 256 rows of (BL)
  for (int idx = tid; idx < 384 * 12; idx += 256) wlds[idx] = dw[idx];
  if (tid < 256) { }  // no-op
  for (int idx = tid; idx < 384; idx += 256) blds[idx] = db[idx];
  for (int idx = tid; idx < 256 * 12; idx += 256) {
    int l = idx / 12, k = idx - l * 12;
    dl[l * 13 + k] = dbl[(size_t)(row0 + l) * NDBL + k];
  }
  __syncthreads();
  float dv[12];
#pragma unroll
  for (int k = 0; k < 12; ++k) dv[k] = dl[tid * 13 + k];
  int b = row0 >> 12;
  int lbase = (row0 & (L_ - 1)) + tid;
  float* outb = dt_t + (size_t)b * DI * L_ + lbase;
  for (int j = 0; j < 384; ++j) {
    float acc = blds[j];
#pragma unroll
    for (int k = 0; k < 12; ++k) acc = fmaf(wlds[j * 12 + k], dv[k], acc);
    float sp = fmaxf(acc, 0.f) + log1pf(__expf(-fabsf(acc)));
    outb[(size_t)j * L_] = sp;
  }
}

// ---------------- scan pass A: per-chunk local scan, store Hloc & S=sum(dt) ----------
__global__ __launch_bounds__(256) void k_scanA(const float* __restrict__ dt_t,
                                               const float* __restrict__ xs,
                                               const float* __restrict__ dbl,
                                               const float* __restrict__ A_log,
                                               float* __restrict__ Hloc,
                                               float* __restrict__ Sbuf) {
  int tid = threadIdx.x;
  int gw = (blockIdx.x << 2) + (tid >> 6);
  int lane = tid & 63;
  int g = lane >> 4, n = lane & 15;
  int chunk = gw & 63;
  int rest = gw >> 6;
  int dq = rest % 96;
  int b = rest / 96;
  int d = (dq << 2) + g;
  float An = -__expf(A_log[d * 16 + n]);
  int l0 = chunk << 6;
  const float* dtp = dt_t + ((size_t)b * DI + d) * L_ + l0;
  const float* xp = xs + ((size_t)b * L_ + l0) * DI + d;
  const float* bp = dbl + ((size_t)b * L_ + l0) * NDBL + DTR + n;
  float h = 0.f, S = 0.f;
  for (int i = 0; i < CSZ; ++i) {
    float dt = dtp[i];
    float xv = xp[(size_t)i * DI];
    float Bn = bp[(size_t)i * NDBL];
    float dA = __expf(dt * An);
    h = fmaf(dA, h, dt * xv * Bn);
    S += dt;
  }
  size_t base = ((size_t)b * DI + d) * NCHUNK + chunk;
  Hloc[base * 16 + n] = h;
  if (n == 0) Sbuf[base] = S;
}

// ---------------- scan pass B: chunk-level recurrence -> Hin per chunk ---------------
__global__ __launch_bounds__(256) void k_scanB(const float* __restrict__ A_log,
                                               const float* __restrict__ Hloc,
                                               const float* __restrict__ Sbuf,
                                               float* __restrict__ Hin) {
  int gid = blockIdx.x * 256 + threadIdx.x;
  int n = gid & 15;
  int rest = gid >> 4;
  int d = rest % 384;
  int b = rest / 384;
  float An = -__expf(A_log[d * 16 + n]);
  float h = 0.f;
  size_t base = ((size_t)b * DI + d) * NCHUNK;
  for (int c = 0; c < NCHUNK; ++c) {
    Hin[(base + c) * 16 + n] = h;
    float S = Sbuf[base + c];
    float P = __expf(An * S);
    h = fmaf(P, h, Hloc[(base + c) * 16 + n]);
  }
}

// ---------------- scan pass C: redo local scan w/ carry, fuse y & gating -------------
__global__ __launch_bounds__(256) void k_scanC(const float* __restrict__ dt_t,
                                               const float* __restrict__ xs,
                                               const float* __restrict__ dbl,
                                               const float* __restrict__ z,
                                               const float* __restrict__ A_log,
                                               const float* __restrict__ Dw,
                                               const float* __restrict__ Hin,
                                               float* __restrict__ ybuf) {
  int tid = threadIdx.x;
  int gw = (blockIdx.x << 2) + (tid >> 6);
  int lane = tid & 63;
  int g = lane >> 4, n = lane & 15;
  int chunk = gw & 63;
  int rest = gw >> 6;
  int dq = rest % 96;
  int b = rest / 96;
  int d = (dq << 2) + g;
  float An = -__expf(A_log[d * 16 + n]);
  float Dd = Dw[d];
  int l0 = chunk << 6;
  const float* dtp = dt_t + ((size_t)b * DI + d) * L_ + l0;
  const float* xp = xs + ((size_t)b * L_ + l0) * DI + d;
  const float* bp = dbl + ((size_t)b * L_ + l0) * NDBL + DTR + n;
  const float* cp = dbl + ((size_t)b * L_ + l0) * NDBL + DTR + DSs + n;
  const float* zp = z + ((size_t)b * L_ + l0) * DI + d;
  float* yp = ybuf + ((size_t)b * L_ + l0) * DI + d;
  size_t base = ((size_t)b * DI + d) * NCHUNK + chunk;
  float h = Hin[base * 16 + n];
  for (int i = 0; i < CSZ; ++i) {
    float dt = dtp[i];
    float xv = xp[(size_t)i * DI];
    float Bn = bp[(size_t)i * NDBL];
    float dA = __expf(dt * An);
    h = fmaf(dA, h, dt * xv * Bn);
    float t = h * cp[(size_t)i * NDBL];
    t += __shfl_xor(t, 1);
    t += __shfl_xor(t, 2);
    t += __shfl_xor(t, 4);
    t += __shfl_xor(t, 8);
    if (n == 0) {
      float y = t + xv * Dd;
      float zv = zp[(size_t)i * DI];
      float sig = 1.f / (1.f + __expf(-zv));
      yp[(size_t)i * DI] = y * (zv * sig);
    }
  }
}

// ---------------- out_proj: y(BL,384) @ W(192,384)^T + x -> out(B,C,L) ---------------
__global__ __launch_bounds__(256) void k_outproj(const float* __restrict__ A,
                                                 const float* __restrict__ Wt,
                                                 const float* __restrict__ x,
                                                 float* __restrict__ out) {
  __shared__ float As[32][68];
  __shared__ float Bs[32][68];
  __shared__ float ct[64][65];
  int tid = threadIdx.x;
  int m0 = blockIdx.x << 6;
  int n0 = blockIdx.y << 6;
  int r = tid >> 2;
  int kq = (tid & 3) << 3;
  int tx = tid & 15, ty = tid >> 4;
  float acc[4][4] = {{0.f}};
  for (int k0 = 0; k0 < 384; k0 += 32) {
    __syncthreads();
    const float* ap = A + (size_t)(m0 + r) * 384 + k0 + kq;
    float4 a0 = *(const float4*)ap;
    float4 a1 = *(const float4*)(ap + 4);
    const float* bp = Wt + (size_t)(n0 + r) * 384 + k0 + kq;
    float4 b0 = *(const float4*)bp;
    float4 b1 = *(const float4*)(bp + 4);
    As[kq + 0][r] = a0.x; As[kq + 1][r] = a0.y; As[kq + 2][r] = a0.z; As[kq + 3][r] = a0.w;
    As[kq + 4][r] = a1.x; As[kq + 5][r] = a1.y; As[kq + 6][r] = a1.z; As[kq + 7][r] = a1.w;
    Bs[kq + 0][r] = b0.x; Bs[kq + 1][r] = b0.y; Bs[kq + 2][r] = b0.z; Bs[kq + 3][r] = b0.w;
    Bs[kq + 4][r] = b1.x; Bs[kq + 5][r] = b1.y; Bs[kq + 6][r] = b1.z; Bs[kq + 7][r] = b1.w;
    __syncthreads();
#pragma unroll
    for (int k = 0; k < 32; ++k) {
      float4 av = *(const float4*)&As[k][ty << 2];
      float4 bv = *(const float4*)&Bs[k][tx << 2];
      float a4[4] = {av.x, av.y, av.z, av.w};
      float b4[4] = {bv.x, bv.y, bv.z, bv.w};
#pragma unroll
      for (int i = 0; i < 4; ++i)
#pragma unroll
        for (int j = 0; j < 4; ++j) acc[i][j] = fmaf(a4[i], b4[j], acc[i][j]);
    }
  }
  __syncthreads();
#pragma unroll
  for (int i = 0; i < 4; ++i)
#pragma unroll
    for (int j = 0; j < 4; ++j) ct[(ty << 2) + i][(tx << 2) + j] = acc[i][j];
  __syncthreads();
  int b = m0 >> 12;
  int lb = m0 & (L_ - 1);
  for (int idx = tid; idx < 64 * 16; idx += 256) {
    int cc = idx >> 4;
    int q = idx & 15;
    int c = n0 + cc;
    size_t off = ((size_t)b * C_ + c) * L_ + lb + (q << 2);
    float4 xv = *(const float4*)&x[off];
    float4 v;
    v.x = ct[(q << 2) + 0][cc] + xv.x;
    v.y = ct[(q << 2) + 1][cc] + xv.y;
    v.z = ct[(q << 2) + 2][cc] + xv.z;
    v.w = ct[(q << 2) + 3][cc] + xv.w;
    *(float4*)&out[off] = v;
  }
}

extern "C" void kernel_launch(void* const* d_in, const int* in_sizes, int n_in,
                              void* d_out, int out_size, void* d_ws, size_t ws_size,
                              hipStream_t stream) {
  const float* x         = (const float*)d_in[0];
  const float* norm_w    = (const float*)d_in[1];
  const float* norm_b    = (const float*)d_in[2];
  const float* in_proj_w = (const float*)d_in[3];
  const float* conv_w    = (const float*)d_in[4];
  const float* conv_b    = (const float*)d_in[5];
  const float* x_proj_w  = (const float*)d_in[6];
  const float* dt_proj_w = (const float*)d_in[7];
  const float* dt_proj_b = (const float*)d_in[8];
  const float* A_log     = (const float*)d_in[9];
  const float* Dw        = (const float*)d_in[10];
  const float* out_proj_w= (const float*)d_in[11];
  float* out = (float*)d_out;
  float* ws = (float*)d_ws;

  float* seqn = ws + OFF_SEQN;
  float* xin  = ws + OFF_XIN;
  float* z    = ws + OFF_Z;
  float* xs   = ws + OFF_XS;
  float* dbl  = ws + OFF_DBL;
  float* dt_t = ws + OFF_DTT;
  float* Sbuf = ws + OFF_SBUF;
  float* Hloc = ws + OFF_HLOC;
  float* Hin  = ws + OFF_HIN;
  float* ybuf = xin;  // xin dead after conv

  hipLaunchKernelGGL(k_ln, dim3(256), dim3(256), 0, stream, x, norm_w, norm_b, seqn);
  hipLaunchKernelGGL(k_inproj, dim3(256, 12), dim3(256), 0, stream, seqn, in_proj_w, xin, z);
  hipLaunchKernelGGL(k_conv, dim3(6, 64, 4), dim3(256), 0, stream, xin, conv_w, conv_b, xs);
  hipLaunchKernelGGL(k_xproj, dim3(256), dim3(256), 0, stream, xs, x_proj_w, dbl);
  hipLaunchKernelGGL(k_dtproj, dim3(64), dim3(256), 0, stream, dbl, dt_proj_w, dt_proj_b, dt_t);
  hipLaunchKernelGGL(k_scanA, dim3(6144), dim3(256), 0, stream, dt_t, xs, dbl, A_log, Hloc, Sbuf);
  hipLaunchKernelGGL(k_scanB, dim3(96), dim3(256), 0, stream, A_log, Hloc, Sbuf, Hin);
  hipLaunchKernelGGL(k_scanC, dim3(6144), dim3(256), 0, stream, dt_t, xs, dbl, z, A_log, Dw, Hin,
                     ybuf);
  hipLaunchKernelGGL(k_outproj, dim3(256, 3), dim3(256), 0, stream, ybuf, out_proj_w, x, out);
}

// Round 2
// 271.682 us; speedup vs baseline: 1.8354x; 1.8354x over previous
//
#include <hip/hip_runtime.h>
#include <hip/hip_bf16.h>

// Problem constants
constexpr int B_ = 4;
constexpr int C_ = 192;
constexpr int L_ = 4096;     // H*W = 64*64
constexpr int DI = 384;      // d_inner
constexpr int DSs = 16;      // d_state
constexpr int DTR = 12;      // dt_rank
constexpr int NDBL = 44;     // dt_rank + 2*d_state
constexpr int NCHUNK = 128;  // scan chunks
constexpr int CSZ = 32;      // chunk size (NCHUNK*CSZ == L_)

constexpr size_t BL = (size_t)B_ * L_;                    // 16384
constexpr size_t OFF_SEQN = 0;                            // BL*C_  (reused as Hloc after in_proj)
constexpr size_t OFF_XIN  = OFF_SEQN + BL * C_;           // BL*DI  (reused as ybuf after conv)
constexpr size_t OFF_Z    = OFF_XIN + BL * DI;            // BL*DI
constexpr size_t OFF_XS   = OFF_Z + BL * DI;              // BL*DI
constexpr size_t OFF_DBL  = OFF_XS + BL * DI;             // BL*NDBL
constexpr size_t OFF_DT   = OFF_DBL + BL * NDBL;          // BL*DI  (B,L,DI) layout
constexpr size_t OFF_SBUF = OFF_DT + BL * DI;             // B*NCHUNK*DI
// total = OFF_SBUF + B*NCHUNK*DI = 29,229,056 floats ~= 117 MB (prev round used 129 MB: safe)

// ---------------- LayerNorm over C per (b,l), x(B,C,L) -> seqn(B,L,C) ----------------
__global__ __launch_bounds__(256) void k_ln(const float* __restrict__ x,
                                            const float* __restrict__ nw,
                                            const float* __restrict__ nb,
                                            float* __restrict__ seqn) {
  __shared__ float xt[192][65];
  __shared__ float ps[4][64], ps2[4][64];
  __shared__ float mu_[64], rs_[64];
  __shared__ float wsh[192], bsh[192];
  int tid = threadIdx.x;
  int blk = blockIdx.x;            // 0..255
  int b = blk >> 6;
  int l0 = (blk & 63) << 6;
  const float* xb = x + (size_t)b * C_ * L_;
  for (int idx = tid; idx < 192 * 64; idx += 256) {
    int c = idx >> 6, ll = idx & 63;
    xt[c][ll] = xb[(size_t)c * L_ + l0 + ll];
  }
  if (tid < 192) { wsh[tid] = nw[tid]; bsh[tid] = nb[tid]; }
  __syncthreads();
  int ll = tid & 63, q = tid >> 6;
  float s = 0.f, ss = 0.f;
  for (int c = q * 48; c < q * 48 + 48; ++c) { float v = xt[c][ll]; s += v; ss += v * v; }
  ps[q][ll] = s; ps2[q][ll] = ss;
  __syncthreads();
  if (q == 0) {
    float st = ps[0][ll] + ps[1][ll] + ps[2][ll] + ps[3][ll];
    float sst = ps2[0][ll] + ps2[1][ll] + ps2[2][ll] + ps2[3][ll];
    float mu = st * (1.f / 192.f);
    float var = sst * (1.f / 192.f) - mu * mu;
    mu_[ll] = mu; rs_[ll] = rsqrtf(var + 1e-5f);
  }
  __syncthreads();
  float* so = seqn + ((size_t)b * L_ + l0) * C_;
  for (int idx = tid; idx < 64 * 192; idx += 256) {
    int l = idx / 192, c = idx - l * 192;
    so[idx] = (xt[c][l] - mu_[l]) * rs_[l] * wsh[c] + bsh[c];
  }
}

// ---------------- in_proj: seqn(BL,192) @ W(768,192)^T -> xin(BL,384), z(BL,384) -----
__global__ __launch_bounds__(256) void k_inproj(const float* __restrict__ A,
                                                const float* __restrict__ Wt,
                                                float* __restrict__ xin,
                                                float* __restrict__ z) {
  __shared__ float As[32][68];
  __shared__ float Bs[32][68];
  int tid = threadIdx.x;
  int m0 = blockIdx.x << 6;
  int n0 = blockIdx.y << 6;
  int r = tid >> 2;
  int kq = (tid & 3) << 3;
  int tx = tid & 15, ty = tid >> 4;
  float acc[4][4] = {{0.f}};
  for (int k0 = 0; k0 < 192; k0 += 32) {
    __syncthreads();
    const float* ap = A + (size_t)(m0 + r) * 192 + k0 + kq;
    float4 a0 = *(const float4*)ap;
    float4 a1 = *(const float4*)(ap + 4);
    const float* bp = Wt + (size_t)(n0 + r) * 192 + k0 + kq;
    float4 b0 = *(const float4*)bp;
    float4 b1 = *(const float4*)(bp + 4);
    As[kq + 0][r] = a0.x; As[kq + 1][r] = a0.y; As[kq + 2][r] = a0.z; As[kq + 3][r] = a0.w;
    As[kq + 4][r] = a1.x; As[kq + 5][r] = a1.y; As[kq + 6][r] = a1.z; As[kq + 7][r] = a1.w;
    Bs[kq + 0][r] = b0.x; Bs[kq + 1][r] = b0.y; Bs[kq + 2][r] = b0.z; Bs[kq + 3][r] = b0.w;
    Bs[kq + 4][r] = b1.x; Bs[kq + 5][r] = b1.y; Bs[kq + 6][r] = b1.z; Bs[kq + 7][r] = b1.w;
    __syncthreads();
#pragma unroll
    for (int k = 0; k < 32; ++k) {
      float4 av = *(const float4*)&As[k][ty << 2];
      float4 bv = *(const float4*)&Bs[k][tx << 2];
      float a4[4] = {av.x, av.y, av.z, av.w};
      float b4[4] = {bv.x, bv.y, bv.z, bv.w};
#pragma unroll
      for (int i = 0; i < 4; ++i)
#pragma unroll
        for (int j = 0; j < 4; ++j) acc[i][j] = fmaf(a4[i], b4[j], acc[i][j]);
    }
  }
  int col = n0 + (tx << 2);
  float* dst = (col < 384) ? xin : z;
  int cl = (col < 384) ? col : col - 384;
#pragma unroll
  for (int i = 0; i < 4; ++i) {
    int row = m0 + (ty << 2) + i;
    *(float4*)&dst[(size_t)row * DI + cl] = make_float4(acc[i][0], acc[i][1], acc[i][2], acc[i][3]);
  }
}

// ---------------- depthwise causal conv(4) + SiLU: xin(B,L,DI) -> xs(B,L,DI) ---------
__global__ __launch_bounds__(256) void k_conv(const float* __restrict__ xin,
                                              const float* __restrict__ cw,
                                              const float* __restrict__ cb,
                                              float* __restrict__ xs) {
  __shared__ float xt[67][64];
  __shared__ float res[64][65];
  int tid = threadIdx.x;
  int d0 = blockIdx.x << 6;
  int l0 = blockIdx.y << 6;
  int b = blockIdx.z;
  for (int idx = tid; idx < 67 * 16; idx += 256) {
    int rr = idx >> 4, q = idx & 15;
    int l = l0 - 3 + rr;
    float4 v = make_float4(0.f, 0.f, 0.f, 0.f);
    if (l >= 0) v = *(const float4*)&xin[((size_t)b * L_ + l) * DI + d0 + (q << 2)];
    *(float4*)&xt[rr][q << 2] = v;
  }
  __syncthreads();
  int dd = tid & 63, lq = tid >> 6;
  float4 w4 = *(const float4*)&cw[(d0 + dd) * 4];
  float bb = cb[d0 + dd];
  for (int rr = 0; rr < 16; ++rr) {
    int ll = (rr << 2) + lq;
    float a = bb + w4.x * xt[ll][dd] + w4.y * xt[ll + 1][dd] + w4.z * xt[ll + 2][dd] +
              w4.w * xt[ll + 3][dd];
    res[ll][dd] = a / (1.f + __expf(-a));
  }
  __syncthreads();
  for (int idx = tid; idx < 64 * 16; idx += 256) {
    int ll = idx >> 4, q = idx & 15;
    float4 v = make_float4(res[ll][(q << 2)], res[ll][(q << 2) + 1], res[ll][(q << 2) + 2],
                           res[ll][(q << 2) + 3]);
    *(float4*)&xs[((size_t)b * L_ + l0 + ll) * DI + d0 + (q << 2)] = v;
  }
}

// ---------------- x_proj: xs(BL,384) @ W(44,384)^T -> dbl(BL,44) ---------------------
__global__ __launch_bounds__(256) void k_xproj(const float* __restrict__ A,
                                               const float* __restrict__ Wt,
                                               float* __restrict__ dbl) {
  __shared__ float As[32][68];
  __shared__ float Bs[32][68];
  int tid = threadIdx.x;
  int m0 = blockIdx.x << 6;
  int r = tid >> 2;
  int kq = (tid & 3) << 3;
  int tx = tid & 15, ty = tid >> 4;
  float acc[4][4] = {{0.f}};
  for (int k0 = 0; k0 < 384; k0 += 32) {
    __syncthreads();
    const float* ap = A + (size_t)(m0 + r) * 384 + k0 + kq;
    float4 a0 = *(const float4*)ap;
    float4 a1 = *(const float4*)(ap + 4);
    float4 b0 = make_float4(0.f, 0.f, 0.f, 0.f), b1 = b0;
    if (r < 44) {
      const float* bp = Wt + (size_t)r * 384 + k0 + kq;
      b0 = *(const float4*)bp;
      b1 = *(const float4*)(bp + 4);
    }
    As[kq + 0][r] = a0.x; As[kq + 1][r] = a0.y; As[kq + 2][r] = a0.z; As[kq + 3][r] = a0.w;
    As[kq + 4][r] = a1.x; As[kq + 5][r] = a1.y; As[kq + 6][r] = a1.z; As[kq + 7][r] = a1.w;
    Bs[kq + 0][r] = b0.x; Bs[kq + 1][r] = b0.y; Bs[kq + 2][r] = b0.z; Bs[kq + 3][r] = b0.w;
    Bs[kq + 4][r] = b1.x; Bs[kq + 5][r] = b1.y; Bs[kq + 6][r] = b1.z; Bs[kq + 7][r] = b1.w;
    __syncthreads();
#pragma unroll
    for (int k = 0; k < 32; ++k) {
      float4 av = *(const float4*)&As[k][ty << 2];
      float4 bv = *(const float4*)&Bs[k][tx << 2];
      float a4[4] = {av.x, av.y, av.z, av.w};
      float b4[4] = {bv.x, bv.y, bv.z, bv.w};
#pragma unroll
      for (int i = 0; i < 4; ++i)
#pragma unroll
        for (int j = 0; j < 4; ++j) acc[i][j] = fmaf(a4[i], b4[j], acc[i][j]);
    }
  }
#pragma unroll
  for (int i = 0; i < 4; ++i) {
    int row = m0 + (ty << 2) + i;
#pragma unroll
    for (int j = 0; j < 4; ++j) {
      int col = (tx << 2) + j;
      if (col < NDBL) dbl[(size_t)row * NDBL + col] = acc[i][j];
    }
  }
}

// ---------------- dt_proj + softplus -> dt(B,L,DI) -----------------------------------
// Thread owns output column j; 64 rows per block; coalesced writes.
__global__ __launch_bounds__(384) void k_dtproj(const float* __restrict__ dbl,
                                                const float* __restrict__ dw,
                                                const float* __restrict__ db,
                                                float* __restrict__ dt) {
  __shared__ float dl[64][12];
  int tid = threadIdx.x;
  int row0 = blockIdx.x << 6;
  for (int idx = tid; idx < 64 * 12; idx += 384) {
    int r = idx / 12, k = idx - r * 12;
    dl[r][k] = dbl[(size_t)(row0 + r) * NDBL + k];
  }
  float w[12];
#pragma unroll
  for (int k = 0; k < 12; ++k) w[k] = dw[tid * 12 + k];
  float bias = db[tid];
  __syncthreads();
  for (int r = 0; r < 64; ++r) {
    float acc = bias;
#pragma unroll
    for (int k = 0; k < 12; ++k) acc = fmaf(w[k], dl[r][k], acc);
    float sp = fmaxf(acc, 0.f) + log1pf(__expf(-fabsf(acc)));
    dt[(size_t)(row0 + r) * DI + tid] = sp;
  }
}

// ---------------- scan pass A: thread-per-d, h[16] in regs; local chunk scan ---------
__global__ __launch_bounds__(384) void k_scanA(const float* __restrict__ dt,
                                               const float* __restrict__ xs,
                                               const float* __restrict__ dbl,
                                               const float* __restrict__ A_log,
                                               float* __restrict__ Hloc,
                                               float* __restrict__ Sbuf) {
  __shared__ float Bsh[CSZ][16];
  int tid = threadIdx.x;
  int blk = blockIdx.x;          // b*NCHUNK + chunk
  int b = blk >> 7;
  int chunk = blk & (NCHUNK - 1);
  int l0 = chunk * CSZ;
  for (int idx = tid; idx < CSZ * 16; idx += 384) {
    int r = idx >> 4, n = idx & 15;
    Bsh[r][n] = dbl[((size_t)b * L_ + l0 + r) * NDBL + DTR + n];
  }
  int d = tid;
  float An[16];
#pragma unroll
  for (int n = 0; n < 16; ++n) An[n] = -__expf(A_log[d * 16 + n]);
  float h[16];
#pragma unroll
  for (int n = 0; n < 16; ++n) h[n] = 0.f;
  const float* dtp = dt + ((size_t)b * L_ + l0) * DI + d;
  const float* xp = xs + ((size_t)b * L_ + l0) * DI + d;
  float S = 0.f;
  __syncthreads();
  float dtn = dtp[0], xn = xp[0];
  for (int i = 0; i < CSZ; ++i) {
    float dtv = dtn, xv = xn;
    if (i + 1 < CSZ) { dtn = dtp[(size_t)(i + 1) * DI]; xn = xp[(size_t)(i + 1) * DI]; }
    float dtx = dtv * xv;
    float Bv[16];
    *(float4*)&Bv[0]  = *(const float4*)&Bsh[i][0];
    *(float4*)&Bv[4]  = *(const float4*)&Bsh[i][4];
    *(float4*)&Bv[8]  = *(const float4*)&Bsh[i][8];
    *(float4*)&Bv[12] = *(const float4*)&Bsh[i][12];
#pragma unroll
    for (int n = 0; n < 16; ++n) {
      float dA = __expf(dtv * An[n]);
      h[n] = fmaf(dA, h[n], dtx * Bv[n]);
    }
    S += dtv;
  }
  size_t base = (((size_t)b * NCHUNK + chunk) * DI + d) * 16;
  *(float4*)&Hloc[base + 0]  = make_float4(h[0], h[1], h[2], h[3]);
  *(float4*)&Hloc[base + 4]  = make_float4(h[4], h[5], h[6], h[7]);
  *(float4*)&Hloc[base + 8]  = make_float4(h[8], h[9], h[10], h[11]);
  *(float4*)&Hloc[base + 12] = make_float4(h[12], h[13], h[14], h[15]);
  Sbuf[((size_t)b * NCHUNK + chunk) * DI + d] = S;
}

// ---------------- scan pass B: chunk recurrence, IN-PLACE (Hloc -> carry-in) ---------
__global__ __launch_bounds__(256) void k_scanB(const float* __restrict__ A_log,
                                               float* __restrict__ Hloc,
                                               const float* __restrict__ Sbuf) {
  int gid = blockIdx.x * 256 + threadIdx.x;   // B*DI*16 = 24576
  int n = gid & 15;
  int rest = gid >> 4;
  int d = rest % DI;
  int b = rest / DI;
  float An = -__expf(A_log[d * 16 + n]);
  float h = 0.f;
  for (int c = 0; c < NCHUNK; ++c) {
    size_t idx = (((size_t)b * NCHUNK + c) * DI + d) * 16 + n;
    float Hl = Hloc[idx];
    float S = Sbuf[((size_t)b * NCHUNK + c) * DI + d];
    Hloc[idx] = h;                 // overwrite local state with carry-in
    h = fmaf(__expf(An * S), h, Hl);
  }
}

// ---------------- scan pass C: local scan w/ carry, fused y + gating -----------------
__global__ __launch_bounds__(384) void k_scanC(const float* __restrict__ dt,
                                               const float* __restrict__ xs,
                                               const float* __restrict__ dbl,
                                               const float* __restrict__ z,
                                               const float* __restrict__ A_log,
                                               const float* __restrict__ Dw,
                                               const float* __restrict__ Hloc,
                                               float* __restrict__ ybuf) {
  __shared__ float Bsh[CSZ][16];
  __shared__ float Csh[CSZ][16];
  int tid = threadIdx.x;
  int blk = blockIdx.x;
  int b = blk >> 7;
  int chunk = blk & (NCHUNK - 1);
  int l0 = chunk * CSZ;
  for (int idx = tid; idx < CSZ * 32; idx += 384) {
    int r = idx >> 5, n32 = idx & 31;
    float v = dbl[((size_t)b * L_ + l0 + r) * NDBL + DTR + n32];
    if (n32 < 16) Bsh[r][n32] = v; else Csh[r][n32 - 16] = v;
  }
  int d = tid;
  float An[16];
#pragma unroll
  for (int n = 0; n < 16; ++n) An[n] = -__expf(A_log[d * 16 + n]);
  float Dd = Dw[d];
  size_t base = (((size_t)b * NCHUNK + chunk) * DI + d) * 16;
  float h[16];
  {
    float4 h0 = *(const float4*)&Hloc[base + 0];
    float4 h1 = *(const float4*)&Hloc[base + 4];
    float4 h2 = *(const float4*)&Hloc[base + 8];
    float4 h3 = *(const float4*)&Hloc[base + 12];
    h[0] = h0.x; h[1] = h0.y; h[2] = h0.z; h[3] = h0.w;
    h[4] = h1.x; h[5] = h1.y; h[6] = h1.z; h[7] = h1.w;
    h[8] = h2.x; h[9] = h2.y; h[10] = h2.z; h[11] = h2.w;
    h[12] = h3.x; h[13] = h3.y; h[14] = h3.z; h[15] = h3.w;
  }
  const float* dtp = dt + ((size_t)b * L_ + l0) * DI + d;
  const float* xp = xs + ((size_t)b * L_ + l0) * DI + d;
  const float* zp = z + ((size_t)b * L_ + l0) * DI + d;
  float* yp = ybuf + ((size_t)b * L_ + l0) * DI + d;
  __syncthreads();
  float dtn = dtp[0], xn = xp[0], zn = zp[0];
  for (int i = 0; i < CSZ; ++i) {
    float dtv = dtn, xv = xn, zv = zn;
    if (i + 1 < CSZ) {
      dtn = dtp[(size_t)(i + 1) * DI];
      xn = xp[(size_t)(i + 1) * DI];
      zn = zp[(size_t)(i + 1) * DI];
    }
    float dtx = dtv * xv;
    float Bv[16], Cv[16];
    *(float4*)&Bv[0]  = *(const float4*)&Bsh[i][0];
    *(float4*)&Bv[4]  = *(const float4*)&Bsh[i][4];
    *(float4*)&Bv[8]  = *(const float4*)&Bsh[i][8];
    *(float4*)&Bv[12] = *(const float4*)&Bsh[i][12];
    *(float4*)&Cv[0]  = *(const float4*)&Csh[i][0];
    *(float4*)&Cv[4]  = *(const float4*)&Csh[i][4];
    *(float4*)&Cv[8]  = *(const float4*)&Csh[i][8];
    *(float4*)&Cv[12] = *(const float4*)&Csh[i][12];
    float y = 0.f;
#pragma unroll
    for (int n = 0; n < 16; ++n) {
      float dA = __expf(dtv * An[n]);
      h[n] = fmaf(dA, h[n], dtx * Bv[n]);
      y = fmaf(h[n], Cv[n], y);
    }
    y = fmaf(xv, Dd, y);
    float sig = 1.f / (1.f + __expf(-zv));
    yp[(size_t)i * DI] = y * (zv * sig);
  }
}

// ---------------- out_proj: y(BL,384) @ W(192,384)^T + x -> out(B,C,L) ---------------
__global__ __launch_bounds__(256) void k_outproj(const float* __restrict__ A,
                                                 const float* __restrict__ Wt,
                                                 const float* __restrict__ x,
                                                 float* __restrict__ out) {
  __shared__ float As[32][68];
  __shared__ float Bs[32][68];
  __shared__ float ct[64][65];
  int tid = threadIdx.x;
  int m0 = blockIdx.x << 6;
  int n0 = blockIdx.y << 6;
  int r = tid >> 2;
  int kq = (tid & 3) << 3;
  int tx = tid & 15, ty = tid >> 4;
  float acc[4][4] = {{0.f}};
  for (int k0 = 0; k0 < 384; k0 += 32) {
    __syncthreads();
    const float* ap = A + (size_t)(m0 + r) * 384 + k0 + kq;
    float4 a0 = *(const float4*)ap;
    float4 a1 = *(const float4*)(ap + 4);
    const float* bp = Wt + (size_t)(n0 + r) * 384 + k0 + kq;
    float4 b0 = *(const float4*)bp;
    float4 b1 = *(const float4*)(bp + 4);
    As[kq + 0][r] = a0.x; As[kq + 1][r] = a0.y; As[kq + 2][r] = a0.z; As[kq + 3][r] = a0.w;
    As[kq + 4][r] = a1.x; As[kq + 5][r] = a1.y; As[kq + 6][r] = a1.z; As[kq + 7][r] = a1.w;
    Bs[kq + 0][r] = b0.x; Bs[kq + 1][r] = b0.y; Bs[kq + 2][r] = b0.z; Bs[kq + 3][r] = b0.w;
    Bs[kq + 4][r] = b1.x; Bs[kq + 5][r] = b1.y; Bs[kq + 6][r] = b1.z; Bs[kq + 7][r] = b1.w;
    __syncthreads();
#pragma unroll
    for (int k = 0; k < 32; ++k) {
      float4 av = *(const float4*)&As[k][ty << 2];
      float4 bv = *(const float4*)&Bs[k][tx << 2];
      float a4[4] = {av.x, av.y, av.z, av.w};
      float b4[4] = {bv.x, bv.y, bv.z, bv.w};
#pragma unroll
      for (int i = 0; i < 4; ++i)
#pragma unroll
        for (int j = 0; j < 4; ++j) acc[i][j] = fmaf(a4[i], b4[j], acc[i][j]);
    }
  }
  __syncthreads();
#pragma unroll
  for (int i = 0; i < 4; ++i)
#pragma unroll
    for (int j = 0; j < 4; ++j) ct[(ty << 2) + i][(tx << 2) + j] = acc[i][j];
  __syncthreads();
  int b = m0 >> 12;
  int lb = m0 & (L_ - 1);
  for (int idx = tid; idx < 64 * 16; idx += 256) {
    int cc = idx >> 4;
    int q = idx & 15;
    int c = n0 + cc;
    size_t off = ((size_t)b * C_ + c) * L_ + lb + (q << 2);
    float4 xv = *(const float4*)&x[off];
    float4 v;
    v.x = ct[(q << 2) + 0][cc] + xv.x;
    v.y = ct[(q << 2) + 1][cc] + xv.y;
    v.z = ct[(q << 2) + 2][cc] + xv.z;
    v.w = ct[(q << 2) + 3][cc] + xv.w;
    *(float4*)&out[off] = v;
  }
}

extern "C" void kernel_launch(void* const* d_in, const int* in_sizes, int n_in,
                              void* d_out, int out_size, void* d_ws, size_t ws_size,
                              hipStream_t stream) {
  const float* x         = (const float*)d_in[0];
  const float* norm_w    = (const float*)d_in[1];
  const float* norm_b    = (const float*)d_in[2];
  const float* in_proj_w = (const float*)d_in[3];
  const float* conv_w    = (const float*)d_in[4];
  const float* conv_b    = (const float*)d_in[5];
  const float* x_proj_w  = (const float*)d_in[6];
  const float* dt_proj_w = (const float*)d_in[7];
  const float* dt_proj_b = (const float*)d_in[8];
  const float* A_log     = (const float*)d_in[9];
  const float* Dw        = (const float*)d_in[10];
  const float* out_proj_w= (const float*)d_in[11];
  float* out = (float*)d_out;
  float* ws = (float*)d_ws;

  float* seqn = ws + OFF_SEQN;
  float* xin  = ws + OFF_XIN;
  float* z    = ws + OFF_Z;
  float* xs   = ws + OFF_XS;
  float* dbl  = ws + OFF_DBL;
  float* dt   = ws + OFF_DT;
  float* Sbuf = ws + OFF_SBUF;
  float* Hloc = seqn;  // seqn dead after in_proj; exactly B*NCHUNK*DI*16 floats
  float* ybuf = xin;   // xin dead after conv

  hipLaunchKernelGGL(k_ln, dim3(256), dim3(256), 0, stream, x, norm_w, norm_b, seqn);
  hipLaunchKernelGGL(k_inproj, dim3(256, 12), dim3(256), 0, stream, seqn, in_proj_w, xin, z);
  hipLaunchKernelGGL(k_conv, dim3(6, 64, 4), dim3(256), 0, stream, xin, conv_w, conv_b, xs);
  hipLaunchKernelGGL(k_xproj, dim3(256), dim3(256), 0, stream, xs, x_proj_w, dbl);
  hipLaunchKernelGGL(k_dtproj, dim3(256), dim3(384), 0, stream, dbl, dt_proj_w, dt_proj_b, dt);
  hipLaunchKernelGGL(k_scanA, dim3(512), dim3(384), 0, stream, dt, xs, dbl, A_log, Hloc, Sbuf);
  hipLaunchKernelGGL(k_scanB, dim3(96), dim3(256), 0, stream, A_log, Hloc, Sbuf);
  hipLaunchKernelGGL(k_scanC, dim3(512), dim3(384), 0, stream, dt, xs, dbl, z, A_log, Dw, Hloc,
                     ybuf);
  hipLaunchKernelGGL(k_outproj, dim3(256, 3), dim3(256), 0, stream, ybuf, out_proj_w, x, out);
}

// Round 3
// 174.375 us; speedup vs baseline: 2.8597x; 1.5580x over previous
//
#include <hip/hip_runtime.h>
#include <hip/hip_bf16.h>

// Problem constants
constexpr int B_ = 4;
constexpr int C_ = 192;
constexpr int L_ = 4096;     // H*W
constexpr int DI = 384;      // d_inner
constexpr int DSs = 16;      // d_state
constexpr int DTR = 12;      // dt_rank
constexpr int NDBL = 44;     // dt_rank + 2*d_state
constexpr int NCHUNK = 128;  // scan chunks
constexpr int CSZ = 32;      // chunk size

constexpr size_t BL = (size_t)B_ * L_;  // 16384

// Workspace offsets in FLOAT units (bf16 buffers counted at half)
constexpr size_t F_SEQN = 0;                                  // bf16 BL*C
constexpr size_t F_XIN  = F_SEQN + BL * C_ / 2;               // bf16 BL*DI (reused as ybuf)
constexpr size_t F_Z    = F_XIN + BL * DI / 2;                // bf16 BL*DI
constexpr size_t F_XS   = F_Z + BL * DI / 2;                  // f32  BL*DI
constexpr size_t F_XSB  = F_XS + BL * DI;                     // bf16 BL*DI
constexpr size_t F_DBL  = F_XSB + BL * DI / 2;                // f32  BL*NDBL
constexpr size_t F_DT   = F_DBL + BL * NDBL;                  // f32  BL*DI
constexpr size_t F_SBUF = F_DT + BL * DI;                     // f32  B*NCHUNK*DI
constexpr size_t F_HLOC = F_SBUF + (size_t)B_ * NCHUNK * DI;  // f32  B*NCHUNK*DI*16
constexpr size_t F_WBUF = F_HLOC + (size_t)B_ * NCHUNK * DI * 16;  // bf16 weights
// wbuf: inproj 147456 + xproj(48x384 padded) 18432 + outproj 73728 = 239616 ushorts
// total ~= 111 MB (< previously used 129 MB)

typedef __attribute__((ext_vector_type(8))) short bf16x8;
typedef __attribute__((ext_vector_type(4))) float f32x4;

__device__ __forceinline__ unsigned short f2bf(float v) {
  unsigned x = __builtin_bit_cast(unsigned, v);
  unsigned r = x + 0x7FFFu + ((x >> 16) & 1u);   // RNE
  return (unsigned short)(r >> 16);
}
__device__ __forceinline__ float bf2f(unsigned short u) {
  return __builtin_bit_cast(float, (unsigned)u << 16);
}
__device__ __forceinline__ void gload16(const void* g, void* l) {
  __builtin_amdgcn_global_load_lds((const __attribute__((address_space(1))) void*)g,
                                   (__attribute__((address_space(3))) void*)l, 16, 0, 0);
}
#define MFMA16(a, b, c) __builtin_amdgcn_mfma_f32_16x16x32_bf16(a, b, c, 0, 0, 0)

// ---------------- weight convert: f32 -> bf16 (xproj zero-padded to 48 rows) ---------
__global__ __launch_bounds__(256) void k_cvtw(const float* __restrict__ ipw,
                                              const float* __restrict__ xpw,
                                              const float* __restrict__ opw,
                                              unsigned short* __restrict__ wbuf) {
  int t = blockIdx.x * 256 + threadIdx.x;
  if (t >= 239616) return;
  float v;
  if (t < 147456) v = ipw[t];
  else if (t < 165888) {
    int j = t - 147456;
    int r = j / 384, c = j - r * 384;
    v = (r < 44) ? xpw[r * 384 + c] : 0.f;
  } else v = opw[t - 165888];
  wbuf[t] = f2bf(v);
}

// ---------------- LayerNorm over C per (b,l), x(B,C,L) -> seqn(B,L,C) bf16 -----------
__global__ __launch_bounds__(256) void k_ln(const float* __restrict__ x,
                                            const float* __restrict__ nw,
                                            const float* __restrict__ nb,
                                            unsigned short* __restrict__ seqn) {
  __shared__ float xt[192][65];
  __shared__ float ps[4][64], ps2[4][64];
  __shared__ float mu_[64], rs_[64];
  __shared__ float wsh[192], bsh[192];
  int tid = threadIdx.x;
  int blk = blockIdx.x;
  int b = blk >> 6;
  int l0 = (blk & 63) << 6;
  const float* xb = x + (size_t)b * C_ * L_;
  for (int idx = tid; idx < 192 * 64; idx += 256) {
    int c = idx >> 6, ll = idx & 63;
    xt[c][ll] = xb[(size_t)c * L_ + l0 + ll];
  }
  if (tid < 192) { wsh[tid] = nw[tid]; bsh[tid] = nb[tid]; }
  __syncthreads();
  int ll = tid & 63, q = tid >> 6;
  float s = 0.f, ss = 0.f;
  for (int c = q * 48; c < q * 48 + 48; ++c) { float v = xt[c][ll]; s += v; ss += v * v; }
  ps[q][ll] = s; ps2[q][ll] = ss;
  __syncthreads();
  if (q == 0) {
    float st = ps[0][ll] + ps[1][ll] + ps[2][ll] + ps[3][ll];
    float sst = ps2[0][ll] + ps2[1][ll] + ps2[2][ll] + ps2[3][ll];
    float mu = st * (1.f / 192.f);
    float var = sst * (1.f / 192.f) - mu * mu;
    mu_[ll] = mu; rs_[ll] = rsqrtf(var + 1e-5f);
  }
  __syncthreads();
  unsigned short* so = seqn + ((size_t)b * L_ + l0) * C_;
  for (int idx = tid; idx < 64 * 192; idx += 256) {
    int l = idx / 192, c = idx - l * 192;
    so[idx] = f2bf((xt[c][l] - mu_[l]) * rs_[l] * wsh[c] + bsh[c]);
  }
}

// ---------------- in_proj MFMA: seqn(BL,192)bf16 @ W(768,192)^T -> xin,z bf16 --------
__global__ __launch_bounds__(256) void k_inproj(const unsigned short* __restrict__ A,
                                                const unsigned short* __restrict__ W,
                                                unsigned short* __restrict__ xin,
                                                unsigned short* __restrict__ z) {
  __shared__ unsigned short smem[16384];  // As[0:8192] 128x64, Bs[8192:] 128x64; out tile reuse
  unsigned short* As = smem;
  unsigned short* Bs = smem + 8192;
  int tid = threadIdx.x;
  int w = tid >> 6, l = tid & 63;
  int wr = w >> 1, wc = w & 1;
  int m0 = blockIdx.x << 7;
  int n0 = blockIdx.y << 7;
  f32x4 acc[4][4];
#pragma unroll
  for (int i = 0; i < 4; ++i)
#pragma unroll
    for (int j = 0; j < 4; ++j) acc[i][j] = (f32x4){0.f, 0.f, 0.f, 0.f};
  int lr = l & 15, lk = l >> 4;
  for (int kt = 0; kt < 3; ++kt) {
    int k0 = kt * 64;
    if (kt) __syncthreads();
#pragma unroll
    for (int i = 0; i < 4; ++i) {
      int row = (i << 5) + (tid >> 3);
      int gc = k0 + (((tid & 7) ^ (row & 7)) << 3);
      gload16(A + (size_t)(m0 + row) * 192 + gc, &As[(i << 11) + (w << 9)]);
      gload16(W + (size_t)(n0 + row) * 192 + gc, &Bs[(i << 11) + (w << 9)]);
    }
    __syncthreads();
#pragma unroll
    for (int ks = 0; ks < 2; ++ks) {
      int s = (ks << 2) + lk;
      bf16x8 af[4], bfr[4];
#pragma unroll
      for (int mi = 0; mi < 4; ++mi) {
        int r = (wr << 6) + (mi << 4) + lr;
        af[mi] = *(const bf16x8*)&As[r * 64 + ((s ^ (r & 7)) << 3)];
      }
#pragma unroll
      for (int ni = 0; ni < 4; ++ni) {
        int r = (wc << 6) + (ni << 4) + lr;
        bfr[ni] = *(const bf16x8*)&Bs[r * 64 + ((s ^ (r & 7)) << 3)];
      }
#pragma unroll
      for (int mi = 0; mi < 4; ++mi)
#pragma unroll
        for (int ni = 0; ni < 4; ++ni) acc[mi][ni] = MFMA16(af[mi], bfr[ni], acc[mi][ni]);
    }
  }
  __syncthreads();
#pragma unroll
  for (int mi = 0; mi < 4; ++mi)
#pragma unroll
    for (int ni = 0; ni < 4; ++ni) {
      int col = (wc << 6) + (ni << 4) + lr;
#pragma unroll
      for (int r = 0; r < 4; ++r) {
        int row = (wr << 6) + (mi << 4) + (lk << 2) + r;
        smem[(row << 7) + col] = f2bf(acc[mi][ni][r]);
      }
    }
  __syncthreads();
#pragma unroll
  for (int i = 0; i < 8; ++i) {
    int chunk = i * 256 + tid;
    int row = chunk >> 4, cq = chunk & 15;
    int n = n0 + (cq << 3);
    unsigned short* dst = (n < 384) ? (xin + (size_t)(m0 + row) * DI + n)
                                    : (z + (size_t)(m0 + row) * DI + (n - 384));
    *(bf16x8*)dst = *(const bf16x8*)&smem[(row << 7) + (cq << 3)];
  }
}

// ---------------- conv(4) causal + SiLU: xin bf16 -> xs f32 + xsb bf16 ---------------
__global__ __launch_bounds__(256) void k_conv(const unsigned short* __restrict__ xin,
                                              const float* __restrict__ cw,
                                              const float* __restrict__ cb,
                                              float* __restrict__ xs,
                                              unsigned short* __restrict__ xsb) {
  __shared__ float xt[67][64];
  __shared__ float res[64][65];
  int tid = threadIdx.x;
  int d0 = blockIdx.x << 6;
  int l0 = blockIdx.y << 6;
  int b = blockIdx.z;
  for (int idx = tid; idx < 67 * 16; idx += 256) {
    int rr = idx >> 4, q = idx & 15;
    int l = l0 - 3 + rr;
    float4 v = make_float4(0.f, 0.f, 0.f, 0.f);
    if (l >= 0) {
      ushort4 u = *(const ushort4*)&xin[((size_t)b * L_ + l) * DI + d0 + (q << 2)];
      v = make_float4(bf2f(u.x), bf2f(u.y), bf2f(u.z), bf2f(u.w));
    }
    *(float4*)&xt[rr][q << 2] = v;
  }
  __syncthreads();
  int dd = tid & 63, lq = tid >> 6;
  float4 w4 = *(const float4*)&cw[(d0 + dd) * 4];
  float bb = cb[d0 + dd];
  for (int rr = 0; rr < 16; ++rr) {
    int ll = (rr << 2) + lq;
    float a = bb + w4.x * xt[ll][dd] + w4.y * xt[ll + 1][dd] + w4.z * xt[ll + 2][dd] +
              w4.w * xt[ll + 3][dd];
    res[ll][dd] = a / (1.f + __expf(-a));
  }
  __syncthreads();
  for (int idx = tid; idx < 64 * 16; idx += 256) {
    int ll = idx >> 4, q = idx & 15;
    float4 v = make_float4(res[ll][(q << 2)], res[ll][(q << 2) + 1], res[ll][(q << 2) + 2],
                           res[ll][(q << 2) + 3]);
    size_t off = ((size_t)b * L_ + l0 + ll) * DI + d0 + (q << 2);
    *(float4*)&xs[off] = v;
    ushort4 u;
    u.x = f2bf(v.x); u.y = f2bf(v.y); u.z = f2bf(v.z); u.w = f2bf(v.w);
    *(ushort4*)&xsb[off] = u;
  }
}

// ---------------- x_proj MFMA: xsb(BL,384) @ Wp(48,384)^T -> dbl f32 (cols<44) -------
__global__ __launch_bounds__(256) void k_xproj(const unsigned short* __restrict__ A,
                                               const unsigned short* __restrict__ W,
                                               float* __restrict__ dbl) {
  __shared__ unsigned short smem[4096 + 3072];  // As 64x64, Bs 48x64
  unsigned short* As = smem;
  unsigned short* Bs = smem + 4096;
  int tid = threadIdx.x;
  int w = tid >> 6, l = tid & 63;
  int m0 = blockIdx.x << 6;
  int lr = l & 15, lk = l >> 4;
  f32x4 acc[3];
#pragma unroll
  for (int i = 0; i < 3; ++i) acc[i] = (f32x4){0.f, 0.f, 0.f, 0.f};
  for (int kt = 0; kt < 6; ++kt) {
    int k0 = kt * 64;
    if (kt) __syncthreads();
#pragma unroll
    for (int i = 0; i < 2; ++i) {
      int row = (i << 5) + (tid >> 3);
      int gc = k0 + (((tid & 7) ^ (row & 7)) << 3);
      gload16(A + (size_t)(m0 + row) * 384 + gc, &As[(i << 11) + (w << 9)]);
    }
    {
      int row = tid >> 3;
      int gc = k0 + (((tid & 7) ^ (row & 7)) << 3);
      gload16(W + (size_t)row * 384 + gc, &Bs[w << 9]);
    }
    if (w < 2) {
      int row = 32 + (tid >> 3);
      int gc = k0 + (((tid & 7) ^ (row & 7)) << 3);
      gload16(W + (size_t)row * 384 + gc, &Bs[2048 + (w << 9)]);
    }
    __syncthreads();
#pragma unroll
    for (int ks = 0; ks < 2; ++ks) {
      int s = (ks << 2) + lk;
      int ar = (w << 4) + lr;
      bf16x8 a = *(const bf16x8*)&As[ar * 64 + ((s ^ (ar & 7)) << 3)];
#pragma unroll
      for (int ni = 0; ni < 3; ++ni) {
        int br = (ni << 4) + lr;
        bf16x8 bb = *(const bf16x8*)&Bs[br * 64 + ((s ^ (br & 7)) << 3)];
        acc[ni] = MFMA16(a, bb, acc[ni]);
      }
    }
  }
#pragma unroll
  for (int ni = 0; ni < 3; ++ni)
#pragma unroll
    for (int r = 0; r < 4; ++r) {
      int col = (ni << 4) + lr;
      if (col < NDBL) dbl[(size_t)(m0 + (w << 4) + (lk << 2) + r) * NDBL + col] = acc[ni][r];
    }
}

// ---------------- dt_proj + softplus -> dt(B,L,DI) f32 -------------------------------
__global__ __launch_bounds__(384) void k_dtproj(const float* __restrict__ dbl,
                                                const float* __restrict__ dw,
                                                const float* __restrict__ db,
                                                float* __restrict__ dt) {
  __shared__ float dl[64][12];
  int tid = threadIdx.x;
  int row0 = blockIdx.x << 6;
  for (int idx = tid; idx < 64 * 12; idx += 384) {
    int r = idx / 12, k = idx - r * 12;
    dl[r][k] = dbl[(size_t)(row0 + r) * NDBL + k];
  }
  float w[12];
#pragma unroll
  for (int k = 0; k < 12; ++k) w[k] = dw[tid * 12 + k];
  float bias = db[tid];
  __syncthreads();
  for (int r = 0; r < 64; ++r) {
    float acc = bias;
#pragma unroll
    for (int k = 0; k < 12; ++k) acc = fmaf(w[k], dl[r][k], acc);
    float sp = fmaxf(acc, 0.f) + log1pf(__expf(-fabsf(acc)));
    dt[(size_t)(row0 + r) * DI + tid] = sp;
  }
}

// ---------------- scan pass A ---------------------------------------------------------
__global__ __launch_bounds__(384) void k_scanA(const float* __restrict__ dt,
                                               const float* __restrict__ xs,
                                               const float* __restrict__ dbl,
                                               const float* __restrict__ A_log,
                                               float* __restrict__ Hloc,
                                               float* __restrict__ Sbuf) {
  __shared__ float Bsh[CSZ][16];
  int tid = threadIdx.x;
  int blk = blockIdx.x;
  int b = blk >> 7;
  int chunk = blk & (NCHUNK - 1);
  int l0 = chunk * CSZ;
  for (int idx = tid; idx < CSZ * 16; idx += 384) {
    int r = idx >> 4, n = idx & 15;
    Bsh[r][n] = dbl[((size_t)b * L_ + l0 + r) * NDBL + DTR + n];
  }
  int d = tid;
  float An[16];
#pragma unroll
  for (int n = 0; n < 16; ++n) An[n] = -__expf(A_log[d * 16 + n]);
  float h[16];
#pragma unroll
  for (int n = 0; n < 16; ++n) h[n] = 0.f;
  const float* dtp = dt + ((size_t)b * L_ + l0) * DI + d;
  const float* xp = xs + ((size_t)b * L_ + l0) * DI + d;
  float S = 0.f;
  __syncthreads();
  float dtn = dtp[0], xn = xp[0];
  for (int i = 0; i < CSZ; ++i) {
    float dtv = dtn, xv = xn;
    if (i + 1 < CSZ) { dtn = dtp[(size_t)(i + 1) * DI]; xn = xp[(size_t)(i + 1) * DI]; }
    float dtx = dtv * xv;
    float Bv[16];
    *(float4*)&Bv[0]  = *(const float4*)&Bsh[i][0];
    *(float4*)&Bv[4]  = *(const float4*)&Bsh[i][4];
    *(float4*)&Bv[8]  = *(const float4*)&Bsh[i][8];
    *(float4*)&Bv[12] = *(const float4*)&Bsh[i][12];
#pragma unroll
    for (int n = 0; n < 16; ++n) {
      float dA = __expf(dtv * An[n]);
      h[n] = fmaf(dA, h[n], dtx * Bv[n]);
    }
    S += dtv;
  }
  size_t base = (((size_t)b * NCHUNK + chunk) * DI + d) * 16;
  *(float4*)&Hloc[base + 0]  = make_float4(h[0], h[1], h[2], h[3]);
  *(float4*)&Hloc[base + 4]  = make_float4(h[4], h[5], h[6], h[7]);
  *(float4*)&Hloc[base + 8]  = make_float4(h[8], h[9], h[10], h[11]);
  *(float4*)&Hloc[base + 12] = make_float4(h[12], h[13], h[14], h[15]);
  Sbuf[((size_t)b * NCHUNK + chunk) * DI + d] = S;
}

// ---------------- scan pass B: chunk recurrence in-place ------------------------------
__global__ __launch_bounds__(256) void k_scanB(const float* __restrict__ A_log,
                                               float* __restrict__ Hloc,
                                               const float* __restrict__ Sbuf) {
  int gid = blockIdx.x * 256 + threadIdx.x;
  int n = gid & 15;
  int rest = gid >> 4;
  int d = rest % DI;
  int b = rest / DI;
  float An = -__expf(A_log[d * 16 + n]);
  float h = 0.f;
  for (int c = 0; c < NCHUNK; ++c) {
    size_t idx = (((size_t)b * NCHUNK + c) * DI + d) * 16 + n;
    float Hl = Hloc[idx];
    float S = Sbuf[((size_t)b * NCHUNK + c) * DI + d];
    Hloc[idx] = h;
    h = fmaf(__expf(An * S), h, Hl);
  }
}

// ---------------- scan pass C: local scan + carry, fused y/gating, bf16 out ----------
__global__ __launch_bounds__(384) void k_scanC(const float* __restrict__ dt,
                                               const float* __restrict__ xs,
                                               const float* __restrict__ dbl,
                                               const unsigned short* __restrict__ z,
                                               const float* __restrict__ A_log,
                                               const float* __restrict__ Dw,
                                               const float* __restrict__ Hloc,
                                               unsigned short* __restrict__ ybuf) {
  __shared__ float Bsh[CSZ][16];
  __shared__ float Csh[CSZ][16];
  int tid = threadIdx.x;
  int blk = blockIdx.x;
  int b = blk >> 7;
  int chunk = blk & (NCHUNK - 1);
  int l0 = chunk * CSZ;
  for (int idx = tid; idx < CSZ * 32; idx += 384) {
    int r = idx >> 5, n32 = idx & 31;
    float v = dbl[((size_t)b * L_ + l0 + r) * NDBL + DTR + n32];
    if (n32 < 16) Bsh[r][n32] = v; else Csh[r][n32 - 16] = v;
  }
  int d = tid;
  float An[16];
#pragma unroll
  for (int n = 0; n < 16; ++n) An[n] = -__expf(A_log[d * 16 + n]);
  float Dd = Dw[d];
  size_t base = (((size_t)b * NCHUNK + chunk) * DI + d) * 16;
  float h[16];
  {
    float4 h0 = *(const float4*)&Hloc[base + 0];
    float4 h1 = *(const float4*)&Hloc[base + 4];
    float4 h2 = *(const float4*)&Hloc[base + 8];
    float4 h3 = *(const float4*)&Hloc[base + 12];
    h[0] = h0.x; h[1] = h0.y; h[2] = h0.z; h[3] = h0.w;
    h[4] = h1.x; h[5] = h1.y; h[6] = h1.z; h[7] = h1.w;
    h[8] = h2.x; h[9] = h2.y; h[10] = h2.z; h[11] = h2.w;
    h[12] = h3.x; h[13] = h3.y; h[14] = h3.z; h[15] = h3.w;
  }
  const float* dtp = dt + ((size_t)b * L_ + l0) * DI + d;
  const float* xp = xs + ((size_t)b * L_ + l0) * DI + d;
  const unsigned short* zp = z + ((size_t)b * L_ + l0) * DI + d;
  unsigned short* yp = ybuf + ((size_t)b * L_ + l0) * DI + d;
  __syncthreads();
  float dtn = dtp[0], xn = xp[0];
  unsigned short zn = zp[0];
  for (int i = 0; i < CSZ; ++i) {
    float dtv = dtn, xv = xn;
    float zv = bf2f(zn);
    if (i + 1 < CSZ) {
      dtn = dtp[(size_t)(i + 1) * DI];
      xn = xp[(size_t)(i + 1) * DI];
      zn = zp[(size_t)(i + 1) * DI];
    }
    float dtx = dtv * xv;
    float Bv[16], Cv[16];
    *(float4*)&Bv[0]  = *(const float4*)&Bsh[i][0];
    *(float4*)&Bv[4]  = *(const float4*)&Bsh[i][4];
    *(float4*)&Bv[8]  = *(const float4*)&Bsh[i][8];
    *(float4*)&Bv[12] = *(const float4*)&Bsh[i][12];
    *(float4*)&Cv[0]  = *(const float4*)&Csh[i][0];
    *(float4*)&Cv[4]  = *(const float4*)&Csh[i][4];
    *(float4*)&Cv[8]  = *(const float4*)&Csh[i][8];
    *(float4*)&Cv[12] = *(const float4*)&Csh[i][12];
    float y = 0.f;
#pragma unroll
    for (int n = 0; n < 16; ++n) {
      float dA = __expf(dtv * An[n]);
      h[n] = fmaf(dA, h[n], dtx * Bv[n]);
      y = fmaf(h[n], Cv[n], y);
    }
    y = fmaf(xv, Dd, y);
    float sig = 1.f / (1.f + __expf(-zv));
    yp[(size_t)i * DI] = f2bf(y * (zv * sig));
  }
}

// ---------------- out_proj MFMA + residual: ybuf(BL,384) @ W(192,384)^T + x ----------
__global__ __launch_bounds__(256) void k_outproj(const unsigned short* __restrict__ Y,
                                                 const unsigned short* __restrict__ W,
                                                 const float* __restrict__ x,
                                                 float* __restrict__ out) {
  __shared__ float smemf[8448];  // staging: As 128x64 + Bs 64x64 bf16 (24KB); epi: [64][132] f32
  unsigned short* As = (unsigned short*)smemf;
  unsigned short* Bs = (unsigned short*)smemf + 8192;
  int tid = threadIdx.x;
  int w = tid >> 6, l = tid & 63;
  int wr = w >> 1, wc = w & 1;
  int m0 = blockIdx.x << 7;
  int n0 = blockIdx.y << 6;
  int lr = l & 15, lk = l >> 4;
  f32x4 acc[4][2];
#pragma unroll
  for (int i = 0; i < 4; ++i)
#pragma unroll
    for (int j = 0; j < 2; ++j) acc[i][j] = (f32x4){0.f, 0.f, 0.f, 0.f};
  for (int kt = 0; kt < 6; ++kt) {
    int k0 = kt * 64;
    if (kt) __syncthreads();
#pragma unroll
    for (int i = 0; i < 4; ++i) {
      int row = (i << 5) + (tid >> 3);
      int gc = k0 + (((tid & 7) ^ (row & 7)) << 3);
      gload16(Y + (size_t)(m0 + row) * 384 + gc, &As[(i << 11) + (w << 9)]);
    }
#pragma unroll
    for (int i = 0; i < 2; ++i) {
      int row = (i << 5) + (tid >> 3);
      int gc = k0 + (((tid & 7) ^ (row & 7)) << 3);
      gload16(W + (size_t)(n0 + row) * 384 + gc, &Bs[(i << 11) + (w << 9)]);
    }
    __syncthreads();
#pragma unroll
    for (int ks = 0; ks < 2; ++ks) {
      int s = (ks << 2) + lk;
      bf16x8 bfr[2];
#pragma unroll
      for (int ni = 0; ni < 2; ++ni) {
        int r = (wc << 5) + (ni << 4) + lr;
        bfr[ni] = *(const bf16x8*)&Bs[r * 64 + ((s ^ (r & 7)) << 3)];
      }
#pragma unroll
      for (int mi = 0; mi < 4; ++mi) {
        int r = (wr << 6) + (mi << 4) + lr;
        bf16x8 a = *(const bf16x8*)&As[r * 64 + ((s ^ (r & 7)) << 3)];
#pragma unroll
        for (int ni = 0; ni < 2; ++ni) acc[mi][ni] = MFMA16(a, bfr[ni], acc[mi][ni]);
      }
    }
  }
  __syncthreads();
#pragma unroll
  for (int mi = 0; mi < 4; ++mi)
#pragma unroll
    for (int ni = 0; ni < 2; ++ni) {
      int c = (wc << 5) + (ni << 4) + lr;
      int lrow = (wr << 6) + (mi << 4) + (lk << 2);
      *(f32x4*)&smemf[c * 132 + lrow] = acc[mi][ni];
    }
  __syncthreads();
  int b = m0 >> 12;
  int l0 = m0 & (L_ - 1);
#pragma unroll
  for (int i = 0; i < 8; ++i) {
    int chunk = i * 256 + tid;
    int c = chunk >> 5, lq = chunk & 31;
    f32x4 v = *(const f32x4*)&smemf[c * 132 + (lq << 2)];
    size_t off = ((size_t)b * C_ + n0 + c) * L_ + l0 + (lq << 2);
    f32x4 xv = *(const f32x4*)&x[off];
    v = v + xv;
    *(f32x4*)&out[off] = v;
  }
}

extern "C" void kernel_launch(void* const* d_in, const int* in_sizes, int n_in,
                              void* d_out, int out_size, void* d_ws, size_t ws_size,
                              hipStream_t stream) {
  const float* x         = (const float*)d_in[0];
  const float* norm_w    = (const float*)d_in[1];
  const float* norm_b    = (const float*)d_in[2];
  const float* in_proj_w = (const float*)d_in[3];
  const float* conv_w    = (const float*)d_in[4];
  const float* conv_b    = (const float*)d_in[5];
  const float* x_proj_w  = (const float*)d_in[6];
  const float* dt_proj_w = (const float*)d_in[7];
  const float* dt_proj_b = (const float*)d_in[8];
  const float* A_log     = (const float*)d_in[9];
  const float* Dw        = (const float*)d_in[10];
  const float* out_proj_w= (const float*)d_in[11];
  float* out = (float*)d_out;
  float* ws = (float*)d_ws;

  unsigned short* seqn = (unsigned short*)(ws + F_SEQN);
  unsigned short* xin  = (unsigned short*)(ws + F_XIN);
  unsigned short* z    = (unsigned short*)(ws + F_Z);
  float* xs            = ws + F_XS;
  unsigned short* xsb  = (unsigned short*)(ws + F_XSB);
  float* dbl           = ws + F_DBL;
  float* dt            = ws + F_DT;
  float* Sbuf          = ws + F_SBUF;
  float* Hloc          = ws + F_HLOC;
  unsigned short* wbuf = (unsigned short*)(ws + F_WBUF);
  unsigned short* ipw  = wbuf;
  unsigned short* xpw  = wbuf + 147456;
  unsigned short* opw  = wbuf + 165888;
  unsigned short* ybuf = xin;  // xin dead after conv

  hipLaunchKernelGGL(k_cvtw, dim3(936), dim3(256), 0, stream, in_proj_w, x_proj_w, out_proj_w,
                     wbuf);
  hipLaunchKernelGGL(k_ln, dim3(256), dim3(256), 0, stream, x, norm_w, norm_b, seqn);
  hipLaunchKernelGGL(k_inproj, dim3(128, 6), dim3(256), 0, stream, seqn, ipw, xin, z);
  hipLaunchKernelGGL(k_conv, dim3(6, 64, 4), dim3(256), 0, stream, xin, conv_w, conv_b, xs, xsb);
  hipLaunchKernelGGL(k_xproj, dim3(256), dim3(256), 0, stream, xsb, xpw, dbl);
  hipLaunchKernelGGL(k_dtproj, dim3(256), dim3(384), 0, stream, dbl, dt_proj_w, dt_proj_b, dt);
  hipLaunchKernelGGL(k_scanA, dim3(512), dim3(384), 0, stream, dt, xs, dbl, A_log, Hloc, Sbuf);
  hipLaunchKernelGGL(k_scanB, dim3(96), dim3(256), 0, stream, A_log, Hloc, Sbuf);
  hipLaunchKernelGGL(k_scanC, dim3(512), dim3(384), 0, stream, dt, xs, dbl, z, A_log, Dw, Hloc,
                     ybuf);
  hipLaunchKernelGGL(k_outproj, dim3(128, 3), dim3(256), 0, stream, ybuf, opw, x, out);
}

// Round 4
// 155.590 us; speedup vs baseline: 3.2049x; 1.1207x over previous
//
#include <hip/hip_runtime.h>
#include <hip/hip_bf16.h>

// Problem constants
constexpr int B_ = 4;
constexpr int C_ = 192;
constexpr int L_ = 4096;     // H*W
constexpr int DI = 384;      // d_inner
constexpr int DSs = 16;      // d_state
constexpr int DTR = 12;      // dt_rank
constexpr int NDBL = 44;     // dt_rank + 2*d_state
constexpr int NCHUNK = 256;  // scan chunks
constexpr int CSZ = 16;      // chunk size

constexpr size_t BL = (size_t)B_ * L_;  // 16384

// Workspace offsets in FLOAT units (bf16 buffers counted at half)
constexpr size_t F_SEQN = 0;                                  // bf16 BL*C
constexpr size_t F_XIN  = F_SEQN + BL * C_ / 2;               // bf16 BL*DI (reused as ybuf)
constexpr size_t F_Z    = F_XIN + BL * DI / 2;                // bf16 BL*DI
constexpr size_t F_XSB  = F_Z + BL * DI / 2;                  // bf16 BL*DI
constexpr size_t F_DBL  = F_XSB + BL * DI / 2;                // f32  BL*NDBL
constexpr size_t F_SBUF = F_DBL + BL * NDBL;                  // f32  B*NCHUNK*DI
constexpr size_t F_HLOC = F_SBUF + (size_t)B_ * NCHUNK * DI;  // f32  B*NCHUNK*DI*16
constexpr size_t F_WBUF = F_HLOC + (size_t)B_ * NCHUNK * DI * 16;  // bf16 weights
// total ~= 74 MB (< previously used 111 MB: safe)

typedef __attribute__((ext_vector_type(8))) short bf16x8;
typedef __attribute__((ext_vector_type(4))) float f32x4;

__device__ __forceinline__ unsigned short f2bf(float v) {
  unsigned x = __builtin_bit_cast(unsigned, v);
  unsigned r = x + 0x7FFFu + ((x >> 16) & 1u);   // RNE
  return (unsigned short)(r >> 16);
}
__device__ __forceinline__ float bf2f(unsigned short u) {
  return __builtin_bit_cast(float, (unsigned)u << 16);
}
__device__ __forceinline__ void gload16(const void* g, void* l) {
  __builtin_amdgcn_global_load_lds((const __attribute__((address_space(1))) void*)g,
                                   (__attribute__((address_space(3))) void*)l, 16, 0, 0);
}
#define MFMA16(a, b, c) __builtin_amdgcn_mfma_f32_16x16x32_bf16(a, b, c, 0, 0, 0)

// ---------------- weight convert: f32 -> bf16 (xproj zero-padded to 48 rows) ---------
__global__ __launch_bounds__(256) void k_cvtw(const float* __restrict__ ipw,
                                              const float* __restrict__ xpw,
                                              const float* __restrict__ opw,
                                              unsigned short* __restrict__ wbuf) {
  int t = blockIdx.x * 256 + threadIdx.x;
  if (t >= 239616) return;
  float v;
  if (t < 147456) v = ipw[t];
  else if (t < 165888) {
    int j = t - 147456;
    int r = j / 384, c = j - r * 384;
    v = (r < 44) ? xpw[r * 384 + c] : 0.f;
  } else v = opw[t - 165888];
  wbuf[t] = f2bf(v);
}

// ---------------- LayerNorm over C per (b,l), x(B,C,L) -> seqn(B,L,C) bf16 -----------
__global__ __launch_bounds__(256) void k_ln(const float* __restrict__ x,
                                            const float* __restrict__ nw,
                                            const float* __restrict__ nb,
                                            unsigned short* __restrict__ seqn) {
  __shared__ float xt[192][65];
  __shared__ float ps[4][64], ps2[4][64];
  __shared__ float mu_[64], rs_[64];
  __shared__ float wsh[192], bsh[192];
  int tid = threadIdx.x;
  int blk = blockIdx.x;
  int b = blk >> 6;
  int l0 = (blk & 63) << 6;
  const float* xb = x + (size_t)b * C_ * L_;
  for (int idx = tid; idx < 192 * 64; idx += 256) {
    int c = idx >> 6, ll = idx & 63;
    xt[c][ll] = xb[(size_t)c * L_ + l0 + ll];
  }
  if (tid < 192) { wsh[tid] = nw[tid]; bsh[tid] = nb[tid]; }
  __syncthreads();
  int ll = tid & 63, q = tid >> 6;
  float s = 0.f, ss = 0.f;
  for (int c = q * 48; c < q * 48 + 48; ++c) { float v = xt[c][ll]; s += v; ss += v * v; }
  ps[q][ll] = s; ps2[q][ll] = ss;
  __syncthreads();
  if (q == 0) {
    float st = ps[0][ll] + ps[1][ll] + ps[2][ll] + ps[3][ll];
    float sst = ps2[0][ll] + ps2[1][ll] + ps2[2][ll] + ps2[3][ll];
    float mu = st * (1.f / 192.f);
    float var = sst * (1.f / 192.f) - mu * mu;
    mu_[ll] = mu; rs_[ll] = rsqrtf(var + 1e-5f);
  }
  __syncthreads();
  unsigned short* so = seqn + ((size_t)b * L_ + l0) * C_;
  for (int idx = tid; idx < 64 * 192; idx += 256) {
    int l = idx / 192, c = idx - l * 192;
    so[idx] = f2bf((xt[c][l] - mu_[l]) * rs_[l] * wsh[c] + bsh[c]);
  }
}

// ---------------- in_proj MFMA: seqn(BL,192)bf16 @ W(768,192)^T -> xin,z bf16 --------
__global__ __launch_bounds__(256) void k_inproj(const unsigned short* __restrict__ A,
                                                const unsigned short* __restrict__ W,
                                                unsigned short* __restrict__ xin,
                                                unsigned short* __restrict__ z) {
  __shared__ unsigned short smem[16384];
  unsigned short* As = smem;
  unsigned short* Bs = smem + 8192;
  int tid = threadIdx.x;
  int w = tid >> 6, l = tid & 63;
  int wr = w >> 1, wc = w & 1;
  int m0 = blockIdx.x << 7;
  int n0 = blockIdx.y << 7;
  f32x4 acc[4][4];
#pragma unroll
  for (int i = 0; i < 4; ++i)
#pragma unroll
    for (int j = 0; j < 4; ++j) acc[i][j] = (f32x4){0.f, 0.f, 0.f, 0.f};
  int lr = l & 15, lk = l >> 4;
  for (int kt = 0; kt < 3; ++kt) {
    int k0 = kt * 64;
    if (kt) __syncthreads();
#pragma unroll
    for (int i = 0; i < 4; ++i) {
      int row = (i << 5) + (tid >> 3);
      int gc = k0 + (((tid & 7) ^ (row & 7)) << 3);
      gload16(A + (size_t)(m0 + row) * 192 + gc, &As[(i << 11) + (w << 9)]);
      gload16(W + (size_t)(n0 + row) * 192 + gc, &Bs[(i << 11) + (w << 9)]);
    }
    __syncthreads();
#pragma unroll
    for (int ks = 0; ks < 2; ++ks) {
      int s = (ks << 2) + lk;
      bf16x8 af[4], bfr[4];
#pragma unroll
      for (int mi = 0; mi < 4; ++mi) {
        int r = (wr << 6) + (mi << 4) + lr;
        af[mi] = *(const bf16x8*)&As[r * 64 + ((s ^ (r & 7)) << 3)];
      }
#pragma unroll
      for (int ni = 0; ni < 4; ++ni) {
        int r = (wc << 6) + (ni << 4) + lr;
        bfr[ni] = *(const bf16x8*)&Bs[r * 64 + ((s ^ (r & 7)) << 3)];
      }
#pragma unroll
      for (int mi = 0; mi < 4; ++mi)
#pragma unroll
        for (int ni = 0; ni < 4; ++ni) acc[mi][ni] = MFMA16(af[mi], bfr[ni], acc[mi][ni]);
    }
  }
  __syncthreads();
#pragma unroll
  for (int mi = 0; mi < 4; ++mi)
#pragma unroll
    for (int ni = 0; ni < 4; ++ni) {
      int col = (wc << 6) + (ni << 4) + lr;
#pragma unroll
      for (int r = 0; r < 4; ++r) {
        int row = (wr << 6) + (mi << 4) + (lk << 2) + r;
        smem[(row << 7) + col] = f2bf(acc[mi][ni][r]);
      }
    }
  __syncthreads();
#pragma unroll
  for (int i = 0; i < 8; ++i) {
    int chunk = i * 256 + tid;
    int row = chunk >> 4, cq = chunk & 15;
    int n = n0 + (cq << 3);
    unsigned short* dst = (n < 384) ? (xin + (size_t)(m0 + row) * DI + n)
                                    : (z + (size_t)(m0 + row) * DI + (n - 384));
    *(bf16x8*)dst = *(const bf16x8*)&smem[(row << 7) + (cq << 3)];
  }
}

// ---------------- conv(4) causal + SiLU: xin bf16 -> xsb bf16 ------------------------
__global__ __launch_bounds__(256) void k_conv(const unsigned short* __restrict__ xin,
                                              const float* __restrict__ cw,
                                              const float* __restrict__ cb,
                                              unsigned short* __restrict__ xsb) {
  __shared__ float xt[67][64];
  __shared__ float res[64][65];
  int tid = threadIdx.x;
  int d0 = blockIdx.x << 6;
  int l0 = blockIdx.y << 6;
  int b = blockIdx.z;
  for (int idx = tid; idx < 67 * 16; idx += 256) {
    int rr = idx >> 4, q = idx & 15;
    int l = l0 - 3 + rr;
    float4 v = make_float4(0.f, 0.f, 0.f, 0.f);
    if (l >= 0) {
      ushort4 u = *(const ushort4*)&xin[((size_t)b * L_ + l) * DI + d0 + (q << 2)];
      v = make_float4(bf2f(u.x), bf2f(u.y), bf2f(u.z), bf2f(u.w));
    }
    *(float4*)&xt[rr][q << 2] = v;
  }
  __syncthreads();
  int dd = tid & 63, lq = tid >> 6;
  float4 w4 = *(const float4*)&cw[(d0 + dd) * 4];
  float bb = cb[d0 + dd];
  for (int rr = 0; rr < 16; ++rr) {
    int ll = (rr << 2) + lq;
    float a = bb + w4.x * xt[ll][dd] + w4.y * xt[ll + 1][dd] + w4.z * xt[ll + 2][dd] +
              w4.w * xt[ll + 3][dd];
    res[ll][dd] = a / (1.f + __expf(-a));
  }
  __syncthreads();
  for (int idx = tid; idx < 64 * 16; idx += 256) {
    int ll = idx >> 4, q = idx & 15;
    ushort4 u;
    u.x = f2bf(res[ll][(q << 2)]);
    u.y = f2bf(res[ll][(q << 2) + 1]);
    u.z = f2bf(res[ll][(q << 2) + 2]);
    u.w = f2bf(res[ll][(q << 2) + 3]);
    *(ushort4*)&xsb[((size_t)b * L_ + l0 + ll) * DI + d0 + (q << 2)] = u;
  }
}

// ---------------- x_proj MFMA: xsb(BL,384) @ Wp(48,384)^T -> dbl f32 (cols<44) -------
__global__ __launch_bounds__(256) void k_xproj(const unsigned short* __restrict__ A,
                                               const unsigned short* __restrict__ W,
                                               float* __restrict__ dbl) {
  __shared__ unsigned short smem[4096 + 3072];
  unsigned short* As = smem;
  unsigned short* Bs = smem + 4096;
  int tid = threadIdx.x;
  int w = tid >> 6, l = tid & 63;
  int m0 = blockIdx.x << 6;
  int lr = l & 15, lk = l >> 4;
  f32x4 acc[3];
#pragma unroll
  for (int i = 0; i < 3; ++i) acc[i] = (f32x4){0.f, 0.f, 0.f, 0.f};
  for (int kt = 0; kt < 6; ++kt) {
    int k0 = kt * 64;
    if (kt) __syncthreads();
#pragma unroll
    for (int i = 0; i < 2; ++i) {
      int row = (i << 5) + (tid >> 3);
      int gc = k0 + (((tid & 7) ^ (row & 7)) << 3);
      gload16(A + (size_t)(m0 + row) * 384 + gc, &As[(i << 11) + (w << 9)]);
    }
    {
      int row = tid >> 3;
      int gc = k0 + (((tid & 7) ^ (row & 7)) << 3);
      gload16(W + (size_t)row * 384 + gc, &Bs[w << 9]);
    }
    if (w < 2) {
      int row = 32 + (tid >> 3);
      int gc = k0 + (((tid & 7) ^ (row & 7)) << 3);
      gload16(W + (size_t)row * 384 + gc, &Bs[2048 + (w << 9)]);
    }
    __syncthreads();
#pragma unroll
    for (int ks = 0; ks < 2; ++ks) {
      int s = (ks << 2) + lk;
      int ar = (w << 4) + lr;
      bf16x8 a = *(const bf16x8*)&As[ar * 64 + ((s ^ (ar & 7)) << 3)];
#pragma unroll
      for (int ni = 0; ni < 3; ++ni) {
        int br = (ni << 4) + lr;
        bf16x8 bb = *(const bf16x8*)&Bs[br * 64 + ((s ^ (br & 7)) << 3)];
        acc[ni] = MFMA16(a, bb, acc[ni]);
      }
    }
  }
#pragma unroll
  for (int ni = 0; ni < 3; ++ni)
#pragma unroll
    for (int r = 0; r < 4; ++r) {
      int col = (ni << 4) + lr;
      if (col < NDBL) dbl[(size_t)(m0 + (w << 4) + (lk << 2) + r) * NDBL + col] = acc[ni][r];
    }
}

// ---------------- scan pass A: fused dt_proj + local scan, h[16] in regs -------------
__global__ __launch_bounds__(384) void k_scanA(const unsigned short* __restrict__ xsb,
                                               const float* __restrict__ dbl,
                                               const float* __restrict__ dw,
                                               const float* __restrict__ dbias,
                                               const float* __restrict__ A_log,
                                               float* __restrict__ Hloc,
                                               float* __restrict__ Sbuf) {
  __shared__ float Bsh[CSZ][16];
  __shared__ float dl[CSZ][12];
  int tid = threadIdx.x;
  int blk = blockIdx.x;
  int b = blk >> 8;
  int chunk = blk & (NCHUNK - 1);
  int l0 = chunk * CSZ;
  for (int idx = tid; idx < CSZ * 16; idx += 384) {
    int r = idx >> 4, n = idx & 15;
    Bsh[r][n] = dbl[((size_t)b * L_ + l0 + r) * NDBL + DTR + n];
  }
  for (int idx = tid; idx < CSZ * 12; idx += 384) {
    int r = idx / 12, k = idx - r * 12;
    dl[r][k] = dbl[((size_t)b * L_ + l0 + r) * NDBL + k];
  }
  int d = tid;
  float4 wv0 = *(const float4*)&dw[d * 12];
  float4 wv1 = *(const float4*)&dw[d * 12 + 4];
  float4 wv2 = *(const float4*)&dw[d * 12 + 8];
  float bias = dbias[d];
  float An[16];
  {
    float4 a0 = *(const float4*)&A_log[d * 16 + 0];
    float4 a1 = *(const float4*)&A_log[d * 16 + 4];
    float4 a2 = *(const float4*)&A_log[d * 16 + 8];
    float4 a3 = *(const float4*)&A_log[d * 16 + 12];
    An[0] = -__expf(a0.x); An[1] = -__expf(a0.y); An[2] = -__expf(a0.z); An[3] = -__expf(a0.w);
    An[4] = -__expf(a1.x); An[5] = -__expf(a1.y); An[6] = -__expf(a1.z); An[7] = -__expf(a1.w);
    An[8] = -__expf(a2.x); An[9] = -__expf(a2.y); An[10] = -__expf(a2.z); An[11] = -__expf(a2.w);
    An[12] = -__expf(a3.x); An[13] = -__expf(a3.y); An[14] = -__expf(a3.z); An[15] = -__expf(a3.w);
  }
  bool fast = true;
#pragma unroll
  for (int n = 0; n < 16; ++n) fast = fast && (fabsf(An[n] + (float)(n + 1)) < 2e-3f);
  const unsigned short* xp = xsb + ((size_t)b * L_ + l0) * DI + d;
  __syncthreads();
  float dtf[CSZ];
  float S = 0.f;
#pragma unroll
  for (int i = 0; i < CSZ; ++i) {
    float4 c0 = *(const float4*)&dl[i][0];
    float4 c1 = *(const float4*)&dl[i][4];
    float4 c2 = *(const float4*)&dl[i][8];
    float a = bias;
    a = fmaf(wv0.x, c0.x, a); a = fmaf(wv0.y, c0.y, a);
    a = fmaf(wv0.z, c0.z, a); a = fmaf(wv0.w, c0.w, a);
    a = fmaf(wv1.x, c1.x, a); a = fmaf(wv1.y, c1.y, a);
    a = fmaf(wv1.z, c1.z, a); a = fmaf(wv1.w, c1.w, a);
    a = fmaf(wv2.x, c2.x, a); a = fmaf(wv2.y, c2.y, a);
    a = fmaf(wv2.z, c2.z, a); a = fmaf(wv2.w, c2.w, a);
    float sp = fmaxf(a, 0.f) + log1pf(__expf(-fabsf(a)));
    dtf[i] = sp;
    S += sp;
  }
  float h[16];
#pragma unroll
  for (int n = 0; n < 16; ++n) h[n] = 0.f;
  if (fast) {
#pragma unroll
    for (int i = 0; i < CSZ; ++i) {
      float dtv = dtf[i];
      float xv = bf2f(xp[(size_t)i * DI]);
      float dtx = dtv * xv;
      float dA[16];
      dA[0] = __expf(-dtv);
      dA[1] = dA[0] * dA[0];
      dA[2] = dA[1] * dA[0];
      dA[3] = dA[1] * dA[1];
#pragma unroll
      for (int n = 0; n < 4; ++n) dA[n + 4] = dA[n] * dA[3];
#pragma unroll
      for (int n = 0; n < 8; ++n) dA[n + 8] = dA[n] * dA[7];
      float4 B0 = *(const float4*)&Bsh[i][0];
      float4 B1 = *(const float4*)&Bsh[i][4];
      float4 B2 = *(const float4*)&Bsh[i][8];
      float4 B3 = *(const float4*)&Bsh[i][12];
      float Bv[16] = {B0.x, B0.y, B0.z, B0.w, B1.x, B1.y, B1.z, B1.w,
                      B2.x, B2.y, B2.z, B2.w, B3.x, B3.y, B3.z, B3.w};
#pragma unroll
      for (int n = 0; n < 16; ++n) h[n] = fmaf(dA[n], h[n], dtx * Bv[n]);
    }
  } else {
#pragma unroll
    for (int i = 0; i < CSZ; ++i) {
      float dtv = dtf[i];
      float xv = bf2f(xp[(size_t)i * DI]);
      float dtx = dtv * xv;
      float4 B0 = *(const float4*)&Bsh[i][0];
      float4 B1 = *(const float4*)&Bsh[i][4];
      float4 B2 = *(const float4*)&Bsh[i][8];
      float4 B3 = *(const float4*)&Bsh[i][12];
      float Bv[16] = {B0.x, B0.y, B0.z, B0.w, B1.x, B1.y, B1.z, B1.w,
                      B2.x, B2.y, B2.z, B2.w, B3.x, B3.y, B3.z, B3.w};
#pragma unroll
      for (int n = 0; n < 16; ++n) h[n] = fmaf(__expf(dtv * An[n]), h[n], dtx * Bv[n]);
    }
  }
  size_t base = (((size_t)b * NCHUNK + chunk) * DI + d) * 16;
  *(float4*)&Hloc[base + 0]  = make_float4(h[0], h[1], h[2], h[3]);
  *(float4*)&Hloc[base + 4]  = make_float4(h[4], h[5], h[6], h[7]);
  *(float4*)&Hloc[base + 8]  = make_float4(h[8], h[9], h[10], h[11]);
  *(float4*)&Hloc[base + 12] = make_float4(h[12], h[13], h[14], h[15]);
  Sbuf[((size_t)b * NCHUNK + chunk) * DI + d] = S;
}

// ---------------- scan pass B: chunk recurrence in-place, prefetch-pipelined ---------
__global__ __launch_bounds__(256) void k_scanB(const float* __restrict__ A_log,
                                               float* __restrict__ Hloc,
                                               const float* __restrict__ Sbuf) {
  int gid = blockIdx.x * 256 + threadIdx.x;
  int n = gid & 15;
  int rest = gid >> 4;
  int d = rest % DI;
  int b = rest / DI;
  float An = -__expf(A_log[d * 16 + n]);
  float* Hp = Hloc + ((size_t)b * NCHUNK * DI + d) * 16 + n;
  const float* Sp = Sbuf + (size_t)b * NCHUNK * DI + d;
  constexpr size_t HS = (size_t)DI * 16;
  float h = 0.f;
  float SA[8], HA[8], SB[8], HB[8];
#define LDGRP(Sa, Ha, cb)                        \
  _Pragma("unroll") for (int u = 0; u < 8; ++u) { \
    Sa[u] = Sp[(size_t)((cb) + u) * DI];          \
    Ha[u] = Hp[(size_t)((cb) + u) * HS];          \
  }
#define STGRP(Sa, Ha, cb)                        \
  _Pragma("unroll") for (int u = 0; u < 8; ++u) { \
    Hp[(size_t)((cb) + u) * HS] = h;              \
    h = fmaf(__expf(An * Sa[u]), h, Ha[u]);       \
  }
  LDGRP(SA, HA, 0)
  for (int g = 0; g < 32; g += 2) {
    LDGRP(SB, HB, (g + 1) * 8)
    STGRP(SA, HA, g * 8)
    if (g + 2 < 32) LDGRP(SA, HA, (g + 2) * 8)
    STGRP(SB, HB, (g + 1) * 8)
  }
#undef LDGRP
#undef STGRP
}

// ---------------- scan pass C: fused dt + local scan + carry + y/gating --------------
__global__ __launch_bounds__(384) void k_scanC(const unsigned short* __restrict__ xsb,
                                               const float* __restrict__ dbl,
                                               const unsigned short* __restrict__ z,
                                               const float* __restrict__ dw,
                                               const float* __restrict__ dbias,
                                               const float* __restrict__ A_log,
                                               const float* __restrict__ Dw,
                                               const float* __restrict__ Hloc,
                                               unsigned short* __restrict__ ybuf) {
  __shared__ float BCsh[CSZ][32];  // [r][0:16]=B, [r][16:32]=C
  __shared__ float dl[CSZ][12];
  int tid = threadIdx.x;
  int blk = blockIdx.x;
  int b = blk >> 8;
  int chunk = blk & (NCHUNK - 1);
  int l0 = chunk * CSZ;
  for (int idx = tid; idx < CSZ * 32; idx += 384) {
    int r = idx >> 5, n32 = idx & 31;
    BCsh[r][n32] = dbl[((size_t)b * L_ + l0 + r) * NDBL + DTR + n32];
  }
  for (int idx = tid; idx < CSZ * 12; idx += 384) {
    int r = idx / 12, k = idx - r * 12;
    dl[r][k] = dbl[((size_t)b * L_ + l0 + r) * NDBL + k];
  }
  int d = tid;
  float4 wv0 = *(const float4*)&dw[d * 12];
  float4 wv1 = *(const float4*)&dw[d * 12 + 4];
  float4 wv2 = *(const float4*)&dw[d * 12 + 8];
  float bias = dbias[d];
  float Dd = Dw[d];
  float An[16];
  {
    float4 a0 = *(const float4*)&A_log[d * 16 + 0];
    float4 a1 = *(const float4*)&A_log[d * 16 + 4];
    float4 a2 = *(const float4*)&A_log[d * 16 + 8];
    float4 a3 = *(const float4*)&A_log[d * 16 + 12];
    An[0] = -__expf(a0.x); An[1] = -__expf(a0.y); An[2] = -__expf(a0.z); An[3] = -__expf(a0.w);
    An[4] = -__expf(a1.x); An[5] = -__expf(a1.y); An[6] = -__expf(a1.z); An[7] = -__expf(a1.w);
    An[8] = -__expf(a2.x); An[9] = -__expf(a2.y); An[10] = -__expf(a2.z); An[11] = -__expf(a2.w);
    An[12] = -__expf(a3.x); An[13] = -__expf(a3.y); An[14] = -__expf(a3.z); An[15] = -__expf(a3.w);
  }
  bool fast = true;
#pragma unroll
  for (int n = 0; n < 16; ++n) fast = fast && (fabsf(An[n] + (float)(n + 1)) < 2e-3f);
  size_t base = (((size_t)b * NCHUNK + chunk) * DI + d) * 16;
  float h[16];
  {
    float4 h0 = *(const float4*)&Hloc[base + 0];
    float4 h1 = *(const float4*)&Hloc[base + 4];
    float4 h2 = *(const float4*)&Hloc[base + 8];
    float4 h3 = *(const float4*)&Hloc[base + 12];
    h[0] = h0.x; h[1] = h0.y; h[2] = h0.z; h[3] = h0.w;
    h[4] = h1.x; h[5] = h1.y; h[6] = h1.z; h[7] = h1.w;
    h[8] = h2.x; h[9] = h2.y; h[10] = h2.z; h[11] = h2.w;
    h[12] = h3.x; h[13] = h3.y; h[14] = h3.z; h[15] = h3.w;
  }
  const unsigned short* xp = xsb + ((size_t)b * L_ + l0) * DI + d;
  const unsigned short* zp = z + ((size_t)b * L_ + l0) * DI + d;
  unsigned short* yp = ybuf + ((size_t)b * L_ + l0) * DI + d;
  __syncthreads();
  float dtf[CSZ];
#pragma unroll
  for (int i = 0; i < CSZ; ++i) {
    float4 c0 = *(const float4*)&dl[i][0];
    float4 c1 = *(const float4*)&dl[i][4];
    float4 c2 = *(const float4*)&dl[i][8];
    float a = bias;
    a = fmaf(wv0.x, c0.x, a); a = fmaf(wv0.y, c0.y, a);
    a = fmaf(wv0.z, c0.z, a); a = fmaf(wv0.w, c0.w, a);
    a = fmaf(wv1.x, c1.x, a); a = fmaf(wv1.y, c1.y, a);
    a = fmaf(wv1.z, c1.z, a); a = fmaf(wv1.w, c1.w, a);
    a = fmaf(wv2.x, c2.x, a); a = fmaf(wv2.y, c2.y, a);
    a = fmaf(wv2.z, c2.z, a); a = fmaf(wv2.w, c2.w, a);
    dtf[i] = fmaxf(a, 0.f) + log1pf(__expf(-fabsf(a)));
  }
  if (fast) {
#pragma unroll
    for (int i = 0; i < CSZ; ++i) {
      float dtv = dtf[i];
      float xv = bf2f(xp[(size_t)i * DI]);
      float zv = bf2f(zp[(size_t)i * DI]);
      float dtx = dtv * xv;
      float dA[16];
      dA[0] = __expf(-dtv);
      dA[1] = dA[0] * dA[0];
      dA[2] = dA[1] * dA[0];
      dA[3] = dA[1] * dA[1];
#pragma unroll
      for (int n = 0; n < 4; ++n) dA[n + 4] = dA[n] * dA[3];
#pragma unroll
      for (int n = 0; n < 8; ++n) dA[n + 8] = dA[n] * dA[7];
      float4 B0 = *(const float4*)&BCsh[i][0];
      float4 B1 = *(const float4*)&BCsh[i][4];
      float4 B2 = *(const float4*)&BCsh[i][8];
      float4 B3 = *(const float4*)&BCsh[i][12];
      float4 C0 = *(const float4*)&BCsh[i][16];
      float4 C1 = *(const float4*)&BCsh[i][20];
      float4 C2 = *(const float4*)&BCsh[i][24];
      float4 C3 = *(const float4*)&BCsh[i][28];
      float Bv[16] = {B0.x, B0.y, B0.z, B0.w, B1.x, B1.y, B1.z, B1.w,
                      B2.x, B2.y, B2.z, B2.w, B3.x, B3.y, B3.z, B3.w};
      float Cv[16] = {C0.x, C0.y, C0.z, C0.w, C1.x, C1.y, C1.z, C1.w,
                      C2.x, C2.y, C2.z, C2.w, C3.x, C3.y, C3.z, C3.w};
      float y = 0.f;
#pragma unroll
      for (int n = 0; n < 16; ++n) {
        h[n] = fmaf(dA[n], h[n], dtx * Bv[n]);
        y = fmaf(h[n], Cv[n], y);
      }
      y = fmaf(xv, Dd, y);
      float sig = 1.f / (1.f + __expf(-zv));
      yp[(size_t)i * DI] = f2bf(y * (zv * sig));
    }
  } else {
#pragma unroll
    for (int i = 0; i < CSZ; ++i) {
      float dtv = dtf[i];
      float xv = bf2f(xp[(size_t)i * DI]);
      float zv = bf2f(zp[(size_t)i * DI]);
      float dtx = dtv * xv;
      float4 B0 = *(const float4*)&BCsh[i][0];
      float4 B1 = *(const float4*)&BCsh[i][4];
      float4 B2 = *(const float4*)&BCsh[i][8];
      float4 B3 = *(const float4*)&BCsh[i][12];
      float4 C0 = *(const float4*)&BCsh[i][16];
      float4 C1 = *(const float4*)&BCsh[i][20];
      float4 C2 = *(const float4*)&BCsh[i][24];
      float4 C3 = *(const float4*)&BCsh[i][28];
      float Bv[16] = {B0.x, B0.y, B0.z, B0.w, B1.x, B1.y, B1.z, B1.w,
                      B2.x, B2.y, B2.z, B2.w, B3.x, B3.y, B3.z, B3.w};
      float Cv[16] = {C0.x, C0.y, C0.z, C0.w, C1.x, C1.y, C1.z, C1.w,
                      C2.x, C2.y, C2.z, C2.w, C3.x, C3.y, C3.z, C3.w};
      float y = 0.f;
#pragma unroll
      for (int n = 0; n < 16; ++n) {
        h[n] = fmaf(__expf(dtv * An[n]), h[n], dtx * Bv[n]);
        y = fmaf(h[n], Cv[n], y);
      }
      y = fmaf(xv, Dd, y);
      float sig = 1.f / (1.f + __expf(-zv));
      yp[(size_t)i * DI] = f2bf(y * (zv * sig));
    }
  }
}

// ---------------- out_proj MFMA + residual: ybuf(BL,384) @ W(192,384)^T + x ----------
__global__ __launch_bounds__(256) void k_outproj(const unsigned short* __restrict__ Y,
                                                 const unsigned short* __restrict__ W,
                                                 const float* __restrict__ x,
                                                 float* __restrict__ out) {
  __shared__ float smemf[8448];
  unsigned short* As = (unsigned short*)smemf;
  unsigned short* Bs = (unsigned short*)smemf + 8192;
  int tid = threadIdx.x;
  int w = tid >> 6, l = tid & 63;
  int wr = w >> 1, wc = w & 1;
  int m0 = blockIdx.x << 7;
  int n0 = blockIdx.y << 6;
  int lr = l & 15, lk = l >> 4;
  f32x4 acc[4][2];
#pragma unroll
  for (int i = 0; i < 4; ++i)
#pragma unroll
    for (int j = 0; j < 2; ++j) acc[i][j] = (f32x4){0.f, 0.f, 0.f, 0.f};
  for (int kt = 0; kt < 6; ++kt) {
    int k0 = kt * 64;
    if (kt) __syncthreads();
#pragma unroll
    for (int i = 0; i < 4; ++i) {
      int row = (i << 5) + (tid >> 3);
      int gc = k0 + (((tid & 7) ^ (row & 7)) << 3);
      gload16(Y + (size_t)(m0 + row) * 384 + gc, &As[(i << 11) + (w << 9)]);
    }
#pragma unroll
    for (int i = 0; i < 2; ++i) {
      int row = (i << 5) + (tid >> 3);
      int gc = k0 + (((tid & 7) ^ (row & 7)) << 3);
      gload16(W + (size_t)(n0 + row) * 384 + gc, &Bs[(i << 11) + (w << 9)]);
    }
    __syncthreads();
#pragma unroll
    for (int ks = 0; ks < 2; ++ks) {
      int s = (ks << 2) + lk;
      bf16x8 bfr[2];
#pragma unroll
      for (int ni = 0; ni < 2; ++ni) {
        int r = (wc << 5) + (ni << 4) + lr;
        bfr[ni] = *(const bf16x8*)&Bs[r * 64 + ((s ^ (r & 7)) << 3)];
      }
#pragma unroll
      for (int mi = 0; mi < 4; ++mi) {
        int r = (wr << 6) + (mi << 4) + lr;
        bf16x8 a = *(const bf16x8*)&As[r * 64 + ((s ^ (r & 7)) << 3)];
#pragma unroll
        for (int ni = 0; ni < 2; ++ni) acc[mi][ni] = MFMA16(a, bfr[ni], acc[mi][ni]);
      }
    }
  }
  __syncthreads();
#pragma unroll
  for (int mi = 0; mi < 4; ++mi)
#pragma unroll
    for (int ni = 0; ni < 2; ++ni) {
      int c = (wc << 5) + (ni << 4) + lr;
      int lrow = (wr << 6) + (mi << 4) + (lk << 2);
      *(f32x4*)&smemf[c * 132 + lrow] = acc[mi][ni];
    }
  __syncthreads();
  int b = m0 >> 12;
  int l0 = m0 & (L_ - 1);
#pragma unroll
  for (int i = 0; i < 8; ++i) {
    int chunk = i * 256 + tid;
    int c = chunk >> 5, lq = chunk & 31;
    f32x4 v = *(const f32x4*)&smemf[c * 132 + (lq << 2)];
    size_t off = ((size_t)b * C_ + n0 + c) * L_ + l0 + (lq << 2);
    f32x4 xv = *(const f32x4*)&x[off];
    v = v + xv;
    *(f32x4*)&out[off] = v;
  }
}

extern "C" void kernel_launch(void* const* d_in, const int* in_sizes, int n_in,
                              void* d_out, int out_size, void* d_ws, size_t ws_size,
                              hipStream_t stream) {
  const float* x         = (const float*)d_in[0];
  const float* norm_w    = (const float*)d_in[1];
  const float* norm_b    = (const float*)d_in[2];
  const float* in_proj_w = (const float*)d_in[3];
  const float* conv_w    = (const float*)d_in[4];
  const float* conv_b    = (const float*)d_in[5];
  const float* x_proj_w  = (const float*)d_in[6];
  const float* dt_proj_w = (const float*)d_in[7];
  const float* dt_proj_b = (const float*)d_in[8];
  const float* A_log     = (const float*)d_in[9];
  const float* Dw        = (const float*)d_in[10];
  const float* out_proj_w= (const float*)d_in[11];
  float* out = (float*)d_out;
  float* ws = (float*)d_ws;

  unsigned short* seqn = (unsigned short*)(ws + F_SEQN);
  unsigned short* xin  = (unsigned short*)(ws + F_XIN);
  unsigned short* z    = (unsigned short*)(ws + F_Z);
  unsigned short* xsb  = (unsigned short*)(ws + F_XSB);
  float* dbl           = ws + F_DBL;
  float* Sbuf          = ws + F_SBUF;
  float* Hloc          = ws + F_HLOC;
  unsigned short* wbuf = (unsigned short*)(ws + F_WBUF);
  unsigned short* ipw  = wbuf;
  unsigned short* xpw  = wbuf + 147456;
  unsigned short* opw  = wbuf + 165888;
  unsigned short* ybuf = xin;  // xin dead after conv

  hipLaunchKernelGGL(k_cvtw, dim3(936), dim3(256), 0, stream, in_proj_w, x_proj_w, out_proj_w,
                     wbuf);
  hipLaunchKernelGGL(k_ln, dim3(256), dim3(256), 0, stream, x, norm_w, norm_b, seqn);
  hipLaunchKernelGGL(k_inproj, dim3(128, 6), dim3(256), 0, stream, seqn, ipw, xin, z);
  hipLaunchKernelGGL(k_conv, dim3(6, 64, 4), dim3(256), 0, stream, xin, conv_w, conv_b, xsb);
  hipLaunchKernelGGL(k_xproj, dim3(256), dim3(256), 0, stream, xsb, xpw, dbl);
  hipLaunchKernelGGL(k_scanA, dim3(1024), dim3(384), 0, stream, xsb, dbl, dt_proj_w, dt_proj_b,
                     A_log, Hloc, Sbuf);
  hipLaunchKernelGGL(k_scanB, dim3(96), dim3(256), 0, stream, A_log, Hloc, Sbuf);
  hipLaunchKernelGGL(k_scanC, dim3(1024), dim3(384), 0, stream, xsb, dbl, z, dt_proj_w,
                     dt_proj_b, A_log, Dw, Hloc, ybuf);
  hipLaunchKernelGGL(k_outproj, dim3(128, 3), dim3(256), 0, stream, ybuf, opw, x, out);
}

// Round 5
// 114.817 us; speedup vs baseline: 4.3430x; 1.3551x over previous
//
#include <hip/hip_runtime.h>
#include <hip/hip_bf16.h>

// Problem constants
constexpr int B_ = 4;
constexpr int C_ = 192;
constexpr int L_ = 4096;     // H*W
constexpr int DI = 384;      // d_inner
constexpr int DSs = 16;      // d_state
constexpr int DTR = 12;      // dt_rank
constexpr int NDBL = 44;     // dt_rank + 2*d_state
constexpr int NCHUNK = 256;  // scan chunks
constexpr int CSZ = 16;      // chunk size

constexpr size_t BL = (size_t)B_ * L_;  // 16384

// Workspace offsets in FLOAT units (bf16 buffers counted at half)
constexpr size_t F_SEQN = 0;                                  // bf16 BL*C
constexpr size_t F_XIN  = F_SEQN + BL * C_ / 2;               // bf16 BL*DI (reused as ybuf)
constexpr size_t F_Z    = F_XIN + BL * DI / 2;                // bf16 BL*DI
constexpr size_t F_XSB  = F_Z + BL * DI / 2;                  // bf16 BL*DI
constexpr size_t F_DBL  = F_XSB + BL * DI / 2;                // f32  BL*NDBL
constexpr size_t F_DT   = F_DBL + BL * NDBL;                  // f32  BL*DI
constexpr size_t F_SBUF = F_DT + BL * DI;                     // f32  B*NCHUNK*DI
constexpr size_t F_HLOC = F_SBUF + (size_t)B_ * NCHUNK * DI;  // f32  B*NCHUNK*16*DI
constexpr size_t F_WBUF = F_HLOC + (size_t)B_ * NCHUNK * DI * 16;  // bf16 weights
// total ~= 99 MB (prior rounds used 129 MB: safe)

typedef __attribute__((ext_vector_type(8))) short bf16x8;
typedef __attribute__((ext_vector_type(4))) float f32x4;

__device__ __forceinline__ unsigned short f2bf(float v) {
  unsigned x = __builtin_bit_cast(unsigned, v);
  unsigned r = x + 0x7FFFu + ((x >> 16) & 1u);   // RNE
  return (unsigned short)(r >> 16);
}
__device__ __forceinline__ float bf2f(unsigned short u) {
  return __builtin_bit_cast(float, (unsigned)u << 16);
}
__device__ __forceinline__ void gload16(const void* g, void* l) {
  __builtin_amdgcn_global_load_lds((const __attribute__((address_space(1))) void*)g,
                                   (__attribute__((address_space(3))) void*)l, 16, 0, 0);
}
#define MFMA16(a, b, c) __builtin_amdgcn_mfma_f32_16x16x32_bf16(a, b, c, 0, 0, 0)

// ---------------- weight convert: f32 -> bf16 (xproj zero-padded to 48 rows) ---------
__global__ __launch_bounds__(256) void k_cvtw(const float* __restrict__ ipw,
                                              const float* __restrict__ xpw,
                                              const float* __restrict__ opw,
                                              unsigned short* __restrict__ wbuf) {
  int t = blockIdx.x * 256 + threadIdx.x;
  if (t >= 239616) return;
  float v;
  if (t < 147456) v = ipw[t];
  else if (t < 165888) {
    int j = t - 147456;
    int r = j / 384, c = j - r * 384;
    v = (r < 44) ? xpw[r * 384 + c] : 0.f;
  } else v = opw[t - 165888];
  wbuf[t] = f2bf(v);
}

// ---------------- LayerNorm over C per (b,l), x(B,C,L) -> seqn(B,L,C) bf16 -----------
__global__ __launch_bounds__(256) void k_ln(const float* __restrict__ x,
                                            const float* __restrict__ nw,
                                            const float* __restrict__ nb,
                                            unsigned short* __restrict__ seqn) {
  __shared__ float xt[192][65];
  __shared__ float ps[4][64], ps2[4][64];
  __shared__ float mu_[64], rs_[64];
  __shared__ float wsh[192], bsh[192];
  int tid = threadIdx.x;
  int blk = blockIdx.x;
  int b = blk >> 6;
  int l0 = (blk & 63) << 6;
  const float* xb = x + (size_t)b * C_ * L_;
  for (int idx = tid; idx < 192 * 64; idx += 256) {
    int c = idx >> 6, ll = idx & 63;
    xt[c][ll] = xb[(size_t)c * L_ + l0 + ll];
  }
  if (tid < 192) { wsh[tid] = nw[tid]; bsh[tid] = nb[tid]; }
  __syncthreads();
  int ll = tid & 63, q = tid >> 6;
  float s = 0.f, ss = 0.f;
  for (int c = q * 48; c < q * 48 + 48; ++c) { float v = xt[c][ll]; s += v; ss += v * v; }
  ps[q][ll] = s; ps2[q][ll] = ss;
  __syncthreads();
  if (q == 0) {
    float st = ps[0][ll] + ps[1][ll] + ps[2][ll] + ps[3][ll];
    float sst = ps2[0][ll] + ps2[1][ll] + ps2[2][ll] + ps2[3][ll];
    float mu = st * (1.f / 192.f);
    float var = sst * (1.f / 192.f) - mu * mu;
    mu_[ll] = mu; rs_[ll] = rsqrtf(var + 1e-5f);
  }
  __syncthreads();
  unsigned short* so = seqn + ((size_t)b * L_ + l0) * C_;
  for (int idx = tid; idx < 64 * 192; idx += 256) {
    int l = idx / 192, c = idx - l * 192;
    so[idx] = f2bf((xt[c][l] - mu_[l]) * rs_[l] * wsh[c] + bsh[c]);
  }
}

// ---------------- in_proj MFMA: seqn(BL,192)bf16 @ W(768,192)^T -> xin,z bf16 --------
__global__ __launch_bounds__(256) void k_inproj(const unsigned short* __restrict__ A,
                                                const unsigned short* __restrict__ W,
                                                unsigned short* __restrict__ xin,
                                                unsigned short* __restrict__ z) {
  __shared__ unsigned short smem[16384];
  unsigned short* As = smem;
  unsigned short* Bs = smem + 8192;
  int tid = threadIdx.x;
  int w = tid >> 6, l = tid & 63;
  int wr = w >> 1, wc = w & 1;
  int m0 = blockIdx.x << 7;
  int n0 = blockIdx.y << 7;
  f32x4 acc[4][4];
#pragma unroll
  for (int i = 0; i < 4; ++i)
#pragma unroll
    for (int j = 0; j < 4; ++j) acc[i][j] = (f32x4){0.f, 0.f, 0.f, 0.f};
  int lr = l & 15, lk = l >> 4;
  for (int kt = 0; kt < 3; ++kt) {
    int k0 = kt * 64;
    if (kt) __syncthreads();
#pragma unroll
    for (int i = 0; i < 4; ++i) {
      int row = (i << 5) + (tid >> 3);
      int gc = k0 + (((tid & 7) ^ (row & 7)) << 3);
      gload16(A + (size_t)(m0 + row) * 192 + gc, &As[(i << 11) + (w << 9)]);
      gload16(W + (size_t)(n0 + row) * 192 + gc, &Bs[(i << 11) + (w << 9)]);
    }
    __syncthreads();
#pragma unroll
    for (int ks = 0; ks < 2; ++ks) {
      int s = (ks << 2) + lk;
      bf16x8 af[4], bfr[4];
#pragma unroll
      for (int mi = 0; mi < 4; ++mi) {
        int r = (wr << 6) + (mi << 4) + lr;
        af[mi] = *(const bf16x8*)&As[r * 64 + ((s ^ (r & 7)) << 3)];
      }
#pragma unroll
      for (int ni = 0; ni < 4; ++ni) {
        int r = (wc << 6) + (ni << 4) + lr;
        bfr[ni] = *(const bf16x8*)&Bs[r * 64 + ((s ^ (r & 7)) << 3)];
      }
#pragma unroll
      for (int mi = 0; mi < 4; ++mi)
#pragma unroll
        for (int ni = 0; ni < 4; ++ni) acc[mi][ni] = MFMA16(af[mi], bfr[ni], acc[mi][ni]);
    }
  }
  __syncthreads();
#pragma unroll
  for (int mi = 0; mi < 4; ++mi)
#pragma unroll
    for (int ni = 0; ni < 4; ++ni) {
      int col = (wc << 6) + (ni << 4) + lr;
#pragma unroll
      for (int r = 0; r < 4; ++r) {
        int row = (wr << 6) + (mi << 4) + (lk << 2) + r;
        smem[(row << 7) + col] = f2bf(acc[mi][ni][r]);
      }
    }
  __syncthreads();
#pragma unroll
  for (int i = 0; i < 8; ++i) {
    int chunk = i * 256 + tid;
    int row = chunk >> 4, cq = chunk & 15;
    int n = n0 + (cq << 3);
    unsigned short* dst = (n < 384) ? (xin + (size_t)(m0 + row) * DI + n)
                                    : (z + (size_t)(m0 + row) * DI + (n - 384));
    *(bf16x8*)dst = *(const bf16x8*)&smem[(row << 7) + (cq << 3)];
  }
}

// ---------------- conv(4) causal + SiLU: xin bf16 -> xsb bf16 ------------------------
__global__ __launch_bounds__(256) void k_conv(const unsigned short* __restrict__ xin,
                                              const float* __restrict__ cw,
                                              const float* __restrict__ cb,
                                              unsigned short* __restrict__ xsb) {
  __shared__ float xt[67][64];
  __shared__ float res[64][65];
  int tid = threadIdx.x;
  int d0 = blockIdx.x << 6;
  int l0 = blockIdx.y << 6;
  int b = blockIdx.z;
  for (int idx = tid; idx < 67 * 16; idx += 256) {
    int rr = idx >> 4, q = idx & 15;
    int l = l0 - 3 + rr;
    float4 v = make_float4(0.f, 0.f, 0.f, 0.f);
    if (l >= 0) {
      ushort4 u = *(const ushort4*)&xin[((size_t)b * L_ + l) * DI + d0 + (q << 2)];
      v = make_float4(bf2f(u.x), bf2f(u.y), bf2f(u.z), bf2f(u.w));
    }
    *(float4*)&xt[rr][q << 2] = v;
  }
  __syncthreads();
  int dd = tid & 63, lq = tid >> 6;
  float4 w4 = *(const float4*)&cw[(d0 + dd) * 4];
  float bb = cb[d0 + dd];
  for (int rr = 0; rr < 16; ++rr) {
    int ll = (rr << 2) + lq;
    float a = bb + w4.x * xt[ll][dd] + w4.y * xt[ll + 1][dd] + w4.z * xt[ll + 2][dd] +
              w4.w * xt[ll + 3][dd];
    res[ll][dd] = a * __builtin_amdgcn_rcpf(1.f + __expf(-a));
  }
  __syncthreads();
  for (int idx = tid; idx < 64 * 16; idx += 256) {
    int ll = idx >> 4, q = idx & 15;
    ushort4 u;
    u.x = f2bf(res[ll][(q << 2)]);
    u.y = f2bf(res[ll][(q << 2) + 1]);
    u.z = f2bf(res[ll][(q << 2) + 2]);
    u.w = f2bf(res[ll][(q << 2) + 3]);
    *(ushort4*)&xsb[((size_t)b * L_ + l0 + ll) * DI + d0 + (q << 2)] = u;
  }
}

// ---------------- x_proj MFMA: xsb(BL,384) @ Wp(48,384)^T -> dbl f32 (cols<44) -------
__global__ __launch_bounds__(256) void k_xproj(const unsigned short* __restrict__ A,
                                               const unsigned short* __restrict__ W,
                                               float* __restrict__ dbl) {
  __shared__ unsigned short smem[4096 + 3072];
  unsigned short* As = smem;
  unsigned short* Bs = smem + 4096;
  int tid = threadIdx.x;
  int w = tid >> 6, l = tid & 63;
  int m0 = blockIdx.x << 6;
  int lr = l & 15, lk = l >> 4;
  f32x4 acc[3];
#pragma unroll
  for (int i = 0; i < 3; ++i) acc[i] = (f32x4){0.f, 0.f, 0.f, 0.f};
  for (int kt = 0; kt < 6; ++kt) {
    int k0 = kt * 64;
    if (kt) __syncthreads();
#pragma unroll
    for (int i = 0; i < 2; ++i) {
      int row = (i << 5) + (tid >> 3);
      int gc = k0 + (((tid & 7) ^ (row & 7)) << 3);
      gload16(A + (size_t)(m0 + row) * 384 + gc, &As[(i << 11) + (w << 9)]);
    }
    {
      int row = tid >> 3;
      int gc = k0 + (((tid & 7) ^ (row & 7)) << 3);
      gload16(W + (size_t)row * 384 + gc, &Bs[w << 9]);
    }
    if (w < 2) {
      int row = 32 + (tid >> 3);
      int gc = k0 + (((tid & 7) ^ (row & 7)) << 3);
      gload16(W + (size_t)row * 384 + gc, &Bs[2048 + (w << 9)]);
    }
    __syncthreads();
#pragma unroll
    for (int ks = 0; ks < 2; ++ks) {
      int s = (ks << 2) + lk;
      int ar = (w << 4) + lr;
      bf16x8 a = *(const bf16x8*)&As[ar * 64 + ((s ^ (ar & 7)) << 3)];
#pragma unroll
      for (int ni = 0; ni < 3; ++ni) {
        int br = (ni << 4) + lr;
        bf16x8 bb = *(const bf16x8*)&Bs[br * 64 + ((s ^ (br & 7)) << 3)];
        acc[ni] = MFMA16(a, bb, acc[ni]);
      }
    }
  }
#pragma unroll
  for (int ni = 0; ni < 3; ++ni)
#pragma unroll
    for (int r = 0; r < 4; ++r) {
      int col = (ni << 4) + lr;
      if (col < NDBL) dbl[(size_t)(m0 + (w << 4) + (lk << 2) + r) * NDBL + col] = acc[ni][r];
    }
}

// ---------------- scan pass A: dt_proj once (stores dt), local scan ------------------
// Hloc layout: [b][chunk][n][d] -> all accesses coalesced over d.
__global__ __launch_bounds__(384) void k_scanA(const unsigned short* __restrict__ xsb,
                                               const float* __restrict__ dbl,
                                               const float* __restrict__ dw,
                                               const float* __restrict__ dbias,
                                               const float* __restrict__ A_log,
                                               float* __restrict__ dtb,
                                               float* __restrict__ Hloc,
                                               float* __restrict__ Sbuf) {
  __shared__ float Bsh[CSZ][16];
  __shared__ float dl[CSZ][12];
  int tid = threadIdx.x;
  int blk = blockIdx.x;
  int b = blk >> 8;
  int chunk = blk & (NCHUNK - 1);
  int l0 = chunk * CSZ;
  for (int idx = tid; idx < CSZ * 28; idx += 384) {
    int r = idx / 28, c = idx - r * 28;
    float v = dbl[((size_t)b * L_ + l0 + r) * NDBL + c];
    if (c < 12) dl[r][c] = v; else Bsh[r][c - 12] = v;
  }
  int d = tid;
  float4 wv0 = *(const float4*)&dw[d * 12];
  float4 wv1 = *(const float4*)&dw[d * 12 + 4];
  float4 wv2 = *(const float4*)&dw[d * 12 + 8];
  float bias = dbias[d];
  bool fast = true;
#pragma unroll
  for (int n = 0; n < 16; ++n) {
    float An_ = -__expf(A_log[d * 16 + n]);
    fast = fast && (fabsf(An_ + (float)(n + 1)) < 2e-3f);
  }
  const unsigned short* xp = xsb + ((size_t)b * L_ + l0) * DI + d;
  float* dtp = dtb + ((size_t)b * L_ + l0) * DI + d;
  __syncthreads();
  float h[16];
#pragma unroll
  for (int n = 0; n < 16; ++n) h[n] = 0.f;
  float S = 0.f;
  if (fast) {
#pragma unroll
    for (int i = 0; i < CSZ; ++i) {
      float4 c0 = *(const float4*)&dl[i][0];
      float4 c1 = *(const float4*)&dl[i][4];
      float4 c2 = *(const float4*)&dl[i][8];
      float a = bias;
      a = fmaf(wv0.x, c0.x, a); a = fmaf(wv0.y, c0.y, a);
      a = fmaf(wv0.z, c0.z, a); a = fmaf(wv0.w, c0.w, a);
      a = fmaf(wv1.x, c1.x, a); a = fmaf(wv1.y, c1.y, a);
      a = fmaf(wv1.z, c1.z, a); a = fmaf(wv1.w, c1.w, a);
      a = fmaf(wv2.x, c2.x, a); a = fmaf(wv2.y, c2.y, a);
      a = fmaf(wv2.z, c2.z, a); a = fmaf(wv2.w, c2.w, a);
      float sp = fmaxf(a, 0.f) + __logf(1.f + __expf(-fabsf(a)));
      dtp[(size_t)i * DI] = sp;
      S += sp;
      float xv = bf2f(xp[(size_t)i * DI]);
      float dtx = sp * xv;
      float r = __expf(-sp);
      float r2 = r * r;
      float r4 = r2 * r2;
      float dA0 = r, dA1 = r2, dA2 = r2 * r, dA3 = r4;
#pragma unroll
      for (int g = 0; g < 4; ++g) {
        float4 Bg = *(const float4*)&Bsh[i][g << 2];
        h[(g << 2) + 0] = fmaf(dA0, h[(g << 2) + 0], dtx * Bg.x);
        h[(g << 2) + 1] = fmaf(dA1, h[(g << 2) + 1], dtx * Bg.y);
        h[(g << 2) + 2] = fmaf(dA2, h[(g << 2) + 2], dtx * Bg.z);
        h[(g << 2) + 3] = fmaf(dA3, h[(g << 2) + 3], dtx * Bg.w);
        if (g < 3) { dA0 *= r4; dA1 *= r4; dA2 *= r4; dA3 *= r4; }
      }
    }
  } else {
    float An[16];
#pragma unroll
    for (int n = 0; n < 16; ++n) An[n] = -__expf(A_log[d * 16 + n]);
#pragma unroll
    for (int i = 0; i < CSZ; ++i) {
      float4 c0 = *(const float4*)&dl[i][0];
      float4 c1 = *(const float4*)&dl[i][4];
      float4 c2 = *(const float4*)&dl[i][8];
      float a = bias;
      a = fmaf(wv0.x, c0.x, a); a = fmaf(wv0.y, c0.y, a);
      a = fmaf(wv0.z, c0.z, a); a = fmaf(wv0.w, c0.w, a);
      a = fmaf(wv1.x, c1.x, a); a = fmaf(wv1.y, c1.y, a);
      a = fmaf(wv1.z, c1.z, a); a = fmaf(wv1.w, c1.w, a);
      a = fmaf(wv2.x, c2.x, a); a = fmaf(wv2.y, c2.y, a);
      a = fmaf(wv2.z, c2.z, a); a = fmaf(wv2.w, c2.w, a);
      float sp = fmaxf(a, 0.f) + __logf(1.f + __expf(-fabsf(a)));
      dtp[(size_t)i * DI] = sp;
      S += sp;
      float xv = bf2f(xp[(size_t)i * DI]);
      float dtx = sp * xv;
#pragma unroll
      for (int n = 0; n < 16; ++n)
        h[n] = fmaf(__expf(sp * An[n]), h[n], dtx * Bsh[i][n]);
    }
  }
  size_t hbase = ((size_t)(b * NCHUNK + chunk) * 16) * DI + d;
#pragma unroll
  for (int n = 0; n < 16; ++n) Hloc[hbase + (size_t)n * DI] = h[n];
  Sbuf[((size_t)b * NCHUNK + chunk) * DI + d] = S;
}

// ---------------- scan pass B: chunk recurrence in-place, prefetch-pipelined ---------
__global__ __launch_bounds__(256) void k_scanB(const float* __restrict__ A_log,
                                               float* __restrict__ Hloc,
                                               const float* __restrict__ Sbuf) {
  int gid = blockIdx.x * 256 + threadIdx.x;  // B*16*DI = 24576
  int d = gid % DI;
  int rest = gid / DI;
  int n = rest & 15;
  int b = rest >> 4;
  float An = -__expf(A_log[d * 16 + n]);
  float* Hp = Hloc + ((size_t)b * NCHUNK * 16 + n) * DI + d;
  const float* Sp = Sbuf + (size_t)b * NCHUNK * DI + d;
  constexpr size_t HS = (size_t)16 * DI;
  float h = 0.f;
  float SA[8], HA[8], SB[8], HB[8];
#define LDGRP(Sa, Ha, cb)                         \
  _Pragma("unroll") for (int u = 0; u < 8; ++u) { \
    Sa[u] = Sp[(size_t)((cb) + u) * DI];          \
    Ha[u] = Hp[(size_t)((cb) + u) * HS];          \
  }
#define STGRP(Sa, Ha, cb)                         \
  _Pragma("unroll") for (int u = 0; u < 8; ++u) { \
    Hp[(size_t)((cb) + u) * HS] = h;              \
    h = fmaf(__expf(An * Sa[u]), h, Ha[u]);       \
  }
  LDGRP(SA, HA, 0)
  for (int g = 0; g < 32; g += 2) {
    LDGRP(SB, HB, (g + 1) * 8)
    STGRP(SA, HA, g * 8)
    if (g + 2 < 32) LDGRP(SA, HA, (g + 2) * 8)
    STGRP(SB, HB, (g + 1) * 8)
  }
#undef LDGRP
#undef STGRP
}

// ---------------- scan pass C: local scan + carry + y/gating (dt preloaded) ----------
__global__ __launch_bounds__(384) void k_scanC(const unsigned short* __restrict__ xsb,
                                               const float* __restrict__ dtb,
                                               const float* __restrict__ dbl,
                                               const unsigned short* __restrict__ z,
                                               const float* __restrict__ A_log,
                                               const float* __restrict__ Dw,
                                               const float* __restrict__ Hloc,
                                               unsigned short* __restrict__ ybuf) {
  __shared__ float BCsh[CSZ][32];  // [r][0:16]=B, [r][16:32]=C
  int tid = threadIdx.x;
  int blk = blockIdx.x;
  int b = blk >> 8;
  int chunk = blk & (NCHUNK - 1);
  int l0 = chunk * CSZ;
  for (int idx = tid; idx < CSZ * 32; idx += 384) {
    int r = idx >> 5, n32 = idx & 31;
    BCsh[r][n32] = dbl[((size_t)b * L_ + l0 + r) * NDBL + DTR + n32];
  }
  int d = tid;
  float Dd = Dw[d];
  bool fast = true;
#pragma unroll
  for (int n = 0; n < 16; ++n) {
    float An_ = -__expf(A_log[d * 16 + n]);
    fast = fast && (fabsf(An_ + (float)(n + 1)) < 2e-3f);
  }
  size_t hbase = ((size_t)(b * NCHUNK + chunk) * 16) * DI + d;
  float h[16];
#pragma unroll
  for (int n = 0; n < 16; ++n) h[n] = Hloc[hbase + (size_t)n * DI];
  const unsigned short* xp = xsb + ((size_t)b * L_ + l0) * DI + d;
  const float* dtp = dtb + ((size_t)b * L_ + l0) * DI + d;
  const unsigned short* zp = z + ((size_t)b * L_ + l0) * DI + d;
  unsigned short* yp = ybuf + ((size_t)b * L_ + l0) * DI + d;
  __syncthreads();
  if (fast) {
#pragma unroll
    for (int i = 0; i < CSZ; ++i) {
      float sp = dtp[(size_t)i * DI];
      float xv = bf2f(xp[(size_t)i * DI]);
      float zv = bf2f(zp[(size_t)i * DI]);
      float dtx = sp * xv;
      float r = __expf(-sp);
      float r2 = r * r;
      float r4 = r2 * r2;
      float dA0 = r, dA1 = r2, dA2 = r2 * r, dA3 = r4;
      float y = 0.f;
#pragma unroll
      for (int g = 0; g < 4; ++g) {
        float4 Bg = *(const float4*)&BCsh[i][g << 2];
        float4 Cg = *(const float4*)&BCsh[i][16 + (g << 2)];
        h[(g << 2) + 0] = fmaf(dA0, h[(g << 2) + 0], dtx * Bg.x);
        h[(g << 2) + 1] = fmaf(dA1, h[(g << 2) + 1], dtx * Bg.y);
        h[(g << 2) + 2] = fmaf(dA2, h[(g << 2) + 2], dtx * Bg.z);
        h[(g << 2) + 3] = fmaf(dA3, h[(g << 2) + 3], dtx * Bg.w);
        y = fmaf(h[(g << 2) + 0], Cg.x, y);
        y = fmaf(h[(g << 2) + 1], Cg.y, y);
        y = fmaf(h[(g << 2) + 2], Cg.z, y);
        y = fmaf(h[(g << 2) + 3], Cg.w, y);
        if (g < 3) { dA0 *= r4; dA1 *= r4; dA2 *= r4; dA3 *= r4; }
      }
      y = fmaf(xv, Dd, y);
      float sig = __builtin_amdgcn_rcpf(1.f + __expf(-zv));
      yp[(size_t)i * DI] = f2bf(y * (zv * sig));
    }
  } else {
    float An[16];
#pragma unroll
    for (int n = 0; n < 16; ++n) An[n] = -__expf(A_log[d * 16 + n]);
#pragma unroll
    for (int i = 0; i < CSZ; ++i) {
      float sp = dtp[(size_t)i * DI];
      float xv = bf2f(xp[(size_t)i * DI]);
      float zv = bf2f(zp[(size_t)i * DI]);
      float dtx = sp * xv;
      float y = 0.f;
#pragma unroll
      for (int n = 0; n < 16; ++n) {
        h[n] = fmaf(__expf(sp * An[n]), h[n], dtx * BCsh[i][n]);
        y = fmaf(h[n], BCsh[i][16 + n], y);
      }
      y = fmaf(xv, Dd, y);
      float sig = __builtin_amdgcn_rcpf(1.f + __expf(-zv));
      yp[(size_t)i * DI] = f2bf(y * (zv * sig));
    }
  }
}

// ---------------- out_proj MFMA + residual: ybuf(BL,384) @ W(192,384)^T + x ----------
__global__ __launch_bounds__(256) void k_outproj(const unsigned short* __restrict__ Y,
                                                 const unsigned short* __restrict__ W,
                                                 const float* __restrict__ x,
                                                 float* __restrict__ out) {
  __shared__ float smemf[8448];
  unsigned short* As = (unsigned short*)smemf;
  unsigned short* Bs = (unsigned short*)smemf + 8192;
  int tid = threadIdx.x;
  int w = tid >> 6, l = tid & 63;
  int wr = w >> 1, wc = w & 1;
  int m0 = blockIdx.x << 7;
  int n0 = blockIdx.y << 6;
  int lr = l & 15, lk = l >> 4;
  f32x4 acc[4][2];
#pragma unroll
  for (int i = 0; i < 4; ++i)
#pragma unroll
    for (int j = 0; j < 2; ++j) acc[i][j] = (f32x4){0.f, 0.f, 0.f, 0.f};
  for (int kt = 0; kt < 6; ++kt) {
    int k0 = kt * 64;
    if (kt) __syncthreads();
#pragma unroll
    for (int i = 0; i < 4; ++i) {
      int row = (i << 5) + (tid >> 3);
      int gc = k0 + (((tid & 7) ^ (row & 7)) << 3);
      gload16(Y + (size_t)(m0 + row) * 384 + gc, &As[(i << 11) + (w << 9)]);
    }
#pragma unroll
    for (int i = 0; i < 2; ++i) {
      int row = (i << 5) + (tid >> 3);
      int gc = k0 + (((tid & 7) ^ (row & 7)) << 3);
      gload16(W + (size_t)(n0 + row) * 384 + gc, &Bs[(i << 11) + (w << 9)]);
    }
    __syncthreads();
#pragma unroll
    for (int ks = 0; ks < 2; ++ks) {
      int s = (ks << 2) + lk;
      bf16x8 bfr[2];
#pragma unroll
      for (int ni = 0; ni < 2; ++ni) {
        int r = (wc << 5) + (ni << 4) + lr;
        bfr[ni] = *(const bf16x8*)&Bs[r * 64 + ((s ^ (r & 7)) << 3)];
      }
#pragma unroll
      for (int mi = 0; mi < 4; ++mi) {
        int r = (wr << 6) + (mi << 4) + lr;
        bf16x8 a = *(const bf16x8*)&As[r * 64 + ((s ^ (r & 7)) << 3)];
#pragma unroll
        for (int ni = 0; ni < 2; ++ni) acc[mi][ni] = MFMA16(a, bfr[ni], acc[mi][ni]);
      }
    }
  }
  __syncthreads();
#pragma unroll
  for (int mi = 0; mi < 4; ++mi)
#pragma unroll
    for (int ni = 0; ni < 2; ++ni) {
      int c = (wc << 5) + (ni << 4) + lr;
      int lrow = (wr << 6) + (mi << 4) + (lk << 2);
      *(f32x4*)&smemf[c * 132 + lrow] = acc[mi][ni];
    }
  __syncthreads();
  int b = m0 >> 12;
  int l0 = m0 & (L_ - 1);
#pragma unroll
  for (int i = 0; i < 8; ++i) {
    int chunk = i * 256 + tid;
    int c = chunk >> 5, lq = chunk & 31;
    f32x4 v = *(const f32x4*)&smemf[c * 132 + (lq << 2)];
    size_t off = ((size_t)b * C_ + n0 + c) * L_ + l0 + (lq << 2);
    f32x4 xv = *(const f32x4*)&x[off];
    v = v + xv;
    *(f32x4*)&out[off] = v;
  }
}

extern "C" void kernel_launch(void* const* d_in, const int* in_sizes, int n_in,
                              void* d_out, int out_size, void* d_ws, size_t ws_size,
                              hipStream_t stream) {
  const float* x         = (const float*)d_in[0];
  const float* norm_w    = (const float*)d_in[1];
  const float* norm_b    = (const float*)d_in[2];
  const float* in_proj_w = (const float*)d_in[3];
  const float* conv_w    = (const float*)d_in[4];
  const float* conv_b    = (const float*)d_in[5];
  const float* x_proj_w  = (const float*)d_in[6];
  const float* dt_proj_w = (const float*)d_in[7];
  const float* dt_proj_b = (const float*)d_in[8];
  const float* A_log     = (const float*)d_in[9];
  const float* Dw        = (const float*)d_in[10];
  const float* out_proj_w= (const float*)d_in[11];
  float* out = (float*)d_out;
  float* ws = (float*)d_ws;

  unsigned short* seqn = (unsigned short*)(ws + F_SEQN);
  unsigned short* xin  = (unsigned short*)(ws + F_XIN);
  unsigned short* z    = (unsigned short*)(ws + F_Z);
  unsigned short* xsb  = (unsigned short*)(ws + F_XSB);
  float* dbl           = ws + F_DBL;
  float* dtb           = ws + F_DT;
  float* Sbuf          = ws + F_SBUF;
  float* Hloc          = ws + F_HLOC;
  unsigned short* wbuf = (unsigned short*)(ws + F_WBUF);
  unsigned short* ipw  = wbuf;
  unsigned short* xpw  = wbuf + 147456;
  unsigned short* opw  = wbuf + 165888;
  unsigned short* ybuf = xin;  // xin dead after conv

  hipLaunchKernelGGL(k_cvtw, dim3(936), dim3(256), 0, stream, in_proj_w, x_proj_w, out_proj_w,
                     wbuf);
  hipLaunchKernelGGL(k_ln, dim3(256), dim3(256), 0, stream, x, norm_w, norm_b, seqn);
  hipLaunchKernelGGL(k_inproj, dim3(128, 6), dim3(256), 0, stream, seqn, ipw, xin, z);
  hipLaunchKernelGGL(k_conv, dim3(6, 64, 4), dim3(256), 0, stream, xin, conv_w, conv_b, xsb);
  hipLaunchKernelGGL(k_xproj, dim3(256), dim3(256), 0, stream, xsb, xpw, dbl);
  hipLaunchKernelGGL(k_scanA, dim3(1024), dim3(384), 0, stream, xsb, dbl, dt_proj_w, dt_proj_b,
                     A_log, dtb, Hloc, Sbuf);
  hipLaunchKernelGGL(k_scanB, dim3(96), dim3(256), 0, stream, A_log, Hloc, Sbuf);
  hipLaunchKernelGGL(k_scanC, dim3(1024), dim3(384), 0, stream, xsb, dtb, dbl, z, A_log, Dw,
                     Hloc, ybuf);
  hipLaunchKernelGGL(k_outproj, dim3(128, 3), dim3(256), 0, stream, ybuf, opw, x, out);
}

// Round 6
// 113.490 us; speedup vs baseline: 4.3938x; 1.0117x over previous
//
#include <hip/hip_runtime.h>
#include <hip/hip_bf16.h>

// Problem constants
constexpr int B_ = 4;
constexpr int C_ = 192;
constexpr int L_ = 4096;     // H*W
constexpr int DI = 384;      // d_inner
constexpr int DSs = 16;      // d_state
constexpr int DTR = 12;      // dt_rank
constexpr int NDBL = 44;     // dt_rank + 2*d_state
constexpr int NCHUNK = 256;  // scan chunks
constexpr int CSZ = 16;      // chunk size

constexpr size_t BL = (size_t)B_ * L_;  // 16384

// Workspace offsets in FLOAT units (bf16 buffers counted at half)
constexpr size_t F_SEQN = 0;                                  // bf16 BL*C
constexpr size_t F_XIN  = F_SEQN + BL * C_ / 2;               // bf16 BL*DI (reused as ybuf)
constexpr size_t F_Z    = F_XIN + BL * DI / 2;                // bf16 BL*DI
constexpr size_t F_XSB  = F_Z + BL * DI / 2;                  // bf16 BL*DI
constexpr size_t F_DBL  = F_XSB + BL * DI / 2;                // f32  BL*NDBL
constexpr size_t F_DT   = F_DBL + BL * NDBL;                  // bf16 BL*DI
constexpr size_t F_SBUF = F_DT + BL * DI / 2;                 // f32  B*NCHUNK*DI
constexpr size_t F_HLOC = F_SBUF + (size_t)B_ * NCHUNK * DI;  // bf16 B*NCHUNK*16*DI
constexpr size_t F_WBUF = F_HLOC + (size_t)B_ * NCHUNK * DI * 16 / 2;  // bf16 weights
// total ~= 74 MB (prior rounds used 129 MB: safe)

typedef __attribute__((ext_vector_type(8))) short bf16x8;
typedef __attribute__((ext_vector_type(4))) float f32x4;

__device__ __forceinline__ unsigned short f2bf(float v) {
  unsigned x = __builtin_bit_cast(unsigned, v);
  unsigned r = x + 0x7FFFu + ((x >> 16) & 1u);   // RNE
  return (unsigned short)(r >> 16);
}
__device__ __forceinline__ float bf2f(unsigned short u) {
  return __builtin_bit_cast(float, (unsigned)u << 16);
}
__device__ __forceinline__ void gload16(const void* g, void* l) {
  __builtin_amdgcn_global_load_lds((const __attribute__((address_space(1))) void*)g,
                                   (__attribute__((address_space(3))) void*)l, 16, 0, 0);
}
#define MFMA16(a, b, c) __builtin_amdgcn_mfma_f32_16x16x32_bf16(a, b, c, 0, 0, 0)

// ---------------- LayerNorm (blocks 0..255) + weight cvt (blocks 256..1191) ----------
__global__ __launch_bounds__(256) void k_ln(const float* __restrict__ x,
                                            const float* __restrict__ nw,
                                            const float* __restrict__ nb,
                                            unsigned short* __restrict__ seqn,
                                            const float* __restrict__ ipw,
                                            const float* __restrict__ xpw,
                                            const float* __restrict__ opw,
                                            unsigned short* __restrict__ wbuf) {
  if (blockIdx.x >= 256) {
    int t = (blockIdx.x - 256) * 256 + threadIdx.x;
    if (t < 239616) {
      float v;
      if (t < 147456) v = ipw[t];
      else if (t < 165888) {
        int j = t - 147456;
        int r = j / 384, c = j - r * 384;
        v = (r < 44) ? xpw[r * 384 + c] : 0.f;
      } else v = opw[t - 165888];
      wbuf[t] = f2bf(v);
    }
    return;
  }
  __shared__ float xt[192][65];
  __shared__ float ps[4][64], ps2[4][64];
  __shared__ float mu_[64], rs_[64];
  __shared__ float wsh[192], bsh[192];
  int tid = threadIdx.x;
  int blk = blockIdx.x;
  int b = blk >> 6;
  int l0 = (blk & 63) << 6;
  const float* xb = x + (size_t)b * C_ * L_;
  for (int idx = tid; idx < 192 * 64; idx += 256) {
    int c = idx >> 6, ll = idx & 63;
    xt[c][ll] = xb[(size_t)c * L_ + l0 + ll];
  }
  if (tid < 192) { wsh[tid] = nw[tid]; bsh[tid] = nb[tid]; }
  __syncthreads();
  int ll = tid & 63, q = tid >> 6;
  float s = 0.f, ss = 0.f;
  for (int c = q * 48; c < q * 48 + 48; ++c) { float v = xt[c][ll]; s += v; ss += v * v; }
  ps[q][ll] = s; ps2[q][ll] = ss;
  __syncthreads();
  if (q == 0) {
    float st = ps[0][ll] + ps[1][ll] + ps[2][ll] + ps[3][ll];
    float sst = ps2[0][ll] + ps2[1][ll] + ps2[2][ll] + ps2[3][ll];
    float mu = st * (1.f / 192.f);
    float var = sst * (1.f / 192.f) - mu * mu;
    mu_[ll] = mu; rs_[ll] = rsqrtf(var + 1e-5f);
  }
  __syncthreads();
  unsigned short* so = seqn + ((size_t)b * L_ + l0) * C_;
  for (int idx = tid; idx < 64 * 192; idx += 256) {
    int l = idx / 192, c = idx - l * 192;
    so[idx] = f2bf((xt[c][l] - mu_[l]) * rs_[l] * wsh[c] + bsh[c]);
  }
}

// ---------------- in_proj MFMA: seqn(BL,192)bf16 @ W(768,192)^T -> xin,z bf16 --------
__global__ __launch_bounds__(256) void k_inproj(const unsigned short* __restrict__ A,
                                                const unsigned short* __restrict__ W,
                                                unsigned short* __restrict__ xin,
                                                unsigned short* __restrict__ z) {
  __shared__ unsigned short smem[16384];
  unsigned short* As = smem;
  unsigned short* Bs = smem + 8192;
  int tid = threadIdx.x;
  int w = tid >> 6, l = tid & 63;
  int wr = w >> 1, wc = w & 1;
  int m0 = blockIdx.x << 7;
  int n0 = blockIdx.y << 7;
  f32x4 acc[4][4];
#pragma unroll
  for (int i = 0; i < 4; ++i)
#pragma unroll
    for (int j = 0; j < 4; ++j) acc[i][j] = (f32x4){0.f, 0.f, 0.f, 0.f};
  int lr = l & 15, lk = l >> 4;
  for (int kt = 0; kt < 3; ++kt) {
    int k0 = kt * 64;
    if (kt) __syncthreads();
#pragma unroll
    for (int i = 0; i < 4; ++i) {
      int row = (i << 5) + (tid >> 3);
      int gc = k0 + (((tid & 7) ^ (row & 7)) << 3);
      gload16(A + (size_t)(m0 + row) * 192 + gc, &As[(i << 11) + (w << 9)]);
      gload16(W + (size_t)(n0 + row) * 192 + gc, &Bs[(i << 11) + (w << 9)]);
    }
    __syncthreads();
#pragma unroll
    for (int ks = 0; ks < 2; ++ks) {
      int s = (ks << 2) + lk;
      bf16x8 af[4], bfr[4];
#pragma unroll
      for (int mi = 0; mi < 4; ++mi) {
        int r = (wr << 6) + (mi << 4) + lr;
        af[mi] = *(const bf16x8*)&As[r * 64 + ((s ^ (r & 7)) << 3)];
      }
#pragma unroll
      for (int ni = 0; ni < 4; ++ni) {
        int r = (wc << 6) + (ni << 4) + lr;
        bfr[ni] = *(const bf16x8*)&Bs[r * 64 + ((s ^ (r & 7)) << 3)];
      }
#pragma unroll
      for (int mi = 0; mi < 4; ++mi)
#pragma unroll
        for (int ni = 0; ni < 4; ++ni) acc[mi][ni] = MFMA16(af[mi], bfr[ni], acc[mi][ni]);
    }
  }
  __syncthreads();
#pragma unroll
  for (int mi = 0; mi < 4; ++mi)
#pragma unroll
    for (int ni = 0; ni < 4; ++ni) {
      int col = (wc << 6) + (ni << 4) + lr;
#pragma unroll
      for (int r = 0; r < 4; ++r) {
        int row = (wr << 6) + (mi << 4) + (lk << 2) + r;
        smem[(row << 7) + col] = f2bf(acc[mi][ni][r]);
      }
    }
  __syncthreads();
#pragma unroll
  for (int i = 0; i < 8; ++i) {
    int chunk = i * 256 + tid;
    int row = chunk >> 4, cq = chunk & 15;
    int n = n0 + (cq << 3);
    unsigned short* dst = (n < 384) ? (xin + (size_t)(m0 + row) * DI + n)
                                    : (z + (size_t)(m0 + row) * DI + (n - 384));
    *(bf16x8*)dst = *(const bf16x8*)&smem[(row << 7) + (cq << 3)];
  }
}

// ---------------- conv(4) causal + SiLU: xin bf16 -> xsb bf16 ------------------------
__global__ __launch_bounds__(256) void k_conv(const unsigned short* __restrict__ xin,
                                              const float* __restrict__ cw,
                                              const float* __restrict__ cb,
                                              unsigned short* __restrict__ xsb) {
  __shared__ float xt[67][64];
  __shared__ float res[64][65];
  int tid = threadIdx.x;
  int d0 = blockIdx.x << 6;
  int l0 = blockIdx.y << 6;
  int b = blockIdx.z;
  for (int idx = tid; idx < 67 * 16; idx += 256) {
    int rr = idx >> 4, q = idx & 15;
    int l = l0 - 3 + rr;
    float4 v = make_float4(0.f, 0.f, 0.f, 0.f);
    if (l >= 0) {
      ushort4 u = *(const ushort4*)&xin[((size_t)b * L_ + l) * DI + d0 + (q << 2)];
      v = make_float4(bf2f(u.x), bf2f(u.y), bf2f(u.z), bf2f(u.w));
    }
    *(float4*)&xt[rr][q << 2] = v;
  }
  __syncthreads();
  int dd = tid & 63, lq = tid >> 6;
  float4 w4 = *(const float4*)&cw[(d0 + dd) * 4];
  float bb = cb[d0 + dd];
  for (int rr = 0; rr < 16; ++rr) {
    int ll = (rr << 2) + lq;
    float a = bb + w4.x * xt[ll][dd] + w4.y * xt[ll + 1][dd] + w4.z * xt[ll + 2][dd] +
              w4.w * xt[ll + 3][dd];
    res[ll][dd] = a * __builtin_amdgcn_rcpf(1.f + __expf(-a));
  }
  __syncthreads();
  for (int idx = tid; idx < 64 * 16; idx += 256) {
    int ll = idx >> 4, q = idx & 15;
    ushort4 u;
    u.x = f2bf(res[ll][(q << 2)]);
    u.y = f2bf(res[ll][(q << 2) + 1]);
    u.z = f2bf(res[ll][(q << 2) + 2]);
    u.w = f2bf(res[ll][(q << 2) + 3]);
    *(ushort4*)&xsb[((size_t)b * L_ + l0 + ll) * DI + d0 + (q << 2)] = u;
  }
}

// ---------------- x_proj MFMA: xsb(BL,384) @ Wp(48,384)^T -> dbl f32 (cols<44) -------
__global__ __launch_bounds__(256) void k_xproj(const unsigned short* __restrict__ A,
                                               const unsigned short* __restrict__ W,
                                               float* __restrict__ dbl) {
  __shared__ unsigned short smem[4096 + 3072];
  unsigned short* As = smem;
  unsigned short* Bs = smem + 4096;
  int tid = threadIdx.x;
  int w = tid >> 6, l = tid & 63;
  int m0 = blockIdx.x << 6;
  int lr = l & 15, lk = l >> 4;
  f32x4 acc[3];
#pragma unroll
  for (int i = 0; i < 3; ++i) acc[i] = (f32x4){0.f, 0.f, 0.f, 0.f};
  for (int kt = 0; kt < 6; ++kt) {
    int k0 = kt * 64;
    if (kt) __syncthreads();
#pragma unroll
    for (int i = 0; i < 2; ++i) {
      int row = (i << 5) + (tid >> 3);
      int gc = k0 + (((tid & 7) ^ (row & 7)) << 3);
      gload16(A + (size_t)(m0 + row) * 384 + gc, &As[(i << 11) + (w << 9)]);
    }
    {
      int row = tid >> 3;
      int gc = k0 + (((tid & 7) ^ (row & 7)) << 3);
      gload16(W + (size_t)row * 384 + gc, &Bs[w << 9]);
    }
    if (w < 2) {
      int row = 32 + (tid >> 3);
      int gc = k0 + (((tid & 7) ^ (row & 7)) << 3);
      gload16(W + (size_t)row * 384 + gc, &Bs[2048 + (w << 9)]);
    }
    __syncthreads();
#pragma unroll
    for (int ks = 0; ks < 2; ++ks) {
      int s = (ks << 2) + lk;
      int ar = (w << 4) + lr;
      bf16x8 a = *(const bf16x8*)&As[ar * 64 + ((s ^ (ar & 7)) << 3)];
#pragma unroll
      for (int ni = 0; ni < 3; ++ni) {
        int br = (ni << 4) + lr;
        bf16x8 bb = *(const bf16x8*)&Bs[br * 64 + ((s ^ (br & 7)) << 3)];
        acc[ni] = MFMA16(a, bb, acc[ni]);
      }
    }
  }
#pragma unroll
  for (int ni = 0; ni < 3; ++ni)
#pragma unroll
    for (int r = 0; r < 4; ++r) {
      int col = (ni << 4) + lr;
      if (col < NDBL) dbl[(size_t)(m0 + (w << 4) + (lk << 2) + r) * NDBL + col] = acc[ni][r];
    }
}

// ---------------- scan pass A: dt_proj once (stores bf16 dt), local scan -------------
// Hloc layout: [b][chunk][n][d] bf16 -> all accesses coalesced over d.
__global__ __launch_bounds__(384) void k_scanA(const unsigned short* __restrict__ xsb,
                                               const float* __restrict__ dbl,
                                               const float* __restrict__ dw,
                                               const float* __restrict__ dbias,
                                               const float* __restrict__ A_log,
                                               unsigned short* __restrict__ dtb,
                                               unsigned short* __restrict__ Hloc,
                                               float* __restrict__ Sbuf) {
  __shared__ float Bsh[CSZ][16];
  __shared__ float dl[CSZ][12];
  int tid = threadIdx.x;
  int blk = blockIdx.x;
  int b = blk >> 8;
  int chunk = blk & (NCHUNK - 1);
  int l0 = chunk * CSZ;
  for (int idx = tid; idx < CSZ * 28; idx += 384) {
    int r = idx / 28, c = idx - r * 28;
    float v = dbl[((size_t)b * L_ + l0 + r) * NDBL + c];
    if (c < 12) dl[r][c] = v; else Bsh[r][c - 12] = v;
  }
  int d = tid;
  float4 wv0 = *(const float4*)&dw[d * 12];
  float4 wv1 = *(const float4*)&dw[d * 12 + 4];
  float4 wv2 = *(const float4*)&dw[d * 12 + 8];
  float bias = dbias[d];
  bool fast = true;
#pragma unroll
  for (int n = 0; n < 16; ++n) {
    float An_ = -__expf(A_log[d * 16 + n]);
    fast = fast && (fabsf(An_ + (float)(n + 1)) < 2e-3f);
  }
  const unsigned short* xp = xsb + ((size_t)b * L_ + l0) * DI + d;
  unsigned short* dtp = dtb + ((size_t)b * L_ + l0) * DI + d;
  __syncthreads();
  float h[16];
#pragma unroll
  for (int n = 0; n < 16; ++n) h[n] = 0.f;
  float S = 0.f;
  if (fast) {
#pragma unroll
    for (int i = 0; i < CSZ; ++i) {
      float4 c0 = *(const float4*)&dl[i][0];
      float4 c1 = *(const float4*)&dl[i][4];
      float4 c2 = *(const float4*)&dl[i][8];
      float a = bias;
      a = fmaf(wv0.x, c0.x, a); a = fmaf(wv0.y, c0.y, a);
      a = fmaf(wv0.z, c0.z, a); a = fmaf(wv0.w, c0.w, a);
      a = fmaf(wv1.x, c1.x, a); a = fmaf(wv1.y, c1.y, a);
      a = fmaf(wv1.z, c1.z, a); a = fmaf(wv1.w, c1.w, a);
      a = fmaf(wv2.x, c2.x, a); a = fmaf(wv2.y, c2.y, a);
      a = fmaf(wv2.z, c2.z, a); a = fmaf(wv2.w, c2.w, a);
      float sp = fmaxf(a, 0.f) + __logf(1.f + __expf(-fabsf(a)));
      dtp[(size_t)i * DI] = f2bf(sp);
      S += sp;
      float xv = bf2f(xp[(size_t)i * DI]);
      float dtx = sp * xv;
      float r = __expf(-sp);
      float r2 = r * r;
      float r4 = r2 * r2;
      float dA0 = r, dA1 = r2, dA2 = r2 * r, dA3 = r4;
#pragma unroll
      for (int g = 0; g < 4; ++g) {
        float4 Bg = *(const float4*)&Bsh[i][g << 2];
        h[(g << 2) + 0] = fmaf(dA0, h[(g << 2) + 0], dtx * Bg.x);
        h[(g << 2) + 1] = fmaf(dA1, h[(g << 2) + 1], dtx * Bg.y);
        h[(g << 2) + 2] = fmaf(dA2, h[(g << 2) + 2], dtx * Bg.z);
        h[(g << 2) + 3] = fmaf(dA3, h[(g << 2) + 3], dtx * Bg.w);
        if (g < 3) { dA0 *= r4; dA1 *= r4; dA2 *= r4; dA3 *= r4; }
      }
    }
  } else {
    float An[16];
#pragma unroll
    for (int n = 0; n < 16; ++n) An[n] = -__expf(A_log[d * 16 + n]);
#pragma unroll
    for (int i = 0; i < CSZ; ++i) {
      float4 c0 = *(const float4*)&dl[i][0];
      float4 c1 = *(const float4*)&dl[i][4];
      float4 c2 = *(const float4*)&dl[i][8];
      float a = bias;
      a = fmaf(wv0.x, c0.x, a); a = fmaf(wv0.y, c0.y, a);
      a = fmaf(wv0.z, c0.z, a); a = fmaf(wv0.w, c0.w, a);
      a = fmaf(wv1.x, c1.x, a); a = fmaf(wv1.y, c1.y, a);
      a = fmaf(wv1.z, c1.z, a); a = fmaf(wv1.w, c1.w, a);
      a = fmaf(wv2.x, c2.x, a); a = fmaf(wv2.y, c2.y, a);
      a = fmaf(wv2.z, c2.z, a); a = fmaf(wv2.w, c2.w, a);
      float sp = fmaxf(a, 0.f) + __logf(1.f + __expf(-fabsf(a)));
      dtp[(size_t)i * DI] = f2bf(sp);
      S += sp;
      float xv = bf2f(xp[(size_t)i * DI]);
      float dtx = sp * xv;
#pragma unroll
      for (int n = 0; n < 16; ++n)
        h[n] = fmaf(__expf(sp * An[n]), h[n], dtx * Bsh[i][n]);
    }
  }
  size_t hbase = ((size_t)(b * NCHUNK + chunk) * 16) * DI + d;
#pragma unroll
  for (int n = 0; n < 16; ++n) Hloc[hbase + (size_t)n * DI] = f2bf(h[n]);
  Sbuf[((size_t)b * NCHUNK + chunk) * DI + d] = S;
}

// ---------------- scan pass B: chunk recurrence in-place (bf16), pipelined -----------
__global__ __launch_bounds__(256) void k_scanB(const float* __restrict__ A_log,
                                               unsigned short* __restrict__ Hloc,
                                               const float* __restrict__ Sbuf) {
  int gid = blockIdx.x * 256 + threadIdx.x;  // B*16*DI = 24576
  int d = gid % DI;
  int rest = gid / DI;
  int n = rest & 15;
  int b = rest >> 4;
  float An = -__expf(A_log[d * 16 + n]);
  unsigned short* Hp = Hloc + ((size_t)b * NCHUNK * 16 + n) * DI + d;
  const float* Sp = Sbuf + (size_t)b * NCHUNK * DI + d;
  constexpr size_t HS = (size_t)16 * DI;
  float h = 0.f;
  float SA[8], HA[8], SB[8], HB[8];
#define LDGRP(Sa, Ha, cb)                         \
  _Pragma("unroll") for (int u = 0; u < 8; ++u) { \
    Sa[u] = Sp[(size_t)((cb) + u) * DI];          \
    Ha[u] = bf2f(Hp[(size_t)((cb) + u) * HS]);    \
  }
#define STGRP(Sa, Ha, cb)                         \
  _Pragma("unroll") for (int u = 0; u < 8; ++u) { \
    Hp[(size_t)((cb) + u) * HS] = f2bf(h);        \
    h = fmaf(__expf(An * Sa[u]), h, Ha[u]);       \
  }
  LDGRP(SA, HA, 0)
  for (int g = 0; g < 32; g += 2) {
    LDGRP(SB, HB, (g + 1) * 8)
    STGRP(SA, HA, g * 8)
    if (g + 2 < 32) LDGRP(SA, HA, (g + 2) * 8)
    STGRP(SB, HB, (g + 1) * 8)
  }
#undef LDGRP
#undef STGRP
}

// ---------------- scan pass C: local scan + carry + y/gating (bf16 dt) ---------------
__global__ __launch_bounds__(384) void k_scanC(const unsigned short* __restrict__ xsb,
                                               const unsigned short* __restrict__ dtb,
                                               const float* __restrict__ dbl,
                                               const unsigned short* __restrict__ z,
                                               const float* __restrict__ A_log,
                                               const float* __restrict__ Dw,
                                               const unsigned short* __restrict__ Hloc,
                                               unsigned short* __restrict__ ybuf) {
  __shared__ float BCsh[CSZ][32];  // [r][0:16]=B, [r][16:32]=C
  int tid = threadIdx.x;
  int blk = blockIdx.x;
  int b = blk >> 8;
  int chunk = blk & (NCHUNK - 1);
  int l0 = chunk * CSZ;
  for (int idx = tid; idx < CSZ * 32; idx += 384) {
    int r = idx >> 5, n32 = idx & 31;
    BCsh[r][n32] = dbl[((size_t)b * L_ + l0 + r) * NDBL + DTR + n32];
  }
  int d = tid;
  float Dd = Dw[d];
  bool fast = true;
#pragma unroll
  for (int n = 0; n < 16; ++n) {
    float An_ = -__expf(A_log[d * 16 + n]);
    fast = fast && (fabsf(An_ + (float)(n + 1)) < 2e-3f);
  }
  size_t hbase = ((size_t)(b * NCHUNK + chunk) * 16) * DI + d;
  float h[16];
#pragma unroll
  for (int n = 0; n < 16; ++n) h[n] = bf2f(Hloc[hbase + (size_t)n * DI]);
  const unsigned short* xp = xsb + ((size_t)b * L_ + l0) * DI + d;
  const unsigned short* dtp = dtb + ((size_t)b * L_ + l0) * DI + d;
  const unsigned short* zp = z + ((size_t)b * L_ + l0) * DI + d;
  unsigned short* yp = ybuf + ((size_t)b * L_ + l0) * DI + d;
  __syncthreads();
  if (fast) {
#pragma unroll
    for (int i = 0; i < CSZ; ++i) {
      float sp = bf2f(dtp[(size_t)i * DI]);
      float xv = bf2f(xp[(size_t)i * DI]);
      float zv = bf2f(zp[(size_t)i * DI]);
      float dtx = sp * xv;
      float r = __expf(-sp);
      float r2 = r * r;
      float r4 = r2 * r2;
      float dA0 = r, dA1 = r2, dA2 = r2 * r, dA3 = r4;
      float y = 0.f;
#pragma unroll
      for (int g = 0; g < 4; ++g) {
        float4 Bg = *(const float4*)&BCsh[i][g << 2];
        float4 Cg = *(const float4*)&BCsh[i][16 + (g << 2)];
        h[(g << 2) + 0] = fmaf(dA0, h[(g << 2) + 0], dtx * Bg.x);
        h[(g << 2) + 1] = fmaf(dA1, h[(g << 2) + 1], dtx * Bg.y);
        h[(g << 2) + 2] = fmaf(dA2, h[(g << 2) + 2], dtx * Bg.z);
        h[(g << 2) + 3] = fmaf(dA3, h[(g << 2) + 3], dtx * Bg.w);
        y = fmaf(h[(g << 2) + 0], Cg.x, y);
        y = fmaf(h[(g << 2) + 1], Cg.y, y);
        y = fmaf(h[(g << 2) + 2], Cg.z, y);
        y = fmaf(h[(g << 2) + 3], Cg.w, y);
        if (g < 3) { dA0 *= r4; dA1 *= r4; dA2 *= r4; dA3 *= r4; }
      }
      y = fmaf(xv, Dd, y);
      float sig = __builtin_amdgcn_rcpf(1.f + __expf(-zv));
      yp[(size_t)i * DI] = f2bf(y * (zv * sig));
    }
  } else {
    float An[16];
#pragma unroll
    for (int n = 0; n < 16; ++n) An[n] = -__expf(A_log[d * 16 + n]);
#pragma unroll
    for (int i = 0; i < CSZ; ++i) {
      float sp = bf2f(dtp[(size_t)i * DI]);
      float xv = bf2f(xp[(size_t)i * DI]);
      float zv = bf2f(zp[(size_t)i * DI]);
      float dtx = sp * xv;
      float y = 0.f;
#pragma unroll
      for (int n = 0; n < 16; ++n) {
        h[n] = fmaf(__expf(sp * An[n]), h[n], dtx * BCsh[i][n]);
        y = fmaf(h[n], BCsh[i][16 + n], y);
      }
      y = fmaf(xv, Dd, y);
      float sig = __builtin_amdgcn_rcpf(1.f + __expf(-zv));
      yp[(size_t)i * DI] = f2bf(y * (zv * sig));
    }
  }
}

// ---------------- out_proj MFMA + residual: ybuf(BL,384) @ W(192,384)^T + x ----------
__global__ __launch_bounds__(256) void k_outproj(const unsigned short* __restrict__ Y,
                                                 const unsigned short* __restrict__ W,
                                                 const float* __restrict__ x,
                                                 float* __restrict__ out) {
  __shared__ float smemf[8448];
  unsigned short* As = (unsigned short*)smemf;
  unsigned short* Bs = (unsigned short*)smemf + 8192;
  int tid = threadIdx.x;
  int w = tid >> 6, l = tid & 63;
  int wr = w >> 1, wc = w & 1;
  int m0 = blockIdx.x << 7;
  int n0 = blockIdx.y << 6;
  int lr = l & 15, lk = l >> 4;
  f32x4 acc[4][2];
#pragma unroll
  for (int i = 0; i < 4; ++i)
#pragma unroll
    for (int j = 0; j < 2; ++j) acc[i][j] = (f32x4){0.f, 0.f, 0.f, 0.f};
  for (int kt = 0; kt < 6; ++kt) {
    int k0 = kt * 64;
    if (kt) __syncthreads();
#pragma unroll
    for (int i = 0; i < 4; ++i) {
      int row = (i << 5) + (tid >> 3);
      int gc = k0 + (((tid & 7) ^ (row & 7)) << 3);
      gload16(Y + (size_t)(m0 + row) * 384 + gc, &As[(i << 11) + (w << 9)]);
    }
#pragma unroll
    for (int i = 0; i < 2; ++i) {
      int row = (i << 5) + (tid >> 3);
      int gc = k0 + (((tid & 7) ^ (row & 7)) << 3);
      gload16(W + (size_t)(n0 + row) * 384 + gc, &Bs[(i << 11) + (w << 9)]);
    }
    __syncthreads();
#pragma unroll
    for (int ks = 0; ks < 2; ++ks) {
      int s = (ks << 2) + lk;
      bf16x8 bfr[2];
#pragma unroll
      for (int ni = 0; ni < 2; ++ni) {
        int r = (wc << 5) + (ni << 4) + lr;
        bfr[ni] = *(const bf16x8*)&Bs[r * 64 + ((s ^ (r & 7)) << 3)];
      }
#pragma unroll
      for (int mi = 0; mi < 4; ++mi) {
        int r = (wr << 6) + (mi << 4) + lr;
        bf16x8 a = *(const bf16x8*)&As[r * 64 + ((s ^ (r & 7)) << 3)];
#pragma unroll
        for (int ni = 0; ni < 2; ++ni) acc[mi][ni] = MFMA16(a, bfr[ni], acc[mi][ni]);
      }
    }
  }
  __syncthreads();
#pragma unroll
  for (int mi = 0; mi < 4; ++mi)
#pragma unroll
    for (int ni = 0; ni < 2; ++ni) {
      int c = (wc << 5) + (ni << 4) + lr;
      int lrow = (wr << 6) + (mi << 4) + (lk << 2);
      *(f32x4*)&smemf[c * 132 + lrow] = acc[mi][ni];
    }
  __syncthreads();
  int b = m0 >> 12;
  int l0 = m0 & (L_ - 1);
#pragma unroll
  for (int i = 0; i < 8; ++i) {
    int chunk = i * 256 + tid;
    int c = chunk >> 5, lq = chunk & 31;
    f32x4 v = *(const f32x4*)&smemf[c * 132 + (lq << 2)];
    size_t off = ((size_t)b * C_ + n0 + c) * L_ + l0 + (lq << 2);
    f32x4 xv = *(const f32x4*)&x[off];
    v = v + xv;
    *(f32x4*)&out[off] = v;
  }
}

extern "C" void kernel_launch(void* const* d_in, const int* in_sizes, int n_in,
                              void* d_out, int out_size, void* d_ws, size_t ws_size,
                              hipStream_t stream) {
  const float* x         = (const float*)d_in[0];
  const float* norm_w    = (const float*)d_in[1];
  const float* norm_b    = (const float*)d_in[2];
  const float* in_proj_w = (const float*)d_in[3];
  const float* conv_w    = (const float*)d_in[4];
  const float* conv_b    = (const float*)d_in[5];
  const float* x_proj_w  = (const float*)d_in[6];
  const float* dt_proj_w = (const float*)d_in[7];
  const float* dt_proj_b = (const float*)d_in[8];
  const float* A_log     = (const float*)d_in[9];
  const float* Dw        = (const float*)d_in[10];
  const float* out_proj_w= (const float*)d_in[11];
  float* out = (float*)d_out;
  float* ws = (float*)d_ws;

  unsigned short* seqn = (unsigned short*)(ws + F_SEQN);
  unsigned short* xin  = (unsigned short*)(ws + F_XIN);
  unsigned short* z    = (unsigned short*)(ws + F_Z);
  unsigned short* xsb  = (unsigned short*)(ws + F_XSB);
  float* dbl           = ws + F_DBL;
  unsigned short* dtb  = (unsigned short*)(ws + F_DT);
  float* Sbuf          = ws + F_SBUF;
  unsigned short* Hloc = (unsigned short*)(ws + F_HLOC);
  unsigned short* wbuf = (unsigned short*)(ws + F_WBUF);
  unsigned short* ipw  = wbuf;
  unsigned short* xpw  = wbuf + 147456;
  unsigned short* opw  = wbuf + 165888;
  unsigned short* ybuf = xin;  // xin dead after conv

  hipLaunchKernelGGL(k_ln, dim3(1192), dim3(256), 0, stream, x, norm_w, norm_b, seqn,
                     in_proj_w, x_proj_w, out_proj_w, wbuf);
  hipLaunchKernelGGL(k_inproj, dim3(128, 6), dim3(256), 0, stream, seqn, ipw, xin, z);
  hipLaunchKernelGGL(k_conv, dim3(6, 64, 4), dim3(256), 0, stream, xin, conv_w, conv_b, xsb);
  hipLaunchKernelGGL(k_xproj, dim3(256), dim3(256), 0, stream, xsb, xpw, dbl);
  hipLaunchKernelGGL(k_scanA, dim3(1024), dim3(384), 0, stream, xsb, dbl, dt_proj_w, dt_proj_b,
                     A_log, dtb, Hloc, Sbuf);
  hipLaunchKernelGGL(k_scanB, dim3(96), dim3(256), 0, stream, A_log, Hloc, Sbuf);
  hipLaunchKernelGGL(k_scanC, dim3(1024), dim3(384), 0, stream, xsb, dtb, dbl, z, A_log, Dw,
                     Hloc, ybuf);
  hipLaunchKernelGGL(k_outproj, dim3(128, 3), dim3(256), 0, stream, ybuf, opw, x, out);
}

// Round 7
// 111.585 us; speedup vs baseline: 4.4689x; 1.0171x over previous
//
#include <hip/hip_runtime.h>
#include <hip/hip_bf16.h>

// Problem constants
constexpr int B_ = 4;
constexpr int C_ = 192;
constexpr int L_ = 4096;     // H*W
constexpr int DI = 384;      // d_inner
constexpr int DSs = 16;      // d_state
constexpr int DTR = 12;      // dt_rank
constexpr int NDBL = 44;     // dt_rank + 2*d_state
constexpr int NCHUNK = 256;  // scan chunks
constexpr int CSZ = 16;      // chunk size

constexpr size_t BL = (size_t)B_ * L_;  // 16384

// Workspace offsets in FLOAT units (bf16 buffers counted at half)
constexpr size_t F_SEQN = 0;                                  // bf16 BL*C
constexpr size_t F_XIN  = F_SEQN + BL * C_ / 2;               // bf16 BL*DI (reused as ybuf)
constexpr size_t F_Z    = F_XIN + BL * DI / 2;                // bf16 BL*DI
constexpr size_t F_XSB  = F_Z + BL * DI / 2;                  // bf16 BL*DI
constexpr size_t F_DBL  = F_XSB + BL * DI / 2;                // f32  BL*NDBL
constexpr size_t F_DT   = F_DBL + BL * NDBL;                  // bf16 BL*DI
constexpr size_t F_SBUF = F_DT + BL * DI / 2;                 // f32  B*NCHUNK*DI
constexpr size_t F_HLOC = F_SBUF + (size_t)B_ * NCHUNK * DI;  // bf16 B*NCHUNK*16*DI
constexpr size_t F_WBUF = F_HLOC + (size_t)B_ * NCHUNK * DI * 16 / 2;  // bf16 weights
// total ~= 74 MB (prior rounds used 129 MB: safe)

typedef __attribute__((ext_vector_type(8))) short bf16x8;
typedef __attribute__((ext_vector_type(4))) float f32x4;

__device__ __forceinline__ unsigned short f2bf(float v) {
  unsigned x = __builtin_bit_cast(unsigned, v);
  unsigned r = x + 0x7FFFu + ((x >> 16) & 1u);   // RNE
  return (unsigned short)(r >> 16);
}
__device__ __forceinline__ float bf2f(unsigned short u) {
  return __builtin_bit_cast(float, (unsigned)u << 16);
}
__device__ __forceinline__ void gload16(const void* g, void* l) {
  __builtin_amdgcn_global_load_lds((const __attribute__((address_space(1))) void*)g,
                                   (__attribute__((address_space(3))) void*)l, 16, 0, 0);
}
#define MFMA16(a, b, c) __builtin_amdgcn_mfma_f32_16x16x32_bf16(a, b, c, 0, 0, 0)

// ---------------- LayerNorm (blocks 0..255, bf16 LDS tile) + weight cvt tail ---------
__global__ __launch_bounds__(256) void k_ln(const float* __restrict__ x,
                                            const float* __restrict__ nw,
                                            const float* __restrict__ nb,
                                            unsigned short* __restrict__ seqn,
                                            const float* __restrict__ ipw,
                                            const float* __restrict__ xpw,
                                            const float* __restrict__ opw,
                                            unsigned short* __restrict__ wbuf) {
  if (blockIdx.x >= 256) {
    int t = (blockIdx.x - 256) * 256 + threadIdx.x;
    if (t < 239616) {
      float v;
      if (t < 147456) v = ipw[t];
      else if (t < 165888) {
        int j = t - 147456;
        int r = j / 384, c = j - r * 384;
        v = (r < 44) ? xpw[r * 384 + c] : 0.f;
      } else v = opw[t - 165888];
      wbuf[t] = f2bf(v);
    }
    return;
  }
  __shared__ unsigned short xt[192][66];
  __shared__ float ps[4][64], ps2[4][64];
  __shared__ float mu_[64], rs_[64];
  __shared__ float wsh[192], bsh[192];
  int tid = threadIdx.x;
  int blk = blockIdx.x;
  int b = blk >> 6;
  int l0 = (blk & 63) << 6;
  const float* xb = x + (size_t)b * C_ * L_;
  for (int idx = tid; idx < 192 * 16; idx += 256) {
    int c = idx >> 4, lq = idx & 15;
    float4 v = *(const float4*)&xb[(size_t)c * L_ + l0 + (lq << 2)];
    ushort2 u0, u1;
    u0.x = f2bf(v.x); u0.y = f2bf(v.y);
    u1.x = f2bf(v.z); u1.y = f2bf(v.w);
    *(ushort2*)&xt[c][(lq << 2)] = u0;
    *(ushort2*)&xt[c][(lq << 2) + 2] = u1;
  }
  if (tid < 192) { wsh[tid] = nw[tid]; bsh[tid] = nb[tid]; }
  __syncthreads();
  int ll = tid & 63, q = tid >> 6;
  float s = 0.f, ss = 0.f;
  for (int c = q * 48; c < q * 48 + 48; ++c) {
    float v = bf2f(xt[c][ll]);
    s += v; ss += v * v;
  }
  ps[q][ll] = s; ps2[q][ll] = ss;
  __syncthreads();
  if (q == 0) {
    float st = ps[0][ll] + ps[1][ll] + ps[2][ll] + ps[3][ll];
    float sst = ps2[0][ll] + ps2[1][ll] + ps2[2][ll] + ps2[3][ll];
    float mu = st * (1.f / 192.f);
    float var = sst * (1.f / 192.f) - mu * mu;
    mu_[ll] = mu; rs_[ll] = rsqrtf(var + 1e-5f);
  }
  __syncthreads();
  unsigned short* so = seqn + ((size_t)b * L_ + l0) * C_;
  for (int idx = tid; idx < 64 * 192; idx += 256) {
    int l = idx / 192, c = idx - l * 192;
    so[idx] = f2bf((bf2f(xt[c][l]) - mu_[l]) * rs_[l] * wsh[c] + bsh[c]);
  }
}

// ---------------- in_proj MFMA: seqn(BL,192)bf16 @ W(768,192)^T -> xin,z bf16 --------
__global__ __launch_bounds__(256) void k_inproj(const unsigned short* __restrict__ A,
                                                const unsigned short* __restrict__ W,
                                                unsigned short* __restrict__ xin,
                                                unsigned short* __restrict__ z) {
  __shared__ unsigned short smem[16384];
  unsigned short* As = smem;
  unsigned short* Bs = smem + 8192;
  int tid = threadIdx.x;
  int w = tid >> 6, l = tid & 63;
  int wr = w >> 1, wc = w & 1;
  int m0 = blockIdx.x << 7;
  int n0 = blockIdx.y << 7;
  f32x4 acc[4][4];
#pragma unroll
  for (int i = 0; i < 4; ++i)
#pragma unroll
    for (int j = 0; j < 4; ++j) acc[i][j] = (f32x4){0.f, 0.f, 0.f, 0.f};
  int lr = l & 15, lk = l >> 4;
  for (int kt = 0; kt < 3; ++kt) {
    int k0 = kt * 64;
    if (kt) __syncthreads();
#pragma unroll
    for (int i = 0; i < 4; ++i) {
      int row = (i << 5) + (tid >> 3);
      int gc = k0 + (((tid & 7) ^ (row & 7)) << 3);
      gload16(A + (size_t)(m0 + row) * 192 + gc, &As[(i << 11) + (w << 9)]);
      gload16(W + (size_t)(n0 + row) * 192 + gc, &Bs[(i << 11) + (w << 9)]);
    }
    __syncthreads();
#pragma unroll
    for (int ks = 0; ks < 2; ++ks) {
      int s = (ks << 2) + lk;
      bf16x8 af[4], bfr[4];
#pragma unroll
      for (int mi = 0; mi < 4; ++mi) {
        int r = (wr << 6) + (mi << 4) + lr;
        af[mi] = *(const bf16x8*)&As[r * 64 + ((s ^ (r & 7)) << 3)];
      }
#pragma unroll
      for (int ni = 0; ni < 4; ++ni) {
        int r = (wc << 6) + (ni << 4) + lr;
        bfr[ni] = *(const bf16x8*)&Bs[r * 64 + ((s ^ (r & 7)) << 3)];
      }
#pragma unroll
      for (int mi = 0; mi < 4; ++mi)
#pragma unroll
        for (int ni = 0; ni < 4; ++ni) acc[mi][ni] = MFMA16(af[mi], bfr[ni], acc[mi][ni]);
    }
  }
  __syncthreads();
#pragma unroll
  for (int mi = 0; mi < 4; ++mi)
#pragma unroll
    for (int ni = 0; ni < 4; ++ni) {
      int col = (wc << 6) + (ni << 4) + lr;
#pragma unroll
      for (int r = 0; r < 4; ++r) {
        int row = (wr << 6) + (mi << 4) + (lk << 2) + r;
        smem[(row << 7) + col] = f2bf(acc[mi][ni][r]);
      }
    }
  __syncthreads();
#pragma unroll
  for (int i = 0; i < 8; ++i) {
    int chunk = i * 256 + tid;
    int row = chunk >> 4, cq = chunk & 15;
    int n = n0 + (cq << 3);
    unsigned short* dst = (n < 384) ? (xin + (size_t)(m0 + row) * DI + n)
                                    : (z + (size_t)(m0 + row) * DI + (n - 384));
    *(bf16x8*)dst = *(const bf16x8*)&smem[(row << 7) + (cq << 3)];
  }
}

// ---------------- fused conv(4)+SiLU+x_proj: xin -> xsb (global) + dbl ---------------
__global__ __launch_bounds__(384) void k_convx(const unsigned short* __restrict__ xin,
                                               const float* __restrict__ cw,
                                               const float* __restrict__ cb,
                                               const unsigned short* __restrict__ W,
                                               unsigned short* __restrict__ xsb,
                                               float* __restrict__ dbl) {
  __shared__ unsigned short xs[6 * 4096];  // 6 K-tiles [64 rows][64 cols], XOR-swizzled
  __shared__ unsigned short Bs[3072];      // 48 x 64 per K-step
  int tid = threadIdx.x;
  int w = tid >> 6, l = tid & 63;
  int b = blockIdx.y;
  int l0 = blockIdx.x << 6;
  int d = tid;  // 0..383
  // ---- conv phase ----
  float4 w4 = *(const float4*)&cw[d * 4];
  float bb = cb[d];
  const unsigned short* xp = xin + ((size_t)b * L_ + l0) * DI + d;
  unsigned short* op = xsb + ((size_t)b * L_ + l0) * DI + d;
  float x0 = 0.f, x1 = 0.f, x2 = 0.f;
  if (l0 > 0) {
    x0 = bf2f(*(xp - 3 * DI));
    x1 = bf2f(*(xp - 2 * DI));
    x2 = bf2f(*(xp - DI));
  }
  int kt = d >> 6, col = d & 63, g = col >> 3, e = col & 7;
  unsigned short* xsrow = xs + kt * 4096;
  for (int r = 0; r < 64; ++r) {
    float xv = bf2f(xp[(size_t)r * DI]);
    float a = bb + w4.x * x0 + w4.y * x1 + w4.z * x2 + w4.w * xv;
    float sv = a * __builtin_amdgcn_rcpf(1.f + __expf(-a));
    unsigned short sb = f2bf(sv);
    xsrow[r * 64 + ((g ^ (r & 7)) << 3) + e] = sb;
    op[(size_t)r * DI] = sb;
    x0 = x1; x1 = x2; x2 = xv;
  }
  __syncthreads();
  // ---- x_proj phase (waves 0..3 compute; all stage Bs) ----
  int lr = l & 15, lk = l >> 4;
  f32x4 acc[3];
#pragma unroll
  for (int i = 0; i < 3; ++i) acc[i] = (f32x4){0.f, 0.f, 0.f, 0.f};
  for (int kt2 = 0; kt2 < 6; ++kt2) {
    int k0 = kt2 * 64;
    if (kt2) __syncthreads();
    {
      int row = tid >> 3;  // 0..47
      int gc = k0 + (((tid & 7) ^ (row & 7)) << 3);
      gload16(W + (size_t)row * 384 + gc, &Bs[w << 9]);
    }
    __syncthreads();
    if (w < 4) {
#pragma unroll
      for (int ks = 0; ks < 2; ++ks) {
        int s = (ks << 2) + lk;
        int ar = (w << 4) + lr;
        bf16x8 a = *(const bf16x8*)&xs[kt2 * 4096 + ar * 64 + ((s ^ (ar & 7)) << 3)];
#pragma unroll
        for (int ni = 0; ni < 3; ++ni) {
          int br = (ni << 4) + lr;
          bf16x8 bbv = *(const bf16x8*)&Bs[br * 64 + ((s ^ (br & 7)) << 3)];
          acc[ni] = MFMA16(a, bbv, acc[ni]);
        }
      }
    }
  }
  if (w < 4) {
#pragma unroll
    for (int ni = 0; ni < 3; ++ni)
#pragma unroll
      for (int r = 0; r < 4; ++r) {
        int colq = (ni << 4) + lr;
        if (colq < NDBL)
          dbl[((size_t)b * L_ + l0 + (w << 4) + (lk << 2) + r) * NDBL + colq] = acc[ni][r];
      }
  }
}

// ---------------- scan pass A: dt_proj once (stores bf16 dt), local scan -------------
// Hloc layout: [b][chunk][n][d] bf16 -> all accesses coalesced over d.
__global__ __launch_bounds__(384) void k_scanA(const unsigned short* __restrict__ xsb,
                                               const float* __restrict__ dbl,
                                               const float* __restrict__ dw,
                                               const float* __restrict__ dbias,
                                               const float* __restrict__ A_log,
                                               unsigned short* __restrict__ dtb,
                                               unsigned short* __restrict__ Hloc,
                                               float* __restrict__ Sbuf) {
  __shared__ float Bsh[CSZ][16];
  __shared__ float dl[CSZ][12];
  int tid = threadIdx.x;
  int blk = blockIdx.x;
  int b = blk >> 8;
  int chunk = blk & (NCHUNK - 1);
  int l0 = chunk * CSZ;
  for (int idx = tid; idx < CSZ * 28; idx += 384) {
    int r = idx / 28, c = idx - r * 28;
    float v = dbl[((size_t)b * L_ + l0 + r) * NDBL + c];
    if (c < 12) dl[r][c] = v; else Bsh[r][c - 12] = v;
  }
  int d = tid;
  float4 wv0 = *(const float4*)&dw[d * 12];
  float4 wv1 = *(const float4*)&dw[d * 12 + 4];
  float4 wv2 = *(const float4*)&dw[d * 12 + 8];
  float bias = dbias[d];
  bool fast = true;
#pragma unroll
  for (int n = 0; n < 16; ++n) {
    float An_ = -__expf(A_log[d * 16 + n]);
    fast = fast && (fabsf(An_ + (float)(n + 1)) < 2e-3f);
  }
  const unsigned short* xp = xsb + ((size_t)b * L_ + l0) * DI + d;
  unsigned short* dtp = dtb + ((size_t)b * L_ + l0) * DI + d;
  __syncthreads();
  float h[16];
#pragma unroll
  for (int n = 0; n < 16; ++n) h[n] = 0.f;
  float S = 0.f;
  if (fast) {
#pragma unroll
    for (int i = 0; i < CSZ; ++i) {
      float4 c0 = *(const float4*)&dl[i][0];
      float4 c1 = *(const float4*)&dl[i][4];
      float4 c2 = *(const float4*)&dl[i][8];
      float a = bias;
      a = fmaf(wv0.x, c0.x, a); a = fmaf(wv0.y, c0.y, a);
      a = fmaf(wv0.z, c0.z, a); a = fmaf(wv0.w, c0.w, a);
      a = fmaf(wv1.x, c1.x, a); a = fmaf(wv1.y, c1.y, a);
      a = fmaf(wv1.z, c1.z, a); a = fmaf(wv1.w, c1.w, a);
      a = fmaf(wv2.x, c2.x, a); a = fmaf(wv2.y, c2.y, a);
      a = fmaf(wv2.z, c2.z, a); a = fmaf(wv2.w, c2.w, a);
      float sp = fmaxf(a, 0.f) + __logf(1.f + __expf(-fabsf(a)));
      dtp[(size_t)i * DI] = f2bf(sp);
      S += sp;
      float xv = bf2f(xp[(size_t)i * DI]);
      float dtx = sp * xv;
      float r = __expf(-sp);
      float r2 = r * r;
      float r4 = r2 * r2;
      float dA0 = r, dA1 = r2, dA2 = r2 * r, dA3 = r4;
#pragma unroll
      for (int g = 0; g < 4; ++g) {
        float4 Bg = *(const float4*)&Bsh[i][g << 2];
        h[(g << 2) + 0] = fmaf(dA0, h[(g << 2) + 0], dtx * Bg.x);
        h[(g << 2) + 1] = fmaf(dA1, h[(g << 2) + 1], dtx * Bg.y);
        h[(g << 2) + 2] = fmaf(dA2, h[(g << 2) + 2], dtx * Bg.z);
        h[(g << 2) + 3] = fmaf(dA3, h[(g << 2) + 3], dtx * Bg.w);
        if (g < 3) { dA0 *= r4; dA1 *= r4; dA2 *= r4; dA3 *= r4; }
      }
    }
  } else {
    float An[16];
#pragma unroll
    for (int n = 0; n < 16; ++n) An[n] = -__expf(A_log[d * 16 + n]);
#pragma unroll
    for (int i = 0; i < CSZ; ++i) {
      float4 c0 = *(const float4*)&dl[i][0];
      float4 c1 = *(const float4*)&dl[i][4];
      float4 c2 = *(const float4*)&dl[i][8];
      float a = bias;
      a = fmaf(wv0.x, c0.x, a); a = fmaf(wv0.y, c0.y, a);
      a = fmaf(wv0.z, c0.z, a); a = fmaf(wv0.w, c0.w, a);
      a = fmaf(wv1.x, c1.x, a); a = fmaf(wv1.y, c1.y, a);
      a = fmaf(wv1.z, c1.z, a); a = fmaf(wv1.w, c1.w, a);
      a = fmaf(wv2.x, c2.x, a); a = fmaf(wv2.y, c2.y, a);
      a = fmaf(wv2.z, c2.z, a); a = fmaf(wv2.w, c2.w, a);
      float sp = fmaxf(a, 0.f) + __logf(1.f + __expf(-fabsf(a)));
      dtp[(size_t)i * DI] = f2bf(sp);
      S += sp;
      float xv = bf2f(xp[(size_t)i * DI]);
      float dtx = sp * xv;
#pragma unroll
      for (int n = 0; n < 16; ++n)
        h[n] = fmaf(__expf(sp * An[n]), h[n], dtx * Bsh[i][n]);
    }
  }
  size_t hbase = ((size_t)(b * NCHUNK + chunk) * 16) * DI + d;
#pragma unroll
  for (int n = 0; n < 16; ++n) Hloc[hbase + (size_t)n * DI] = f2bf(h[n]);
  Sbuf[((size_t)b * NCHUNK + chunk) * DI + d] = S;
}

// ---------------- scan pass B: chunk recurrence in-place (bf16), pipelined -----------
__global__ __launch_bounds__(256) void k_scanB(const float* __restrict__ A_log,
                                               unsigned short* __restrict__ Hloc,
                                               const float* __restrict__ Sbuf) {
  int gid = blockIdx.x * 256 + threadIdx.x;  // B*16*DI = 24576
  int d = gid % DI;
  int rest = gid / DI;
  int n = rest & 15;
  int b = rest >> 4;
  float An = -__expf(A_log[d * 16 + n]);
  unsigned short* Hp = Hloc + ((size_t)b * NCHUNK * 16 + n) * DI + d;
  const float* Sp = Sbuf + (size_t)b * NCHUNK * DI + d;
  constexpr size_t HS = (size_t)16 * DI;
  float h = 0.f;
  float SA[8], HA[8], SB[8], HB[8];
#define LDGRP(Sa, Ha, cb)                         \
  _Pragma("unroll") for (int u = 0; u < 8; ++u) { \
    Sa[u] = Sp[(size_t)((cb) + u) * DI];          \
    Ha[u] = bf2f(Hp[(size_t)((cb) + u) * HS]);    \
  }
#define STGRP(Sa, Ha, cb)                         \
  _Pragma("unroll") for (int u = 0; u < 8; ++u) { \
    Hp[(size_t)((cb) + u) * HS] = f2bf(h);        \
    h = fmaf(__expf(An * Sa[u]), h, Ha[u]);       \
  }
  LDGRP(SA, HA, 0)
  for (int g = 0; g < 32; g += 2) {
    LDGRP(SB, HB, (g + 1) * 8)
    STGRP(SA, HA, g * 8)
    if (g + 2 < 32) LDGRP(SA, HA, (g + 2) * 8)
    STGRP(SB, HB, (g + 1) * 8)
  }
#undef LDGRP
#undef STGRP
}

// ---------------- scan pass C: local scan + carry + y/gating (bf16 dt) ---------------
__global__ __launch_bounds__(384) void k_scanC(const unsigned short* __restrict__ xsb,
                                               const unsigned short* __restrict__ dtb,
                                               const float* __restrict__ dbl,
                                               const unsigned short* __restrict__ z,
                                               const float* __restrict__ A_log,
                                               const float* __restrict__ Dw,
                                               const unsigned short* __restrict__ Hloc,
                                               unsigned short* __restrict__ ybuf) {
  __shared__ float BCsh[CSZ][32];  // [r][0:16]=B, [r][16:32]=C
  int tid = threadIdx.x;
  int blk = blockIdx.x;
  int b = blk >> 8;
  int chunk = blk & (NCHUNK - 1);
  int l0 = chunk * CSZ;
  for (int idx = tid; idx < CSZ * 32; idx += 384) {
    int r = idx >> 5, n32 = idx & 31;
    BCsh[r][n32] = dbl[((size_t)b * L_ + l0 + r) * NDBL + DTR + n32];
  }
  int d = tid;
  float Dd = Dw[d];
  bool fast = true;
#pragma unroll
  for (int n = 0; n < 16; ++n) {
    float An_ = -__expf(A_log[d * 16 + n]);
    fast = fast && (fabsf(An_ + (float)(n + 1)) < 2e-3f);
  }
  size_t hbase = ((size_t)(b * NCHUNK + chunk) * 16) * DI + d;
  float h[16];
#pragma unroll
  for (int n = 0; n < 16; ++n) h[n] = bf2f(Hloc[hbase + (size_t)n * DI]);
  const unsigned short* xp = xsb + ((size_t)b * L_ + l0) * DI + d;
  const unsigned short* dtp = dtb + ((size_t)b * L_ + l0) * DI + d;
  const unsigned short* zp = z + ((size_t)b * L_ + l0) * DI + d;
  unsigned short* yp = ybuf + ((size_t)b * L_ + l0) * DI + d;
  __syncthreads();
  if (fast) {
#pragma unroll
    for (int i = 0; i < CSZ; ++i) {
      float sp = bf2f(dtp[(size_t)i * DI]);
      float xv = bf2f(xp[(size_t)i * DI]);
      float zv = bf2f(zp[(size_t)i * DI]);
      float dtx = sp * xv;
      float r = __expf(-sp);
      float r2 = r * r;
      float r4 = r2 * r2;
      float dA0 = r, dA1 = r2, dA2 = r2 * r, dA3 = r4;
      float y = 0.f;
#pragma unroll
      for (int g = 0; g < 4; ++g) {
        float4 Bg = *(const float4*)&BCsh[i][g << 2];
        float4 Cg = *(const float4*)&BCsh[i][16 + (g << 2)];
        h[(g << 2) + 0] = fmaf(dA0, h[(g << 2) + 0], dtx * Bg.x);
        h[(g << 2) + 1] = fmaf(dA1, h[(g << 2) + 1], dtx * Bg.y);
        h[(g << 2) + 2] = fmaf(dA2, h[(g << 2) + 2], dtx * Bg.z);
        h[(g << 2) + 3] = fmaf(dA3, h[(g << 2) + 3], dtx * Bg.w);
        y = fmaf(h[(g << 2) + 0], Cg.x, y);
        y = fmaf(h[(g << 2) + 1], Cg.y, y);
        y = fmaf(h[(g << 2) + 2], Cg.z, y);
        y = fmaf(h[(g << 2) + 3], Cg.w, y);
        if (g < 3) { dA0 *= r4; dA1 *= r4; dA2 *= r4; dA3 *= r4; }
      }
      y = fmaf(xv, Dd, y);
      float sig = __builtin_amdgcn_rcpf(1.f + __expf(-zv));
      yp[(size_t)i * DI] = f2bf(y * (zv * sig));
    }
  } else {
    float An[16];
#pragma unroll
    for (int n = 0; n < 16; ++n) An[n] = -__expf(A_log[d * 16 + n]);
#pragma unroll
    for (int i = 0; i < CSZ; ++i) {
      float sp = bf2f(dtp[(size_t)i * DI]);
      float xv = bf2f(xp[(size_t)i * DI]);
      float zv = bf2f(zp[(size_t)i * DI]);
      float dtx = sp * xv;
      float y = 0.f;
#pragma unroll
      for (int n = 0; n < 16; ++n) {
        h[n] = fmaf(__expf(sp * An[n]), h[n], dtx * BCsh[i][n]);
        y = fmaf(h[n], BCsh[i][16 + n], y);
      }
      y = fmaf(xv, Dd, y);
      float sig = __builtin_amdgcn_rcpf(1.f + __expf(-zv));
      yp[(size_t)i * DI] = f2bf(y * (zv * sig));
    }
  }
}

// ---------------- out_proj MFMA + residual: ybuf(BL,384) @ W(192,384)^T + x ----------
__global__ __launch_bounds__(256) void k_outproj(const unsigned short* __restrict__ Y,
                                                 const unsigned short* __restrict__ W,
                                                 const float* __restrict__ x,
                                                 float* __restrict__ out) {
  __shared__ float smemf[8448];
  unsigned short* As = (unsigned short*)smemf;
  unsigned short* Bs = (unsigned short*)smemf + 8192;
  int tid = threadIdx.x;
  int w = tid >> 6, l = tid & 63;
  int wr = w >> 1, wc = w & 1;
  int m0 = blockIdx.x << 7;
  int n0 = blockIdx.y << 6;
  int lr = l & 15, lk = l >> 4;
  f32x4 acc[4][2];
#pragma unroll
  for (int i = 0; i < 4; ++i)
#pragma unroll
    for (int j = 0; j < 2; ++j) acc[i][j] = (f32x4){0.f, 0.f, 0.f, 0.f};
  for (int kt = 0; kt < 6; ++kt) {
    int k0 = kt * 64;
    if (kt) __syncthreads();
#pragma unroll
    for (int i = 0; i < 4; ++i) {
      int row = (i << 5) + (tid >> 3);
      int gc = k0 + (((tid & 7) ^ (row & 7)) << 3);
      gload16(Y + (size_t)(m0 + row) * 384 + gc, &As[(i << 11) + (w << 9)]);
    }
#pragma unroll
    for (int i = 0; i < 2; ++i) {
      int row = (i << 5) + (tid >> 3);
      int gc = k0 + (((tid & 7) ^ (row & 7)) << 3);
      gload16(W + (size_t)(n0 + row) * 384 + gc, &Bs[(i << 11) + (w << 9)]);
    }
    __syncthreads();
#pragma unroll
    for (int ks = 0; ks < 2; ++ks) {
      int s = (ks << 2) + lk;
      bf16x8 bfr[2];
#pragma unroll
      for (int ni = 0; ni < 2; ++ni) {
        int r = (wc << 5) + (ni << 4) + lr;
        bfr[ni] = *(const bf16x8*)&Bs[r * 64 + ((s ^ (r & 7)) << 3)];
      }
#pragma unroll
      for (int mi = 0; mi < 4; ++mi) {
        int r = (wr << 6) + (mi << 4) + lr;
        bf16x8 a = *(const bf16x8*)&As[r * 64 + ((s ^ (r & 7)) << 3)];
#pragma unroll
        for (int ni = 0; ni < 2; ++ni) acc[mi][ni] = MFMA16(a, bfr[ni], acc[mi][ni]);
      }
    }
  }
  __syncthreads();
#pragma unroll
  for (int mi = 0; mi < 4; ++mi)
#pragma unroll
    for (int ni = 0; ni < 2; ++ni) {
      int c = (wc << 5) + (ni << 4) + lr;
      int lrow = (wr << 6) + (mi << 4) + (lk << 2);
      *(f32x4*)&smemf[c * 132 + lrow] = acc[mi][ni];
    }
  __syncthreads();
  int b = m0 >> 12;
  int l0 = m0 & (L_ - 1);
#pragma unroll
  for (int i = 0; i < 8; ++i) {
    int chunk = i * 256 + tid;
    int c = chunk >> 5, lq = chunk & 31;
    f32x4 v = *(const f32x4*)&smemf[c * 132 + (lq << 2)];
    size_t off = ((size_t)b * C_ + n0 + c) * L_ + l0 + (lq << 2);
    f32x4 xv = *(const f32x4*)&x[off];
    v = v + xv;
    *(f32x4*)&out[off] = v;
  }
}

extern "C" void kernel_launch(void* const* d_in, const int* in_sizes, int n_in,
                              void* d_out, int out_size, void* d_ws, size_t ws_size,
                              hipStream_t stream) {
  const float* x         = (const float*)d_in[0];
  const float* norm_w    = (const float*)d_in[1];
  const float* norm_b    = (const float*)d_in[2];
  const float* in_proj_w = (const float*)d_in[3];
  const float* conv_w    = (const float*)d_in[4];
  const float* conv_b    = (const float*)d_in[5];
  const float* x_proj_w  = (const float*)d_in[6];
  const float* dt_proj_w = (const float*)d_in[7];
  const float* dt_proj_b = (const float*)d_in[8];
  const float* A_log     = (const float*)d_in[9];
  const float* Dw        = (const float*)d_in[10];
  const float* out_proj_w= (const float*)d_in[11];
  float* out = (float*)d_out;
  float* ws = (float*)d_ws;

  unsigned short* seqn = (unsigned short*)(ws + F_SEQN);
  unsigned short* xin  = (unsigned short*)(ws + F_XIN);
  unsigned short* z    = (unsigned short*)(ws + F_Z);
  unsigned short* xsb  = (unsigned short*)(ws + F_XSB);
  float* dbl           = ws + F_DBL;
  unsigned short* dtb  = (unsigned short*)(ws + F_DT);
  float* Sbuf          = ws + F_SBUF;
  unsigned short* Hloc = (unsigned short*)(ws + F_HLOC);
  unsigned short* wbuf = (unsigned short*)(ws + F_WBUF);
  unsigned short* ipw  = wbuf;
  unsigned short* xpw  = wbuf + 147456;
  unsigned short* opw  = wbuf + 165888;
  unsigned short* ybuf = xin;  // xin dead after conv

  hipLaunchKernelGGL(k_ln, dim3(1192), dim3(256), 0, stream, x, norm_w, norm_b, seqn,
                     in_proj_w, x_proj_w, out_proj_w, wbuf);
  hipLaunchKernelGGL(k_inproj, dim3(128, 6), dim3(256), 0, stream, seqn, ipw, xin, z);
  hipLaunchKernelGGL(k_convx, dim3(64, 4), dim3(384), 0, stream, xin, conv_w, conv_b, xpw, xsb,
                     dbl);
  hipLaunchKernelGGL(k_scanA, dim3(1024), dim3(384), 0, stream, xsb, dbl, dt_proj_w, dt_proj_b,
                     A_log, dtb, Hloc, Sbuf);
  hipLaunchKernelGGL(k_scanB, dim3(96), dim3(256), 0, stream, A_log, Hloc, Sbuf);
  hipLaunchKernelGGL(k_scanC, dim3(1024), dim3(384), 0, stream, xsb, dtb, dbl, z, A_log, Dw,
                     Hloc, ybuf);
  hipLaunchKernelGGL(k_outproj, dim3(128, 3), dim3(256), 0, stream, ybuf, opw, x, out);
}

// Round 8
// 111.543 us; speedup vs baseline: 4.4705x; 1.0004x over previous
//
#include <hip/hip_runtime.h>
#include <hip/hip_bf16.h>

// Problem constants
constexpr int B_ = 4;
constexpr int C_ = 192;
constexpr int L_ = 4096;     // H*W
constexpr int DI = 384;      // d_inner
constexpr int DSs = 16;      // d_state
constexpr int DTR = 12;      // dt_rank
constexpr int NDBL = 44;     // dt_rank + 2*d_state
constexpr int NCHUNK = 256;  // scan chunks
constexpr int CSZ = 16;      // chunk size
constexpr int NSUP = 16;     // super-chunks (NSUP * 16 == NCHUNK)

constexpr size_t BL = (size_t)B_ * L_;  // 16384

// Workspace offsets in FLOAT units (bf16 buffers counted at half)
constexpr size_t F_SEQN = 0;                                   // bf16 BL*C
constexpr size_t F_XIN  = F_SEQN + BL * C_ / 2;                // bf16 BL*DI
constexpr size_t F_Z    = F_XIN + BL * DI / 2;                 // bf16 BL*DI
constexpr size_t F_XSB  = F_Z + BL * DI / 2;                   // bf16 BL*DI
constexpr size_t F_DBL  = F_XSB + BL * DI / 2;                 // f32  BL*NDBL
constexpr size_t F_DT   = F_DBL + BL * NDBL;                   // bf16 BL*DI
constexpr size_t F_SBUF = F_DT + BL * DI / 2;                  // f32  B*NCHUNK*DI
constexpr size_t F_HLOC = F_SBUF + (size_t)B_ * NCHUNK * DI;   // bf16 B*NCHUNK*16*DI
constexpr size_t F_SPRE = F_HLOC + (size_t)B_ * NCHUNK * DI * 16 / 2;  // f32 B*NCHUNK*DI
constexpr size_t F_HSUP = F_SPRE + (size_t)B_ * NCHUNK * DI;   // f32 B*NSUP*16*DI
constexpr size_t F_SSUP = F_HSUP + (size_t)B_ * NSUP * 16 * DI;// f32 B*NSUP*DI
constexpr size_t F_ISUP = F_SSUP + (size_t)B_ * NSUP * DI;     // f32 B*NSUP*16*DI
constexpr size_t F_WBUF = F_ISUP + (size_t)B_ * NSUP * 16 * DI;// bf16 weights
// total ~= 79 MB (prior rounds used 129 MB: safe)

typedef __attribute__((ext_vector_type(8))) short bf16x8;
typedef __attribute__((ext_vector_type(4))) float f32x4;

__device__ __forceinline__ unsigned short f2bf(float v) {
  unsigned x = __builtin_bit_cast(unsigned, v);
  unsigned r = x + 0x7FFFu + ((x >> 16) & 1u);   // RNE
  return (unsigned short)(r >> 16);
}
__device__ __forceinline__ float bf2f(unsigned short u) {
  return __builtin_bit_cast(float, (unsigned)u << 16);
}
__device__ __forceinline__ void gload16(const void* g, void* l) {
  __builtin_amdgcn_global_load_lds((const __attribute__((address_space(1))) void*)g,
                                   (__attribute__((address_space(3))) void*)l, 16, 0, 0);
}
#define MFMA16(a, b, c) __builtin_amdgcn_mfma_f32_16x16x32_bf16(a, b, c, 0, 0, 0)

// ---------------- LayerNorm (blocks 0..255, bf16 LDS tile) + weight cvt tail ---------
__global__ __launch_bounds__(256) void k_ln(const float* __restrict__ x,
                                            const float* __restrict__ nw,
                                            const float* __restrict__ nb,
                                            unsigned short* __restrict__ seqn,
                                            const float* __restrict__ ipw,
                                            const float* __restrict__ xpw,
                                            const float* __restrict__ opw,
                                            unsigned short* __restrict__ wbuf) {
  if (blockIdx.x >= 256) {
    int t = (blockIdx.x - 256) * 256 + threadIdx.x;
    if (t < 239616) {
      float v;
      if (t < 147456) v = ipw[t];
      else if (t < 165888) {
        int j = t - 147456;
        int r = j / 384, c = j - r * 384;
        v = (r < 44) ? xpw[r * 384 + c] : 0.f;
      } else v = opw[t - 165888];
      wbuf[t] = f2bf(v);
    }
    return;
  }
  __shared__ unsigned short xt[192][66];
  __shared__ float ps[4][64], ps2[4][64];
  __shared__ float mu_[64], rs_[64];
  __shared__ float wsh[192], bsh[192];
  int tid = threadIdx.x;
  int blk = blockIdx.x;
  int b = blk >> 6;
  int l0 = (blk & 63) << 6;
  const float* xb = x + (size_t)b * C_ * L_;
  for (int idx = tid; idx < 192 * 16; idx += 256) {
    int c = idx >> 4, lq = idx & 15;
    float4 v = *(const float4*)&xb[(size_t)c * L_ + l0 + (lq << 2)];
    ushort2 u0, u1;
    u0.x = f2bf(v.x); u0.y = f2bf(v.y);
    u1.x = f2bf(v.z); u1.y = f2bf(v.w);
    *(ushort2*)&xt[c][(lq << 2)] = u0;
    *(ushort2*)&xt[c][(lq << 2) + 2] = u1;
  }
  if (tid < 192) { wsh[tid] = nw[tid]; bsh[tid] = nb[tid]; }
  __syncthreads();
  int ll = tid & 63, q = tid >> 6;
  float s = 0.f, ss = 0.f;
  for (int c = q * 48; c < q * 48 + 48; ++c) {
    float v = bf2f(xt[c][ll]);
    s += v; ss += v * v;
  }
  ps[q][ll] = s; ps2[q][ll] = ss;
  __syncthreads();
  if (q == 0) {
    float st = ps[0][ll] + ps[1][ll] + ps[2][ll] + ps[3][ll];
    float sst = ps2[0][ll] + ps2[1][ll] + ps2[2][ll] + ps2[3][ll];
    float mu = st * (1.f / 192.f);
    float var = sst * (1.f / 192.f) - mu * mu;
    mu_[ll] = mu; rs_[ll] = rsqrtf(var + 1e-5f);
  }
  __syncthreads();
  unsigned short* so = seqn + ((size_t)b * L_ + l0) * C_;
  for (int idx = tid; idx < 64 * 192; idx += 256) {
    int l = idx / 192, c = idx - l * 192;
    so[idx] = f2bf((bf2f(xt[c][l]) - mu_[l]) * rs_[l] * wsh[c] + bsh[c]);
  }
}

// ---------------- in_proj MFMA: seqn(BL,192)bf16 @ W(768,192)^T -> xin,z bf16 --------
__global__ __launch_bounds__(256) void k_inproj(const unsigned short* __restrict__ A,
                                                const unsigned short* __restrict__ W,
                                                unsigned short* __restrict__ xin,
                                                unsigned short* __restrict__ z) {
  __shared__ unsigned short smem[16384];
  unsigned short* As = smem;
  unsigned short* Bs = smem + 8192;
  int tid = threadIdx.x;
  int w = tid >> 6, l = tid & 63;
  int wr = w >> 1, wc = w & 1;
  int m0 = blockIdx.x << 7;
  int n0 = blockIdx.y << 7;
  f32x4 acc[4][4];
#pragma unroll
  for (int i = 0; i < 4; ++i)
#pragma unroll
    for (int j = 0; j < 4; ++j) acc[i][j] = (f32x4){0.f, 0.f, 0.f, 0.f};
  int lr = l & 15, lk = l >> 4;
  for (int kt = 0; kt < 3; ++kt) {
    int k0 = kt * 64;
    if (kt) __syncthreads();
#pragma unroll
    for (int i = 0; i < 4; ++i) {
      int row = (i << 5) + (tid >> 3);
      int gc = k0 + (((tid & 7) ^ (row & 7)) << 3);
      gload16(A + (size_t)(m0 + row) * 192 + gc, &As[(i << 11) + (w << 9)]);
      gload16(W + (size_t)(n0 + row) * 192 + gc, &Bs[(i << 11) + (w << 9)]);
    }
    __syncthreads();
#pragma unroll
    for (int ks = 0; ks < 2; ++ks) {
      int s = (ks << 2) + lk;
      bf16x8 af[4], bfr[4];
#pragma unroll
      for (int mi = 0; mi < 4; ++mi) {
        int r = (wr << 6) + (mi << 4) + lr;
        af[mi] = *(const bf16x8*)&As[r * 64 + ((s ^ (r & 7)) << 3)];
      }
#pragma unroll
      for (int ni = 0; ni < 4; ++ni) {
        int r = (wc << 6) + (ni << 4) + lr;
        bfr[ni] = *(const bf16x8*)&Bs[r * 64 + ((s ^ (r & 7)) << 3)];
      }
#pragma unroll
      for (int mi = 0; mi < 4; ++mi)
#pragma unroll
        for (int ni = 0; ni < 4; ++ni) acc[mi][ni] = MFMA16(af[mi], bfr[ni], acc[mi][ni]);
    }
  }
  __syncthreads();
#pragma unroll
  for (int mi = 0; mi < 4; ++mi)
#pragma unroll
    for (int ni = 0; ni < 4; ++ni) {
      int col = (wc << 6) + (ni << 4) + lr;
#pragma unroll
      for (int r = 0; r < 4; ++r) {
        int row = (wr << 6) + (mi << 4) + (lk << 2) + r;
        smem[(row << 7) + col] = f2bf(acc[mi][ni][r]);
      }
    }
  __syncthreads();
#pragma unroll
  for (int i = 0; i < 8; ++i) {
    int chunk = i * 256 + tid;
    int row = chunk >> 4, cq = chunk & 15;
    int n = n0 + (cq << 3);
    unsigned short* dst = (n < 384) ? (xin + (size_t)(m0 + row) * DI + n)
                                    : (z + (size_t)(m0 + row) * DI + (n - 384));
    *(bf16x8*)dst = *(const bf16x8*)&smem[(row << 7) + (cq << 3)];
  }
}

// ---------------- fused conv(4)+SiLU+x_proj: xin -> xsb (global) + dbl ---------------
__global__ __launch_bounds__(384) void k_convx(const unsigned short* __restrict__ xin,
                                               const float* __restrict__ cw,
                                               const float* __restrict__ cb,
                                               const unsigned short* __restrict__ W,
                                               unsigned short* __restrict__ xsb,
                                               float* __restrict__ dbl) {
  __shared__ unsigned short xs[6 * 4096];  // 6 K-tiles [64 rows][64 cols], XOR-swizzled
  __shared__ unsigned short Bs[3072];      // 48 x 64 per K-step
  int tid = threadIdx.x;
  int w = tid >> 6, l = tid & 63;
  int b = blockIdx.y;
  int l0 = blockIdx.x << 6;
  int d = tid;  // 0..383
  float4 w4 = *(const float4*)&cw[d * 4];
  float bb = cb[d];
  const unsigned short* xp = xin + ((size_t)b * L_ + l0) * DI + d;
  unsigned short* op = xsb + ((size_t)b * L_ + l0) * DI + d;
  float x0 = 0.f, x1 = 0.f, x2 = 0.f;
  if (l0 > 0) {
    x0 = bf2f(*(xp - 3 * DI));
    x1 = bf2f(*(xp - 2 * DI));
    x2 = bf2f(*(xp - DI));
  }
  int kt = d >> 6, col = d & 63, g = col >> 3, e = col & 7;
  unsigned short* xsrow = xs + kt * 4096;
  for (int r = 0; r < 64; ++r) {
    float xv = bf2f(xp[(size_t)r * DI]);
    float a = bb + w4.x * x0 + w4.y * x1 + w4.z * x2 + w4.w * xv;
    float sv = a * __builtin_amdgcn_rcpf(1.f + __expf(-a));
    unsigned short sb = f2bf(sv);
    xsrow[r * 64 + ((g ^ (r & 7)) << 3) + e] = sb;
    op[(size_t)r * DI] = sb;
    x0 = x1; x1 = x2; x2 = xv;
  }
  __syncthreads();
  int lr = l & 15, lk = l >> 4;
  f32x4 acc[3];
#pragma unroll
  for (int i = 0; i < 3; ++i) acc[i] = (f32x4){0.f, 0.f, 0.f, 0.f};
  for (int kt2 = 0; kt2 < 6; ++kt2) {
    int k0 = kt2 * 64;
    if (kt2) __syncthreads();
    {
      int row = tid >> 3;  // 0..47
      int gc = k0 + (((tid & 7) ^ (row & 7)) << 3);
      gload16(W + (size_t)row * 384 + gc, &Bs[w << 9]);
    }
    __syncthreads();
    if (w < 4) {
#pragma unroll
      for (int ks = 0; ks < 2; ++ks) {
        int s = (ks << 2) + lk;
        int ar = (w << 4) + lr;
        bf16x8 a = *(const bf16x8*)&xs[kt2 * 4096 + ar * 64 + ((s ^ (ar & 7)) << 3)];
#pragma unroll
        for (int ni = 0; ni < 3; ++ni) {
          int br = (ni << 4) + lr;
          bf16x8 bbv = *(const bf16x8*)&Bs[br * 64 + ((s ^ (br & 7)) << 3)];
          acc[ni] = MFMA16(a, bbv, acc[ni]);
        }
      }
    }
  }
  if (w < 4) {
#pragma unroll
    for (int ni = 0; ni < 3; ++ni)
#pragma unroll
      for (int r = 0; r < 4; ++r) {
        int colq = (ni << 4) + lr;
        if (colq < NDBL)
          dbl[((size_t)b * L_ + l0 + (w << 4) + (lk << 2) + r) * NDBL + colq] = acc[ni][r];
      }
  }
}

// ---------------- scan pass A: dt_proj once (stores bf16 dt), local scan -------------
__global__ __launch_bounds__(384) void k_scanA(const unsigned short* __restrict__ xsb,
                                               const float* __restrict__ dbl,
                                               const float* __restrict__ dw,
                                               const float* __restrict__ dbias,
                                               const float* __restrict__ A_log,
                                               unsigned short* __restrict__ dtb,
                                               unsigned short* __restrict__ Hloc,
                                               float* __restrict__ Sbuf) {
  __shared__ float Bsh[CSZ][16];
  __shared__ float dl[CSZ][12];
  int tid = threadIdx.x;
  int blk = blockIdx.x;
  int b = blk >> 8;
  int chunk = blk & (NCHUNK - 1);
  int l0 = chunk * CSZ;
  for (int idx = tid; idx < CSZ * 28; idx += 384) {
    int r = idx / 28, c = idx - r * 28;
    float v = dbl[((size_t)b * L_ + l0 + r) * NDBL + c];
    if (c < 12) dl[r][c] = v; else Bsh[r][c - 12] = v;
  }
  int d = tid;
  float4 wv0 = *(const float4*)&dw[d * 12];
  float4 wv1 = *(const float4*)&dw[d * 12 + 4];
  float4 wv2 = *(const float4*)&dw[d * 12 + 8];
  float bias = dbias[d];
  bool fast = true;
#pragma unroll
  for (int n = 0; n < 16; ++n) {
    float An_ = -__expf(A_log[d * 16 + n]);
    fast = fast && (fabsf(An_ + (float)(n + 1)) < 2e-3f);
  }
  const unsigned short* xp = xsb + ((size_t)b * L_ + l0) * DI + d;
  unsigned short* dtp = dtb + ((size_t)b * L_ + l0) * DI + d;
  __syncthreads();
  float h[16];
#pragma unroll
  for (int n = 0; n < 16; ++n) h[n] = 0.f;
  float S = 0.f;
  if (fast) {
#pragma unroll
    for (int i = 0; i < CSZ; ++i) {
      float4 c0 = *(const float4*)&dl[i][0];
      float4 c1 = *(const float4*)&dl[i][4];
      float4 c2 = *(const float4*)&dl[i][8];
      float a = bias;
      a = fmaf(wv0.x, c0.x, a); a = fmaf(wv0.y, c0.y, a);
      a = fmaf(wv0.z, c0.z, a); a = fmaf(wv0.w, c0.w, a);
      a = fmaf(wv1.x, c1.x, a); a = fmaf(wv1.y, c1.y, a);
      a = fmaf(wv1.z, c1.z, a); a = fmaf(wv1.w, c1.w, a);
      a = fmaf(wv2.x, c2.x, a); a = fmaf(wv2.y, c2.y, a);
      a = fmaf(wv2.z, c2.z, a); a = fmaf(wv2.w, c2.w, a);
      float sp = fmaxf(a, 0.f) + __logf(1.f + __expf(-fabsf(a)));
      dtp[(size_t)i * DI] = f2bf(sp);
      S += sp;
      float xv = bf2f(xp[(size_t)i * DI]);
      float dtx = sp * xv;
      float r = __expf(-sp);
      float r2 = r * r;
      float r4 = r2 * r2;
      float dA0 = r, dA1 = r2, dA2 = r2 * r, dA3 = r4;
#pragma unroll
      for (int g = 0; g < 4; ++g) {
        float4 Bg = *(const float4*)&Bsh[i][g << 2];
        h[(g << 2) + 0] = fmaf(dA0, h[(g << 2) + 0], dtx * Bg.x);
        h[(g << 2) + 1] = fmaf(dA1, h[(g << 2) + 1], dtx * Bg.y);
        h[(g << 2) + 2] = fmaf(dA2, h[(g << 2) + 2], dtx * Bg.z);
        h[(g << 2) + 3] = fmaf(dA3, h[(g << 2) + 3], dtx * Bg.w);
        if (g < 3) { dA0 *= r4; dA1 *= r4; dA2 *= r4; dA3 *= r4; }
      }
    }
  } else {
    float An[16];
#pragma unroll
    for (int n = 0; n < 16; ++n) An[n] = -__expf(A_log[d * 16 + n]);
#pragma unroll
    for (int i = 0; i < CSZ; ++i) {
      float4 c0 = *(const float4*)&dl[i][0];
      float4 c1 = *(const float4*)&dl[i][4];
      float4 c2 = *(const float4*)&dl[i][8];
      float a = bias;
      a = fmaf(wv0.x, c0.x, a); a = fmaf(wv0.y, c0.y, a);
      a = fmaf(wv0.z, c0.z, a); a = fmaf(wv0.w, c0.w, a);
      a = fmaf(wv1.x, c1.x, a); a = fmaf(wv1.y, c1.y, a);
      a = fmaf(wv1.z, c1.z, a); a = fmaf(wv1.w, c1.w, a);
      a = fmaf(wv2.x, c2.x, a); a = fmaf(wv2.y, c2.y, a);
      a = fmaf(wv2.z, c2.z, a); a = fmaf(wv2.w, c2.w, a);
      float sp = fmaxf(a, 0.f) + __logf(1.f + __expf(-fabsf(a)));
      dtp[(size_t)i * DI] = f2bf(sp);
      S += sp;
      float xv = bf2f(xp[(size_t)i * DI]);
      float dtx = sp * xv;
#pragma unroll
      for (int n = 0; n < 16; ++n)
        h[n] = fmaf(__expf(sp * An[n]), h[n], dtx * Bsh[i][n]);
    }
  }
  size_t hbase = ((size_t)(b * NCHUNK + chunk) * 16) * DI + d;
#pragma unroll
  for (int n = 0; n < 16; ++n) Hloc[hbase + (size_t)n * DI] = f2bf(h[n]);
  Sbuf[((size_t)b * NCHUNK + chunk) * DI + d] = S;
}

// ---------------- scan pass B1: per-super local prefix (in-place) + super totals -----
// block = (b, s, n); threads = d.
__global__ __launch_bounds__(384) void k_scanB1(const float* __restrict__ A_log,
                                                unsigned short* __restrict__ Hloc,
                                                const float* __restrict__ Sbuf,
                                                float* __restrict__ Spre,
                                                float* __restrict__ Hsup,
                                                float* __restrict__ Ssup) {
  int d = threadIdx.x;
  int blk = blockIdx.x;
  int n = blk & 15;
  int s = (blk >> 4) & 15;
  int b = blk >> 8;
  float An = -__expf(A_log[d * 16 + n]);
  float h = 0.f, Sp = 0.f;
  int c0 = s * 16;
#pragma unroll
  for (int i = 0; i < 16; ++i) {
    int c = c0 + i;
    size_t hidx = (((size_t)(b * NCHUNK + c) * 16) + n) * DI + d;
    float Hl = bf2f(Hloc[hidx]);
    float S = Sbuf[((size_t)b * NCHUNK + c) * DI + d];
    Hloc[hidx] = f2bf(h);
    if (n == 0) Spre[((size_t)b * NCHUNK + c) * DI + d] = Sp;
    h = fmaf(__expf(An * S), h, Hl);
    Sp += S;
  }
  Hsup[(((size_t)(b * NSUP + s) * 16) + n) * DI + d] = h;
  if (n == 0) Ssup[((size_t)b * NSUP + s) * DI + d] = Sp;
}

// ---------------- scan pass B2: super-chunk recurrence -> Isup -----------------------
__global__ __launch_bounds__(384) void k_scanB2(const float* __restrict__ A_log,
                                                const float* __restrict__ Hsup,
                                                const float* __restrict__ Ssup,
                                                float* __restrict__ Isup) {
  int d = threadIdx.x;
  int blk = blockIdx.x;  // b*16 + n
  int n = blk & 15;
  int b = blk >> 4;
  float An = -__expf(A_log[d * 16 + n]);
  float I = 0.f;
#pragma unroll
  for (int s = 0; s < NSUP; ++s) {
    size_t idx = (((size_t)(b * NSUP + s) * 16) + n) * DI + d;
    Isup[idx] = I;
    I = fmaf(__expf(An * Ssup[((size_t)b * NSUP + s) * DI + d]), I, Hsup[idx]);
  }
}

// ---------------- scan pass C: carry + local scan + gating + fused out_proj ----------
__global__ __launch_bounds__(384) void k_scanC(const unsigned short* __restrict__ xsb,
                                               const unsigned short* __restrict__ dtb,
                                               const float* __restrict__ dbl,
                                               const unsigned short* __restrict__ z,
                                               const float* __restrict__ A_log,
                                               const float* __restrict__ Dw,
                                               const unsigned short* __restrict__ Hloc,
                                               const float* __restrict__ Spre,
                                               const float* __restrict__ Isup,
                                               const unsigned short* __restrict__ Wo,
                                               const float* __restrict__ x,
                                               float* __restrict__ out) {
  __shared__ float BCsh[CSZ][32];          // [r][0:16]=B, [r][16:32]=C
  __shared__ unsigned short yt[6 * 1024];  // y tile 16 x 384 bf16, 6 K-subtiles swizzled
  __shared__ unsigned short Bs[12288];     // W tile 192 x 64 bf16 per K-step
  int tid = threadIdx.x;
  int blk = blockIdx.x;
  int b = blk >> 8;
  int chunk = blk & (NCHUNK - 1);
  int l0 = chunk * CSZ;
  for (int idx = tid; idx < CSZ * 32; idx += 384) {
    int r = idx >> 5, n32 = idx & 31;
    BCsh[r][n32] = dbl[((size_t)b * L_ + l0 + r) * NDBL + DTR + n32];
  }
  int d = tid;
  float Dd = Dw[d];
  bool fast = true;
#pragma unroll
  for (int n = 0; n < 16; ++n) {
    float An_ = -__expf(A_log[d * 16 + n]);
    fast = fast && (fabsf(An_ + (float)(n + 1)) < 2e-3f);
  }
  // carry-in: h[n] = Hloc_local + exp(An*Spre) * Isup
  int sup = chunk >> 4;
  size_t hbase = ((size_t)(b * NCHUNK + chunk) * 16) * DI + d;
  size_t ibase = ((size_t)(b * NSUP + sup) * 16) * DI + d;
  float Spv = Spre[((size_t)b * NCHUNK + chunk) * DI + d];
  float h[16];
  if (fast) {
    float t = __expf(-Spv);
    float t2 = t * t;
    float t4 = t2 * t2;
    float p0 = t, p1 = t2, p2 = t2 * t, p3 = t4;
#pragma unroll
    for (int g = 0; g < 4; ++g) {
      h[(g << 2) + 0] = fmaf(p0, Isup[ibase + (size_t)((g << 2) + 0) * DI],
                             bf2f(Hloc[hbase + (size_t)((g << 2) + 0) * DI]));
      h[(g << 2) + 1] = fmaf(p1, Isup[ibase + (size_t)((g << 2) + 1) * DI],
                             bf2f(Hloc[hbase + (size_t)((g << 2) + 1) * DI]));
      h[(g << 2) + 2] = fmaf(p2, Isup[ibase + (size_t)((g << 2) + 2) * DI],
                             bf2f(Hloc[hbase + (size_t)((g << 2) + 2) * DI]));
      h[(g << 2) + 3] = fmaf(p3, Isup[ibase + (size_t)((g << 2) + 3) * DI],
                             bf2f(Hloc[hbase + (size_t)((g << 2) + 3) * DI]));
      if (g < 3) { p0 *= t4; p1 *= t4; p2 *= t4; p3 *= t4; }
    }
  } else {
#pragma unroll
    for (int n = 0; n < 16; ++n) {
      float An_ = -__expf(A_log[d * 16 + n]);
      h[n] = fmaf(__expf(An_ * Spv), Isup[ibase + (size_t)n * DI],
                  bf2f(Hloc[hbase + (size_t)n * DI]));
    }
  }
  const unsigned short* xp = xsb + ((size_t)b * L_ + l0) * DI + d;
  const unsigned short* dtp = dtb + ((size_t)b * L_ + l0) * DI + d;
  const unsigned short* zp = z + ((size_t)b * L_ + l0) * DI + d;
  int ktile = d >> 6, colq = d & 63, gq = colq >> 3, eq = colq & 7;
  unsigned short* ytp = yt + ktile * 1024;
  __syncthreads();
  if (fast) {
#pragma unroll
    for (int i = 0; i < CSZ; ++i) {
      float sp = bf2f(dtp[(size_t)i * DI]);
      float xv = bf2f(xp[(size_t)i * DI]);
      float zv = bf2f(zp[(size_t)i * DI]);
      float dtx = sp * xv;
      float r = __expf(-sp);
      float r2 = r * r;
      float r4 = r2 * r2;
      float dA0 = r, dA1 = r2, dA2 = r2 * r, dA3 = r4;
      float y = 0.f;
#pragma unroll
      for (int g = 0; g < 4; ++g) {
        float4 Bg = *(const float4*)&BCsh[i][g << 2];
        float4 Cg = *(const float4*)&BCsh[i][16 + (g << 2)];
        h[(g << 2) + 0] = fmaf(dA0, h[(g << 2) + 0], dtx * Bg.x);
        h[(g << 2) + 1] = fmaf(dA1, h[(g << 2) + 1], dtx * Bg.y);
        h[(g << 2) + 2] = fmaf(dA2, h[(g << 2) + 2], dtx * Bg.z);
        h[(g << 2) + 3] = fmaf(dA3, h[(g << 2) + 3], dtx * Bg.w);
        y = fmaf(h[(g << 2) + 0], Cg.x, y);
        y = fmaf(h[(g << 2) + 1], Cg.y, y);
        y = fmaf(h[(g << 2) + 2], Cg.z, y);
        y = fmaf(h[(g << 2) + 3], Cg.w, y);
        if (g < 3) { dA0 *= r4; dA1 *= r4; dA2 *= r4; dA3 *= r4; }
      }
      y = fmaf(xv, Dd, y);
      float sig = __builtin_amdgcn_rcpf(1.f + __expf(-zv));
      ytp[i * 64 + ((gq ^ (i & 7)) << 3) + eq] = f2bf(y * (zv * sig));
    }
  } else {
    float An[16];
#pragma unroll
    for (int n = 0; n < 16; ++n) An[n] = -__expf(A_log[d * 16 + n]);
#pragma unroll
    for (int i = 0; i < CSZ; ++i) {
      float sp = bf2f(dtp[(size_t)i * DI]);
      float xv = bf2f(xp[(size_t)i * DI]);
      float zv = bf2f(zp[(size_t)i * DI]);
      float dtx = sp * xv;
      float y = 0.f;
#pragma unroll
      for (int n = 0; n < 16; ++n) {
        h[n] = fmaf(__expf(sp * An[n]), h[n], dtx * BCsh[i][n]);
        y = fmaf(h[n], BCsh[i][16 + n], y);
      }
      y = fmaf(xv, Dd, y);
      float sig = __builtin_amdgcn_rcpf(1.f + __expf(-zv));
      ytp[i * 64 + ((gq ^ (i & 7)) << 3) + eq] = f2bf(y * (zv * sig));
    }
  }
  // ---- fused out_proj: out[16 x 192] = y(16x384) @ Wo(192,384)^T + x ----
  int w = tid >> 6, l = tid & 63;
  int lr = l & 15, lk = l >> 4;
  f32x4 acc[2];
  acc[0] = (f32x4){0.f, 0.f, 0.f, 0.f};
  acc[1] = (f32x4){0.f, 0.f, 0.f, 0.f};
  for (int kt = 0; kt < 6; ++kt) {
    int k0 = kt * 64;
    __syncthreads();  // yt ready (kt=0) / prev MFMA reads of Bs done (kt>0)
#pragma unroll
    for (int j = 0; j < 4; ++j) {
      int row = j * 48 + (tid >> 3);
      int gc = k0 + (((tid & 7) ^ (row & 7)) << 3);
      gload16(Wo + (size_t)row * 384 + gc, &Bs[j * 3072 + (w << 9)]);
    }
    __syncthreads();
#pragma unroll
    for (int ks = 0; ks < 2; ++ks) {
      int s = (ks << 2) + lk;
      bf16x8 a = *(const bf16x8*)&yt[kt * 1024 + lr * 64 + ((s ^ (lr & 7)) << 3)];
#pragma unroll
      for (int ni = 0; ni < 2; ++ni) {
        int br = ((w << 1) + ni) * 16 + lr;
        bf16x8 bv = *(const bf16x8*)&Bs[br * 64 + ((s ^ (br & 7)) << 3)];
        acc[ni] = MFMA16(a, bv, acc[ni]);
      }
    }
  }
#pragma unroll
  for (int ni = 0; ni < 2; ++ni) {
    int c = ((w << 1) + ni) * 16 + lr;
    size_t off = ((size_t)b * C_ + c) * L_ + l0 + (lk << 2);
    f32x4 xv = *(const f32x4*)&x[off];
    *(f32x4*)&out[off] = acc[ni] + xv;
  }
}

extern "C" void kernel_launch(void* const* d_in, const int* in_sizes, int n_in,
                              void* d_out, int out_size, void* d_ws, size_t ws_size,
                              hipStream_t stream) {
  const float* x         = (const float*)d_in[0];
  const float* norm_w    = (const float*)d_in[1];
  const float* norm_b    = (const float*)d_in[2];
  const float* in_proj_w = (const float*)d_in[3];
  const float* conv_w    = (const float*)d_in[4];
  const float* conv_b    = (const float*)d_in[5];
  const float* x_proj_w  = (const float*)d_in[6];
  const float* dt_proj_w = (const float*)d_in[7];
  const float* dt_proj_b = (const float*)d_in[8];
  const float* A_log     = (const float*)d_in[9];
  const float* Dw        = (const float*)d_in[10];
  const float* out_proj_w= (const float*)d_in[11];
  float* out = (float*)d_out;
  float* ws = (float*)d_ws;

  unsigned short* seqn = (unsigned short*)(ws + F_SEQN);
  unsigned short* xin  = (unsigned short*)(ws + F_XIN);
  unsigned short* z    = (unsigned short*)(ws + F_Z);
  unsigned short* xsb  = (unsigned short*)(ws + F_XSB);
  float* dbl           = ws + F_DBL;
  unsigned short* dtb  = (unsigned short*)(ws + F_DT);
  float* Sbuf          = ws + F_SBUF;
  unsigned short* Hloc = (unsigned short*)(ws + F_HLOC);
  float* Spre          = ws + F_SPRE;
  float* Hsup          = ws + F_HSUP;
  float* Ssup          = ws + F_SSUP;
  float* Isup          = ws + F_ISUP;
  unsigned short* wbuf = (unsigned short*)(ws + F_WBUF);
  unsigned short* ipw  = wbuf;
  unsigned short* xpw  = wbuf + 147456;
  unsigned short* opw  = wbuf + 165888;

  hipLaunchKernelGGL(k_ln, dim3(1192), dim3(256), 0, stream, x, norm_w, norm_b, seqn,
                     in_proj_w, x_proj_w, out_proj_w, wbuf);
  hipLaunchKernelGGL(k_inproj, dim3(128, 6), dim3(256), 0, stream, seqn, ipw, xin, z);
  hipLaunchKernelGGL(k_convx, dim3(64, 4), dim3(384), 0, stream, xin, conv_w, conv_b, xpw, xsb,
                     dbl);
  hipLaunchKernelGGL(k_scanA, dim3(1024), dim3(384), 0, stream, xsb, dbl, dt_proj_w, dt_proj_b,
                     A_log, dtb, Hloc, Sbuf);
  hipLaunchKernelGGL(k_scanB1, dim3(1024), dim3(384), 0, stream, A_log, Hloc, Sbuf, Spre, Hsup,
                     Ssup);
  hipLaunchKernelGGL(k_scanB2, dim3(64), dim3(384), 0, stream, A_log, Hsup, Ssup, Isup);
  hipLaunchKernelGGL(k_scanC, dim3(1024), dim3(384), 0, stream, xsb, dtb, dbl, z, A_log, Dw,
                     Hloc, Spre, Isup, opw, x, out);
}